// Round 7
// baseline (1094.956 us; speedup 1.0000x reference)
//
#include <hip/hip_runtime.h>
#include <hip/hip_bf16.h>
#include <math.h>

typedef __hip_bfloat16 bf16;
typedef __attribute__((ext_vector_type(8))) short short8;   // 8 bf16 (4 VGPRs)
typedef __attribute__((ext_vector_type(4))) short s4v;      // 4 bf16 (8 bytes)
typedef __attribute__((ext_vector_type(4))) float f32x4;

constexpr int B_ = 8, S_ = 1024, F_ = 8, D_ = 512, H_ = 8, E_ = 4;
constexpr int T_  = B_ * S_;       // 8192 tokens
constexpr int D3_ = 3 * D_;        // 1536
constexpr int CAP_ = T_ * 2 + E_ * 128;   // sparse row capacity (top-2, 128-pad/expert)

__device__ __forceinline__ float b2f(bf16 v) { return __bfloat162float(v); }
__device__ __forceinline__ float ldin(const void* p, size_t i, int bf) {
  return bf ? __bfloat162float(((const bf16*)p)[i]) : ((const float*)p)[i];
}
__device__ __forceinline__ void gload16(const void* g, void* l) {
  __builtin_amdgcn_global_load_lds((const __attribute__((address_space(1))) unsigned int*)g,
                                   (__attribute__((address_space(3))) unsigned int*)l, 16, 0, 0);
}

// ---------------- dtype detector ----------------
__global__ void detect_kernel(const void* __restrict__ x, int* __restrict__ flag) {
  if (threadIdx.x == 0 && blockIdx.x == 0) {
    const unsigned short* u = (const unsigned short*)x;
    int c = 0;
    for (int i = 0; i < 256; i += 2) {
      int ex = (u[i] >> 7) & 0xFF;
      if (ex >= 96 && ex <= 144) c++;
    }
    flag[0] = (c >= 64) ? 1 : 0;
  }
}

// ---------------- weight pre-convert: fp32 (or bf16 copy) -> bf16 scratch ----------
__global__ __launch_bounds__(256) void convw_kernel(const void* __restrict__ Asrc, size_t offA,
                                                    size_t nA,
                                                    const void* __restrict__ Bsrc, size_t offB,
                                                    bf16* __restrict__ dst,
                                                    const int* __restrict__ flag) {
  const int bf = flag[0];
  size_t i = ((size_t)blockIdx.x * 256 + threadIdx.x) * 8;
  const void* s = Asrc;
  size_t so = offA + i;
  if (i >= nA) { s = Bsrc; so = offB + (i - nA); }
  if (bf) {
    *(short8*)(dst + i) = *(const short8*)((const bf16*)s + so);
  } else {
    const float* sp = (const float*)s + so;
    short8 v;
#pragma unroll
    for (int u = 0; u < 8; u++) { bf16 t = __float2bfloat16(sp[u]); v[u] = *(short*)&t; }
    *(short8*)(dst + i) = v;
  }
}

// ---------------- instance norm over time axis ----------------
__global__ __launch_bounds__(256) void instnorm_kernel(const void* __restrict__ x,
                                                       float* __restrict__ xn,
                                                       const int* __restrict__ flag) {
  const int bf = flag[0];
  int b = blockIdx.x / F_, f = blockIdx.x % F_;
  int tid = threadIdx.x;
  __shared__ float red[256];
  const int base = b * S_ * F_ + f;
  float s = 0.f;
  for (int j = tid; j < S_; j += 256) s += ldin(x, base + j * F_, bf);
  red[tid] = s; __syncthreads();
  for (int w = 128; w; w >>= 1) { if (tid < w) red[tid] += red[tid + w]; __syncthreads(); }
  float mean = red[0] / S_;
  __syncthreads();
  float v = 0.f;
  for (int j = tid; j < S_; j += 256) { float d = ldin(x, base + j * F_, bf) - mean; v += d * d; }
  red[tid] = v; __syncthreads();
  for (int w = 128; w; w >>= 1) { if (tid < w) red[tid] += red[tid + w]; __syncthreads(); }
  float inv = 1.f / (sqrtf(red[0] / (float)(S_ - 1)) + 1e-5f);
  for (int j = tid; j < S_; j += 256) xn[base + j * F_] = (ldin(x, base + j * F_, bf) - mean) * inv;
}

// ---------------- positional-encoding + bias + freq-emb add-table [S][D] -----------
__global__ __launch_bounds__(256) void pe_kernel(const void* __restrict__ bp,
                                                 const void* __restrict__ femb,
                                                 const int* __restrict__ freq_idx,
                                                 float* __restrict__ addtab,
                                                 const int* __restrict__ flag) {
  const int bf = flag[0];
  int idx = blockIdx.x * 256 + threadIdx.x;      // S*D/2 threads
  int dp = idx & (D_ / 2 - 1);
  int s  = idx / (D_ / 2);
  int d0 = dp * 2;
  int fi = freq_idx[0];
  const float cexp = -9.2103403719761836f / (float)D_;
  float ang = (float)s * expf((float)d0 * cexp);
  float sv, cv;
  sincosf(ang, &sv, &cv);
  addtab[(size_t)s * D_ + d0]     = sv + ldin(bp, d0, bf)     + ldin(femb, (size_t)fi * D_ + d0, bf);
  addtab[(size_t)s * D_ + d0 + 1] = cv + ldin(bp, d0 + 1, bf) + ldin(femb, (size_t)fi * D_ + d0 + 1, bf);
}

// ---------------- input projection: xn @ Wp^T + addtab -----------------------------
constexpr int IPG_ = 8;   // tokens per block
__global__ __launch_bounds__(256) void input_proj_kernel(const float* __restrict__ xn,
                                                         const void* __restrict__ Wp,
                                                         const float* __restrict__ addtab,
                                                         float* __restrict__ h,
                                                         bf16* __restrict__ hb16,
                                                         const int* __restrict__ flag) {
  const int bf = flag[0];
  const int tid = threadIdx.x;
  const int d0 = tid * 2;
  const int tbase = blockIdx.x * IPG_;
  float wp0[8], wp1[8];
  if (bf) {
    short8 w0 = *(const short8*)((const bf16*)Wp + (size_t)d0 * F_);
    short8 w1 = *(const short8*)((const bf16*)Wp + (size_t)(d0 + 1) * F_);
#pragma unroll
    for (int f = 0; f < 8; f++) {
      unsigned short u0 = (unsigned short)w0[f], u1 = (unsigned short)w1[f];
      wp0[f] = __bfloat162float(*(bf16*)&u0);
      wp1[f] = __bfloat162float(*(bf16*)&u1);
    }
  } else {
    const float* wpf = (const float*)Wp + (size_t)d0 * F_;
    f32x4 a = *(const f32x4*)(wpf);
    f32x4 b = *(const f32x4*)(wpf + 4);
    f32x4 c = *(const f32x4*)(wpf + 8);
    f32x4 d = *(const f32x4*)(wpf + 12);
#pragma unroll
    for (int f = 0; f < 4; f++) { wp0[f] = a[f]; wp0[4 + f] = b[f]; wp1[f] = c[f]; wp1[4 + f] = d[f]; }
  }
#pragma unroll
  for (int g = 0; g < IPG_; g++) {
    int t = tbase + g;
    int s = t & (S_ - 1);
    const float* xr = xn + (size_t)t * F_;
    f32x4 x0 = *(const f32x4*)xr;
    f32x4 x1 = *(const f32x4*)(xr + 4);
    const float2 at = *(const float2*)(addtab + (size_t)s * D_ + d0);
    float a0 = at.x, a1 = at.y;
#pragma unroll
    for (int f = 0; f < 4; f++) { a0 += x0[f] * wp0[f]; a1 += x0[f] * wp1[f]; }
#pragma unroll
    for (int f = 0; f < 4; f++) { a0 += x1[f] * wp0[4 + f]; a1 += x1[f] * wp1[4 + f]; }
    *(float2*)(h + (size_t)t * D_ + d0) = make_float2(a0, a1);
    bf16 b0 = __float2bfloat16(a0), b1 = __float2bfloat16(a1);
    unsigned pk = (unsigned)(*(unsigned short*)&b0) | ((unsigned)(*(unsigned short*)&b1) << 16);
    *(unsigned*)(hb16 + (size_t)t * D_ + d0) = pk;
  }
}

// ---------------- dense MFMA GEMM, 128x128 tile (O-proj split-K path) ---------------
template <int MODE>
__global__ __launch_bounds__(256) void mfma_gemm(
    const bf16* __restrict__ A, const bf16* __restrict__ Wt,
    const void* __restrict__ bias, size_t boff, void* __restrict__ C_,
    int Kd, int lda, int ldb, int ldc, const int* __restrict__ flag) {
  const int wbf = flag[0];
  __shared__ bf16 As[2][128][32];
  __shared__ bf16 Bs[2][128][32];
  const int tid = threadIdx.x;
  const int ln = tid & 63, wv = tid >> 6;
  int id = blockIdx.x + gridDim.x * blockIdx.y;
  int xcd = id & 7, idq = id >> 3;
  const int n0 = (idq % gridDim.x) * 128;
  const int m0 = (xcd + 8 * (idq / gridDim.x)) * 128;
  const int wr = (wv >> 1) * 64, wc = (wv & 1) * 64;
  const int mrow = ln & 15, quad = ln >> 4;
  const int srow = ln >> 2;
  const int skof = (ln & 3) * 8;
  const int kchunk = Kd / gridDim.z;
  const int kbeg = blockIdx.z * kchunk;
  const int kend = kbeg + kchunk;

  auto stage = [&](int pb, int k0) {
#pragma unroll
    for (int j = 0; j < 2; j++) {
      int row = 16 * (4 * j + wv) + srow;
      gload16(A + (size_t)(m0 + row) * lda + k0 + skof,
              (char*)&As[pb][0][0] + (size_t)(4 * j + wv) * 1024);
    }
#pragma unroll
    for (int j = 0; j < 2; j++) {
      int row = 16 * (4 * j + wv) + srow;
      gload16(Wt + (size_t)(n0 + row) * ldb + k0 + skof,
              (char*)&Bs[pb][0][0] + (size_t)(4 * j + wv) * 1024);
    }
  };

  f32x4 acc[4][4];
#pragma unroll
  for (int i = 0; i < 4; i++)
#pragma unroll
    for (int j = 0; j < 4; j++) acc[i][j] = (f32x4){0.f, 0.f, 0.f, 0.f};

  stage(0, kbeg);
  int p = 0;
  for (int k0 = kbeg; k0 < kend; k0 += 32) {
    __syncthreads();
    if (k0 + 32 < kend) stage(p ^ 1, k0 + 32);
    short8 af[4], bfr[4];
#pragma unroll
    for (int t = 0; t < 4; t++) {
      af[t]  = *(const short8*)&As[p][wr + t * 16 + mrow][quad * 8];
      bfr[t] = *(const short8*)&Bs[p][wc + t * 16 + mrow][quad * 8];
    }
#pragma unroll
    for (int i = 0; i < 4; i++)
#pragma unroll
      for (int j = 0; j < 4; j++)
        acc[i][j] = __builtin_amdgcn_mfma_f32_16x16x32_bf16(af[i], bfr[j], acc[i][j], 0, 0, 0);
    p ^= 1;
  }

  bf16* slice = (MODE == 0) ? (bf16*)C_ + (size_t)blockIdx.z * T_ * D_ : (bf16*)C_;
#pragma unroll
  for (int tj = 0; tj < 4; tj++) {
    int n = n0 + wc + tj * 16 + mrow;
    float bv = (MODE == 3) ? ldin(bias, boff + n, wbf) : 0.f;
#pragma unroll
    for (int ti = 0; ti < 4; ti++) {
      int mbase = m0 + wr + ti * 16 + quad * 4;
#pragma unroll
      for (int r = 0; r < 4; r++) {
        int m = mbase + r;
        float v = acc[ti][tj][r];
        slice[(size_t)m * ldc + n] = __float2bfloat16(MODE == 3 ? v + bv : v);
      }
    }
  }
}

// ---------------- dense MFMA GEMM, 128x256 tile (QKV) -------------------------------
// 32 MFMA per K-step (2x compute per barrier drain vs 128-tile): short-K latency fix.
// LDS 48KB; acc[4][8]. Grid (N/256, M/128), XCD swizzle as before.
__global__ __launch_bounds__(256) void mfma_gemm256(
    const bf16* __restrict__ A, const bf16* __restrict__ Wt,
    const void* __restrict__ bias, size_t boff, bf16* __restrict__ C_,
    int Kd, int lda, int ldb, int ldc, const int* __restrict__ flag) {
  const int wbf = flag[0];
  __shared__ bf16 As[2][128][32];
  __shared__ bf16 Bs[2][256][32];
  const int tid = threadIdx.x;
  const int ln = tid & 63, wv = tid >> 6;
  int id = blockIdx.x + gridDim.x * blockIdx.y;
  int xcd = id & 7, idq = id >> 3;
  const int n0 = (idq % gridDim.x) * 256;
  const int m0 = (xcd + 8 * (idq / gridDim.x)) * 128;
  const int wr = (wv >> 1) * 64, wc = (wv & 1) * 128;
  const int mrow = ln & 15, quad = ln >> 4;
  const int srow = ln >> 2;
  const int skof = (ln & 3) * 8;

  auto stage = [&](int pb, int k0) {
#pragma unroll
    for (int j = 0; j < 2; j++) {
      int row = 16 * (4 * j + wv) + srow;
      gload16(A + (size_t)(m0 + row) * lda + k0 + skof,
              (char*)&As[pb][0][0] + (size_t)(4 * j + wv) * 1024);
    }
#pragma unroll
    for (int j = 0; j < 4; j++) {
      int row = 16 * (4 * j + wv) + srow;
      gload16(Wt + (size_t)(n0 + row) * ldb + k0 + skof,
              (char*)&Bs[pb][0][0] + (size_t)(4 * j + wv) * 1024);
    }
  };

  f32x4 acc[4][8];
#pragma unroll
  for (int i = 0; i < 4; i++)
#pragma unroll
    for (int j = 0; j < 8; j++) acc[i][j] = (f32x4){0.f, 0.f, 0.f, 0.f};

  stage(0, 0);
  int p = 0;
  for (int k0 = 0; k0 < Kd; k0 += 32) {
    __syncthreads();
    if (k0 + 32 < Kd) stage(p ^ 1, k0 + 32);
    short8 af[4], bfr[8];
#pragma unroll
    for (int t = 0; t < 4; t++) af[t] = *(const short8*)&As[p][wr + t * 16 + mrow][quad * 8];
#pragma unroll
    for (int t = 0; t < 8; t++) bfr[t] = *(const short8*)&Bs[p][wc + t * 16 + mrow][quad * 8];
#pragma unroll
    for (int i = 0; i < 4; i++)
#pragma unroll
      for (int j = 0; j < 8; j++)
        acc[i][j] = __builtin_amdgcn_mfma_f32_16x16x32_bf16(af[i], bfr[j], acc[i][j], 0, 0, 0);
    p ^= 1;
  }

#pragma unroll
  for (int tj = 0; tj < 8; tj++) {
    int n = n0 + wc + tj * 16 + mrow;
    float bv = ldin(bias, boff + n, wbf);
#pragma unroll
    for (int ti = 0; ti < 4; ti++) {
      int mbase = m0 + wr + ti * 16 + quad * 4;
#pragma unroll
      for (int r = 0; r < 4; r++) {
        C_[(size_t)(mbase + r) * ldc + n] = __float2bfloat16(acc[ti][tj][r] + bv);
      }
    }
  }
}

// ---------------- MFMA flash attention: 64-query tile, swapped QK^T softmax --------
__global__ __launch_bounds__(256) void attn_kernel(const bf16* __restrict__ qkv,
                                                   bf16* __restrict__ o) {
  __shared__ bf16 QP[64][72];    // Q tile, then P tile (aliased; rows wv*16.. wave-private)
  __shared__ bf16 Ks[64][72];
  __shared__ bf16 Vt[64][72];    // [d][k ^ swz(d)]
  const int tid = threadIdx.x;
  const int ln = tid & 63, wv = tid >> 6;
  const int mrow = ln & 15, quad = ln >> 4;
  const int id = blockIdx.x;
  const int xcd = id & 7, j = id >> 3;
  const int qt = j & 15;
  const int pr = xcd + 8 * (j >> 4);     // 0..63
  const int hh = pr & 7, b = pr >> 3;
  const int q0 = qt * 64;
  const int sr = tid >> 2;
  const int sg = tid & 3;
  const int sc = sg * 8;

  {
    const bf16* src = qkv + (size_t)(b * S_ + q0 + sr) * D3_ + hh * 64;
    *(short8*)&QP[sr][sc]      = *(const short8*)(src + sc);
    *(short8*)&QP[sr][sc + 32] = *(const short8*)(src + sc + 32);
  }
  __syncthreads();
  short8 aq[2];
  aq[0] = *(const short8*)&QP[wv * 16 + mrow][quad * 8];
  aq[1] = *(const short8*)&QP[wv * 16 + mrow][quad * 8 + 32];

  float m_st = -1e30f, l_st = 0.f;
  f32x4 oacc[4];
#pragma unroll
  for (int t = 0; t < 4; t++) oacc[t] = (f32x4){0.f, 0.f, 0.f, 0.f};

  for (int kt = 0; kt < 16; kt++) {
    int k0 = kt * 64;
    __syncthreads();
    {
      const bf16* src = qkv + (size_t)(b * S_ + k0 + sr) * D3_ + D_ + hh * 64;
      *(short8*)&Ks[sr][sc]      = *(const short8*)(src + sc);
      *(short8*)&Ks[sr][sc + 32] = *(const short8*)(src + sc + 32);
    }
    {
      const bf16* src = qkv + (size_t)(b * S_ + k0 + sr) * D3_ + 2 * D_ + hh * 64;
      short8 v0 = *(const short8*)(src + sc);
      short8 v1 = *(const short8*)(src + sc + 32);
      int col0 = sr ^ (sg << 4);
      int col1 = sr ^ (((sg + 4) & 3) << 4);
#pragma unroll
      for (int u = 0; u < 8; u++) {
        *(short*)&Vt[sc + u][col0]      = v0[u];
        *(short*)&Vt[sc + 32 + u][col1] = v1[u];
      }
    }
    __syncthreads();
    f32x4 s[4];
#pragma unroll
    for (int t = 0; t < 4; t++) {
      s[t] = (f32x4){0.f, 0.f, 0.f, 0.f};
#pragma unroll
      for (int ks = 0; ks < 2; ks++) {
        short8 bk = *(const short8*)&Ks[t * 16 + mrow][quad * 8 + ks * 32];
        s[t] = __builtin_amdgcn_mfma_f32_16x16x32_bf16(bk, aq[ks], s[t], 0, 0, 0);
      }
    }
    float rm = s[0][0];
#pragma unroll
    for (int t = 0; t < 4; t++)
#pragma unroll
      for (int r = 0; r < 4; r++) rm = fmaxf(rm, s[t][r]);
    rm *= 0.125f;
    rm = fmaxf(rm, __shfl_xor(rm, 16, 64));
    rm = fmaxf(rm, __shfl_xor(rm, 32, 64));
    float mnew = fmaxf(m_st, rm);
    float alpha = __expf(m_st - mnew);
    m_st = mnew;
    float rs = 0.f;
#pragma unroll
    for (int t = 0; t < 4; t++) {
      s4v pk;
#pragma unroll
      for (int r = 0; r < 4; r++) {
        float p = __expf(s[t][r] * 0.125f - mnew);
        rs += p;
        bf16 tb = __float2bfloat16(p);
        pk[r] = *(short*)&tb;
      }
      *(s4v*)&QP[wv * 16 + mrow][t * 16 + quad * 4] = pk;
    }
    rs += __shfl_xor(rs, 16, 64);
    rs += __shfl_xor(rs, 32, 64);
    l_st = l_st * alpha + rs;
    float af4[4];
#pragma unroll
    for (int r = 0; r < 4; r++) af4[r] = __shfl(alpha, quad * 4 + r, 64);
#pragma unroll
    for (int t = 0; t < 4; t++)
#pragma unroll
      for (int r = 0; r < 4; r++) oacc[t][r] *= af4[r];
    short8 ap[2];
    ap[0] = *(const short8*)&QP[wv * 16 + mrow][quad * 8];
    ap[1] = *(const short8*)&QP[wv * 16 + mrow][quad * 8 + 32];
#pragma unroll
    for (int t = 0; t < 4; t++) {
      int d = t * 16 + mrow;
      int swz = ((d >> 3) & 3) << 4;
#pragma unroll
      for (int ks = 0; ks < 2; ks++) {
        short8 bv = *(const short8*)&Vt[d][(quad * 8 + ks * 32) ^ swz];
        oacc[t] = __builtin_amdgcn_mfma_f32_16x16x32_bf16(ap[ks], bv, oacc[t], 0, 0, 0);
      }
    }
  }
  float linv[4];
#pragma unroll
  for (int r = 0; r < 4; r++) linv[r] = 1.f / __shfl(l_st, quad * 4 + r, 64);
#pragma unroll
  for (int r = 0; r < 4; r++) {
    size_t base = (size_t)(b * S_ + q0 + wv * 16 + quad * 4 + r) * D_ + hh * 64;
#pragma unroll
    for (int t = 0; t < 4; t++)
      o[base + t * 16 + mrow] = __float2bfloat16(oacc[t][r] * linv[r]);
  }
}

// ---------------- fused: sum partial slices + bias + residual + LayerNorm ----------
__global__ __launch_bounds__(256) void reduce_ln_kernel(float* __restrict__ h,
                                                        bf16* __restrict__ hb16,
                                                        const bf16* __restrict__ ps,
                                                        int nsl, int mode,
                                                        const void* __restrict__ bias,
                                                        size_t boff,
                                                        const float* __restrict__ cw,
                                                        const void* __restrict__ eb2p,
                                                        size_t e2off,
                                                        const void* __restrict__ g,
                                                        const void* __restrict__ beta,
                                                        size_t off,
                                                        const int* __restrict__ flag) {
  const int bf = flag[0];
  int t = blockIdx.x, tid = threadIdx.x;
  __shared__ float r1[256], r2[256];
  const size_t base = (size_t)t * D_;
  float o0 = 0.f, o1 = 0.f;
  for (int s = 0; s < nsl; s++) {
    o0 += b2f(ps[(size_t)s * T_ * D_ + base + tid]);
    o1 += b2f(ps[(size_t)s * T_ * D_ + base + tid + 256]);
  }
  if (mode == 0) {
    o0 += ldin(bias, boff + tid, bf);
    o1 += ldin(bias, boff + tid + 256, bf);
  } else {
#pragma unroll
    for (int e = 0; e < 4; e++) {
      float w = cw[t * 4 + e];
      o0 += w * ldin(eb2p, e2off + e * D_ + tid, bf);
      o1 += w * ldin(eb2p, e2off + e * D_ + tid + 256, bf);
    }
  }
  float* hr = h + base;
  float v0 = hr[tid] + o0;
  float v1 = hr[tid + 256] + o1;
  r1[tid] = v0 + v1;
  r2[tid] = v0 * v0 + v1 * v1;
  __syncthreads();
  for (int w = 128; w; w >>= 1) { if (tid < w) { r1[tid] += r1[tid + w]; r2[tid] += r2[tid + w]; } __syncthreads(); }
  float mean = r1[0] * (1.f / D_);
  float var  = r2[0] * (1.f / D_) - mean * mean;
  float rstd = rsqrtf(var + 1e-5f);
  float n0 = (v0 - mean) * rstd * ldin(g, off + tid, bf) + ldin(beta, off + tid, bf);
  float n1 = (v1 - mean) * rstd * ldin(g, off + tid + 256, bf) + ldin(beta, off + tid + 256, bf);
  hr[tid] = n0;
  hr[tid + 256] = n1;
  hb16[base + tid] = __float2bfloat16(n0);
  hb16[base + tid + 256] = __float2bfloat16(n1);
}

// ---------------- MoE gating: softmax over E=4, top-2; emits routing info ----------
__global__ __launch_bounds__(256) void gate_kernel(const float* __restrict__ hbuf,
                                                   const void* __restrict__ gw, size_t gwoff,
                                                   const void* __restrict__ gb, size_t gboff,
                                                   float* __restrict__ cw,
                                                   int* __restrict__ einfo,
                                                   float* __restrict__ w0a,
                                                   float* __restrict__ w1a,
                                                   const int* __restrict__ flag) {
  const int bf = flag[0];
  int lane = threadIdx.x & 63, wv = threadIdx.x >> 6;
  int t = blockIdx.x * 4 + wv;
  const float* xr = hbuf + (size_t)t * D_;
  float a[4] = {0, 0, 0, 0};
  for (int d = lane; d < D_; d += 64) {
    float xv = xr[d];
#pragma unroll
    for (int e = 0; e < 4; e++) a[e] += xv * ldin(gw, gwoff + e * D_ + d, bf);
  }
#pragma unroll
  for (int e = 0; e < 4; e++)
    for (int off = 32; off; off >>= 1) a[e] += __shfl_xor(a[e], off, 64);
  if (lane == 0) {
    float lg[4];
#pragma unroll
    for (int e = 0; e < 4; e++) lg[e] = a[e] + ldin(gb, gboff + e, bf);
    float m = fmaxf(fmaxf(lg[0], lg[1]), fmaxf(lg[2], lg[3]));
    float p[4], s = 0.f;
#pragma unroll
    for (int e = 0; e < 4; e++) { p[e] = __expf(lg[e] - m); s += p[e]; }
#pragma unroll
    for (int e = 0; e < 4; e++) p[e] /= s;
    int i0 = 0;
    for (int e = 1; e < 4; e++) if (p[e] > p[i0]) i0 = e;
    int i1 = -1;
    for (int e = 0; e < 4; e++) if (e != i0 && (i1 < 0 || p[e] > p[i1])) i1 = e;
    float s2 = p[i0] + p[i1];
    float ww0 = p[i0] / s2, ww1 = p[i1] / s2;
    float outw[4] = {0, 0, 0, 0};
    outw[i0] = ww0; outw[i1] = ww1;
#pragma unroll
    for (int e = 0; e < 4; e++) cw[t * 4 + e] = outw[e];
    einfo[t] = i0 | (i1 << 4);
    w0a[t] = ww0; w1a[t] = ww1;
  }
}

// ---------------- route scan: counts -> offsets + tile table (1 block) ----------------
__global__ __launch_bounds__(256) void route_scan_kernel(const int* __restrict__ einfo,
                                                         int* __restrict__ off,
                                                         int* __restrict__ endp,
                                                         int* __restrict__ cur,
                                                         int* __restrict__ tmap) {
  __shared__ int red[4][256];
  int tid = threadIdx.x;
  int c[4] = {0, 0, 0, 0};
  for (int t = tid; t < T_; t += 256) {
    int inf = einfo[t];
    c[inf & 15]++;
    c[(inf >> 4) & 15]++;
  }
#pragma unroll
  for (int e = 0; e < 4; e++) red[e][tid] = c[e];
  __syncthreads();
  for (int w = 128; w; w >>= 1) {
    if (tid < w)
#pragma unroll
      for (int e = 0; e < 4; e++) red[e][tid] += red[e][tid + w];
    __syncthreads();
  }
  if (tid == 0) {
    int o = 0, idx = 0;
#pragma unroll
    for (int e = 0; e < 4; e++) {
      int cnt = red[e][0];
      off[e] = o;
      endp[e] = o + cnt;
      cur[e] = 0;
      int nt = (cnt + 127) >> 7;
      for (int i = 0; i < nt; i++) tmap[1 + idx++] = e | (i << 8);
      o += nt << 7;
    }
    tmap[0] = idx;   // total active m-tiles (<= 131)
  }
}

// ---------------- scatter: token -> (expert bucket, rank), ballot-aggregated --------
__global__ __launch_bounds__(256) void scatter_kernel(const int* __restrict__ einfo,
                                                      const float* __restrict__ w0a,
                                                      const float* __restrict__ w1a,
                                                      const int* __restrict__ off,
                                                      int* __restrict__ cur,
                                                      int* __restrict__ pack,
                                                      float* __restrict__ wlist) {
  int t = blockIdx.x * 256 + threadIdx.x;
  int lane = threadIdx.x & 63;
  int inf = einfo[t];
#pragma unroll
  for (int rank = 0; rank < 2; rank++) {
    int my_e = (rank == 0) ? (inf & 15) : ((inf >> 4) & 15);
    float w = (rank == 0) ? w0a[t] : w1a[t];
#pragma unroll
    for (int e = 0; e < 4; e++) {
      bool p = (my_e == e);
      unsigned long long mask = __ballot(p);
      if (!mask) continue;
      int leader = __ffsll((long long)mask) - 1;
      int base = 0;
      if (lane == leader) base = atomicAdd(&cur[e], (int)__popcll(mask));
      base = __shfl(base, leader, 64);
      if (p) {
        int pos = off[e] + base + (int)__popcll(mask & ((1ULL << lane) - 1ULL));
        pack[pos] = t * 2 + rank;
        wlist[pos] = w;
      }
    }
  }
}

// ---------------- sparse MoE mat1: 128x256 tile (BK=32, dbuf, tile-table) -----------
// 32 MFMA per K-step; n-tiles = 4 (was 8); grid (4, 136).
__global__ __launch_bounds__(256) void moe_mat1_kernel(
    const bf16* __restrict__ A, const bf16* __restrict__ Wt,
    const void* __restrict__ bias, size_t boff, bf16* __restrict__ hid,
    const int* __restrict__ off, const int* __restrict__ endp,
    const int* __restrict__ pack, const float* __restrict__ wlist,
    const int* __restrict__ tmap, const int* __restrict__ flag) {
  const int wbf = flag[0];
  int id = blockIdx.x + 4 * blockIdx.y;
  int xcd = id & 7, idq = id >> 3;
  int wx = idq & 3, wy = xcd + 8 * (idq >> 2);
  if (wy >= tmap[0]) return;
  int ent = tmap[1 + wy];
  const int e = ent & 255, mt = ent >> 8;
  const int o = off[e], en = endp[e];
  const int n0 = wx * 256;
  __shared__ bf16 As[2][128][32];
  __shared__ bf16 Bs[2][256][32];
  const int tid = threadIdx.x;
  const int ln = tid & 63, wv = tid >> 6;
  const int m0 = o + mt * 128;
  const int wr = (wv >> 1) * 64, wc = (wv & 1) * 128;
  const int mrow = ln & 15, quad = ln >> 4;
  const int srow = ln >> 2;
  const int skof = (ln & 3) * 8;
  int tokr[2];
#pragma unroll
  for (int j = 0; j < 2; j++) {
    int pos = m0 + 16 * (4 * j + wv) + srow;
    tokr[j] = pack[min(pos, en - 1)] >> 1;
  }
  const size_t wbase = (size_t)e * 1024 * 512;

  auto stage = [&](int pb, int k0) {
#pragma unroll
    for (int j = 0; j < 2; j++)
      gload16(A + (size_t)tokr[j] * 512 + k0 + skof,
              (char*)&As[pb][0][0] + (size_t)(4 * j + wv) * 1024);
#pragma unroll
    for (int j = 0; j < 4; j++) {
      int row = 16 * (4 * j + wv) + srow;
      gload16(Wt + wbase + (size_t)(n0 + row) * 512 + k0 + skof,
              (char*)&Bs[pb][0][0] + (size_t)(4 * j + wv) * 1024);
    }
  };

  f32x4 acc[4][8];
#pragma unroll
  for (int i = 0; i < 4; i++)
#pragma unroll
    for (int j = 0; j < 8; j++) acc[i][j] = (f32x4){0.f, 0.f, 0.f, 0.f};

  stage(0, 0);
  int p = 0;
  for (int k0 = 0; k0 < 512; k0 += 32) {
    __syncthreads();
    if (k0 + 32 < 512) stage(p ^ 1, k0 + 32);
    short8 af[4], bfr[8];
#pragma unroll
    for (int t = 0; t < 4; t++) af[t] = *(const short8*)&As[p][wr + t * 16 + mrow][quad * 8];
#pragma unroll
    for (int t = 0; t < 8; t++) bfr[t] = *(const short8*)&Bs[p][wc + t * 16 + mrow][quad * 8];
#pragma unroll
    for (int i = 0; i < 4; i++)
#pragma unroll
      for (int j = 0; j < 8; j++)
        acc[i][j] = __builtin_amdgcn_mfma_f32_16x16x32_bf16(af[i], bfr[j], acc[i][j], 0, 0, 0);
    p ^= 1;
  }

#pragma unroll
  for (int ti = 0; ti < 4; ti++) {
#pragma unroll
    for (int r = 0; r < 4; r++) {
      int pos = m0 + wr + ti * 16 + quad * 4 + r;
      float w = (pos < en) ? wlist[pos] : 0.f;
#pragma unroll
      for (int tj = 0; tj < 8; tj++) {
        int ncol = n0 + wc + tj * 16 + mrow;
        float v = acc[ti][tj][r] + ldin(bias, boff + e * 1024 + ncol, wbf);
        hid[(size_t)pos * 1024 + ncol] = __float2bfloat16(fmaxf(v, 0.f) * w);
      }
    }
  }
}

// ---------------- sparse MoE mat2: 128x256 tile (BK=32, dbuf, split-K z=2) ----------
// n-tiles = 2 (N=512); grid (2, 136, 2).
__global__ __launch_bounds__(256) void moe_mat2_kernel(
    const bf16* __restrict__ hid, const bf16* __restrict__ Wt,
    bf16* __restrict__ psl,
    const int* __restrict__ off, const int* __restrict__ endp,
    const int* __restrict__ pack, const int* __restrict__ tmap,
    const int* __restrict__ flag) {
  int id = blockIdx.x + 2 * blockIdx.y;
  int xcd = id & 7, idq = id >> 3;
  int wx = idq & 1, wy = xcd + 8 * (idq >> 1);
  if (wy >= tmap[0]) return;
  int ent = tmap[1 + wy];
  const int e = ent & 255, mt = ent >> 8;
  const int o = off[e], en = endp[e];
  const int n0 = wx * 256;
  __shared__ bf16 As[2][128][32];
  __shared__ bf16 Bs[2][256][32];
  const int tid = threadIdx.x;
  const int ln = tid & 63, wv = tid >> 6;
  const int m0 = o + mt * 128;
  const int wr = (wv >> 1) * 64, wc = (wv & 1) * 128;
  const int mrow = ln & 15, quad = ln >> 4;
  const int srow = ln >> 2;
  const int skof = (ln & 3) * 8;
  const int kbeg = blockIdx.z * 512;
  const size_t wbase = (size_t)e * 512 * 1024;

  auto stage = [&](int pb, int k0) {
#pragma unroll
    for (int j = 0; j < 2; j++) {
      int row = 16 * (4 * j + wv) + srow;
      gload16(hid + (size_t)(m0 + row) * 1024 + k0 + skof,
              (char*)&As[pb][0][0] + (size_t)(4 * j + wv) * 1024);
    }
#pragma unroll
    for (int j = 0; j < 4; j++) {
      int row = 16 * (4 * j + wv) + srow;
      gload16(Wt + wbase + (size_t)(n0 + row) * 1024 + k0 + skof,
              (char*)&Bs[pb][0][0] + (size_t)(4 * j + wv) * 1024);
    }
  };

  f32x4 acc[4][8];
#pragma unroll
  for (int i = 0; i < 4; i++)
#pragma unroll
    for (int j = 0; j < 8; j++) acc[i][j] = (f32x4){0.f, 0.f, 0.f, 0.f};

  stage(0, kbeg);
  int p = 0;
  for (int k0 = kbeg; k0 < kbeg + 512; k0 += 32) {
    __syncthreads();
    if (k0 + 32 < kbeg + 512) stage(p ^ 1, k0 + 32);
    short8 af[4], bfr[8];
#pragma unroll
    for (int t = 0; t < 4; t++) af[t] = *(const short8*)&As[p][wr + t * 16 + mrow][quad * 8];
#pragma unroll
    for (int t = 0; t < 8; t++) bfr[t] = *(const short8*)&Bs[p][wc + t * 16 + mrow][quad * 8];
#pragma unroll
    for (int i = 0; i < 4; i++)
#pragma unroll
      for (int j = 0; j < 8; j++)
        acc[i][j] = __builtin_amdgcn_mfma_f32_16x16x32_bf16(af[i], bfr[j], acc[i][j], 0, 0, 0);
    p ^= 1;
  }

#pragma unroll
  for (int ti = 0; ti < 4; ti++) {
#pragma unroll
    for (int r = 0; r < 4; r++) {
      int pos = m0 + wr + ti * 16 + quad * 4 + r;
      if (pos < en) {
        int pk = pack[pos];
        int tok = pk >> 1, rank = pk & 1;
        bf16* dst = psl + (size_t)(rank * 2 + blockIdx.z) * T_ * D_ + (size_t)tok * D_;
#pragma unroll
        for (int tj = 0; tj < 8; tj++) {
          int ncol = n0 + wc + tj * 16 + mrow;
          dst[ncol] = __float2bfloat16(acc[ti][tj][r]);
        }
      }
    }
  }
}

// ---------------- head ----------------
__global__ __launch_bounds__(256) void head_kernel(const float* __restrict__ hbuf,
                                                   const void* __restrict__ hw,
                                                   const void* __restrict__ hb,
                                                   void* __restrict__ out,
                                                   const int* __restrict__ flag) {
  const int bf = flag[0];
  int bq = blockIdx.x, tid = threadIdx.x;
  int b = bq / 3, q = bq % 3;
  __shared__ float red[256];
  const float* xr = hbuf + (size_t)(b * S_ + (S_ - 1)) * D_;
  float sacc = xr[tid] * ldin(hw, (size_t)q * D_ + tid, bf)
             + xr[tid + 256] * ldin(hw, (size_t)q * D_ + tid + 256, bf);
  red[tid] = sacc; __syncthreads();
  for (int w = 128; w; w >>= 1) { if (tid < w) red[tid] += red[tid + w]; __syncthreads(); }
  if (tid == 0) {
    float r = red[0] + ldin(hb, q, bf);
    if (bf) ((bf16*)out)[bq] = __float2bfloat16(r);
    else    ((float*)out)[bq] = r;
  }
}

extern "C" void kernel_launch(void* const* d_in, const int* in_sizes, int n_in,
                              void* d_out, int out_size, void* d_ws, size_t ws_size,
                              hipStream_t stream) {
  const void* x    = d_in[0];
  const void* Wp   = d_in[1];
  const void* bp   = d_in[2];
  const void* femb = d_in[3];
  const void* qkvw = d_in[4];
  const void* qkvb = d_in[5];
  const void* ow   = d_in[6];
  const void* ob   = d_in[7];
  const void* g1   = d_in[8];
  const void* be1  = d_in[9];
  const void* gw   = d_in[10];
  const void* gb   = d_in[11];
  const void* ew1  = d_in[12];
  const void* eb1  = d_in[13];
  const void* ew2  = d_in[14];
  const void* eb2  = d_in[15];
  const void* g2   = d_in[16];
  const void* be2  = d_in[17];
  const void* hw   = d_in[18];
  const void* hb   = d_in[19];
  const int*  freq = (const int*)d_in[20];

  // workspace layout: peak ~99.6 MB (within previously proven-safe 101 MB)
  int*   flag  = (int*)d_ws;                        // 64 ints
  int*   off   = flag + 64;                         // 4
  int*   endp  = off + 4;                           // 4
  int*   cur   = endp + 4;                          // 4 (+pad)
  int*   einfo = flag + 128;                        // T ints
  float* w0a   = (float*)(einfo + T_);              // T
  float* w1a   = w0a + T_;                          // T
  int*   pack  = (int*)(w1a + T_);                  // CAP ints
  float* wlist = (float*)(pack + CAP_);             // CAP
  int*   tmap  = (int*)(wlist + CAP_);              // 160 ints (count + tiles)
  float* xn    = (float*)(tmap + 160);              // 65536
  float* h     = xn + 65536;                        // T*D f    (16 MB)
  float* cw    = h + (size_t)T_ * D_;               // T*4
  bf16*  hb16  = (bf16*)(cw + (size_t)T_ * E_);     // T*D bf16 (8 MB)
  bf16*  R     = hb16 + (size_t)T_ * D_;            // alias region
  bf16*  qkvb16 = R;                                // T*3D bf16 (24 MB)
  bf16*  ao    = R + (size_t)T_ * D3_;              // T*D bf16  (8 MB)
  bf16*  hid   = R;                                 // CAP*1024 bf16 (~33 MB)
  bf16*  psl   = R + (size_t)CAP_ * 1024;           // 4x T*D bf16 (32 MB partial slices)
  bf16*  wcvt  = psl + (size_t)4 * T_ * D_;         // 8.4 MB bf16 weight scratch
  bf16*  wq    = wcvt;
  bf16*  wo    = wcvt + (size_t)D3_ * D_;
  bf16*  we1   = wcvt;
  bf16*  we2   = wcvt + (size_t)E_ * 1024 * 512;
  float* addtab = (float*)R;                        // [S][D] f32 PE table (dead before QKV GEMM)

  constexpr size_t NQ = (size_t)D3_ * D_;           // 786432
  constexpr size_t NO = (size_t)D_ * D_;            // 262144
  constexpr size_t NE = (size_t)E_ * 1024 * 512;    // 2097152

  detect_kernel<<<1, 64, 0, stream>>>(x, flag);
  instnorm_kernel<<<B_ * F_, 256, 0, stream>>>(x, xn, flag);
  pe_kernel<<<(S_ * D_ / 2) / 256, 256, 0, stream>>>(bp, femb, freq, addtab, flag);
  input_proj_kernel<<<T_ / IPG_, 256, 0, stream>>>(xn, Wp, addtab, h, hb16, flag);

  for (int l = 0; l < 3; l++) {
    // convert this layer's qkv_w + ow to bf16 scratch (copy if already bf16)
    convw_kernel<<<(NQ + NO) / 2048, 256, 0, stream>>>(
        qkvw, (size_t)l * NQ, NQ, ow, (size_t)l * NO, wcvt, flag);
    // QKV projection -> bf16 (128x256 tile)
    mfma_gemm256<<<dim3(D3_ / 256, T_ / 128), 256, 0, stream>>>(
        hb16, wq, qkvb, (size_t)l * D3_, qkvb16, D_, D_, D_, D3_, flag);
    attn_kernel<<<B_ * H_ * (S_ / 64), 256, 0, stream>>>(qkvb16, ao);
    // O-projection: split-K=2 -> slices 0,1; fused reduce + bias + LN
    mfma_gemm<0><<<dim3(D_ / 128, T_ / 128, 2), 256, 0, stream>>>(
        ao, wo, nullptr, 0, psl, D_, D_, D_, D_, flag);
    reduce_ln_kernel<<<T_, 256, 0, stream>>>(
        h, hb16, psl, 2, 0, ob, (size_t)l * D_, nullptr, nullptr, 0,
        g1, be1, (size_t)l * D_, flag);
    // gating + routing
    gate_kernel<<<T_ / 4, 256, 0, stream>>>(h, gw, (size_t)l * E_ * D_, gb, (size_t)l * E_,
                                            cw, einfo, w0a, w1a, flag);
    route_scan_kernel<<<1, 256, 0, stream>>>(einfo, off, endp, cur, tmap);
    scatter_kernel<<<T_ / 256, 256, 0, stream>>>(einfo, w0a, w1a, off, cur, pack, wlist);
    // convert this layer's ew1 + ew2 to bf16 scratch (wq/wo dead past here)
    convw_kernel<<<(NE + NE) / 2048, 256, 0, stream>>>(
        ew1, (size_t)l * NE, NE, ew2, (size_t)l * NE, wcvt, flag);
    // sparse expert GEMMs (hid aliases qkv+ao, both dead here)
    moe_mat1_kernel<<<dim3(4, 136), 256, 0, stream>>>(
        hb16, we1, eb1, (size_t)l * E_ * 1024, hid,
        off, endp, pack, wlist, tmap, flag);
    moe_mat2_kernel<<<dim3(2, 136, 2), 256, 0, stream>>>(
        hid, we2, psl, off, endp, pack, tmap, flag);
    reduce_ln_kernel<<<T_, 256, 0, stream>>>(
        h, hb16, psl, 4, 1, nullptr, 0, cw, eb2, (size_t)l * E_ * D_,
        g2, be2, (size_t)l * D_, flag);
  }

  head_kernel<<<24, 256, 0, stream>>>(h, hw, hb, d_out, flag);
}

// Round 8
// 850.280 us; speedup vs baseline: 1.2878x; 1.2878x over previous
//
#include <hip/hip_runtime.h>
#include <hip/hip_bf16.h>
#include <math.h>

typedef __hip_bfloat16 bf16;
typedef __attribute__((ext_vector_type(8))) short short8;   // 8 bf16 (4 VGPRs)
typedef __attribute__((ext_vector_type(4))) short s4v;      // 4 bf16 (8 bytes)
typedef __attribute__((ext_vector_type(4))) float f32x4;

constexpr int B_ = 8, S_ = 1024, F_ = 8, D_ = 512, H_ = 8, E_ = 4;
constexpr int T_  = B_ * S_;       // 8192 tokens
constexpr int D3_ = 3 * D_;        // 1536
constexpr int CAP_ = T_ * 2 + E_ * 128;   // sparse row capacity (top-2, 128-pad/expert)

__device__ __forceinline__ float b2f(bf16 v) { return __bfloat162float(v); }
__device__ __forceinline__ float ldin(const void* p, size_t i, int bf) {
  return bf ? __bfloat162float(((const bf16*)p)[i]) : ((const float*)p)[i];
}
__device__ __forceinline__ void gload16(const void* g, void* l) {
  __builtin_amdgcn_global_load_lds((const __attribute__((address_space(1))) unsigned int*)g,
                                   (__attribute__((address_space(3))) unsigned int*)l, 16, 0, 0);
}

// ---------------- dtype detector ----------------
__global__ void detect_kernel(const void* __restrict__ x, int* __restrict__ flag) {
  if (threadIdx.x == 0 && blockIdx.x == 0) {
    const unsigned short* u = (const unsigned short*)x;
    int c = 0;
    for (int i = 0; i < 256; i += 2) {
      int ex = (u[i] >> 7) & 0xFF;
      if (ex >= 96 && ex <= 144) c++;
    }
    flag[0] = (c >= 64) ? 1 : 0;
  }
}

// ---------------- weight pre-convert: fp32 (or bf16 copy) -> bf16 scratch ----------
__global__ __launch_bounds__(256) void convw_kernel(const void* __restrict__ Asrc, size_t offA,
                                                    size_t nA,
                                                    const void* __restrict__ Bsrc, size_t offB,
                                                    bf16* __restrict__ dst,
                                                    const int* __restrict__ flag) {
  const int bf = flag[0];
  size_t i = ((size_t)blockIdx.x * 256 + threadIdx.x) * 8;
  const void* s = Asrc;
  size_t so = offA + i;
  if (i >= nA) { s = Bsrc; so = offB + (i - nA); }
  if (bf) {
    *(short8*)(dst + i) = *(const short8*)((const bf16*)s + so);
  } else {
    const float* sp = (const float*)s + so;
    short8 v;
#pragma unroll
    for (int u = 0; u < 8; u++) { bf16 t = __float2bfloat16(sp[u]); v[u] = *(short*)&t; }
    *(short8*)(dst + i) = v;
  }
}

// ---------------- instance norm over time axis ----------------
__global__ __launch_bounds__(256) void instnorm_kernel(const void* __restrict__ x,
                                                       float* __restrict__ xn,
                                                       const int* __restrict__ flag) {
  const int bf = flag[0];
  int b = blockIdx.x / F_, f = blockIdx.x % F_;
  int tid = threadIdx.x;
  __shared__ float red[256];
  const int base = b * S_ * F_ + f;
  float s = 0.f;
  for (int j = tid; j < S_; j += 256) s += ldin(x, base + j * F_, bf);
  red[tid] = s; __syncthreads();
  for (int w = 128; w; w >>= 1) { if (tid < w) red[tid] += red[tid + w]; __syncthreads(); }
  float mean = red[0] / S_;
  __syncthreads();
  float v = 0.f;
  for (int j = tid; j < S_; j += 256) { float d = ldin(x, base + j * F_, bf) - mean; v += d * d; }
  red[tid] = v; __syncthreads();
  for (int w = 128; w; w >>= 1) { if (tid < w) red[tid] += red[tid + w]; __syncthreads(); }
  float inv = 1.f / (sqrtf(red[0] / (float)(S_ - 1)) + 1e-5f);
  for (int j = tid; j < S_; j += 256) xn[base + j * F_] = (ldin(x, base + j * F_, bf) - mean) * inv;
}

// ---------------- positional-encoding + bias + freq-emb add-table [S][D] -----------
__global__ __launch_bounds__(256) void pe_kernel(const void* __restrict__ bp,
                                                 const void* __restrict__ femb,
                                                 const int* __restrict__ freq_idx,
                                                 float* __restrict__ addtab,
                                                 const int* __restrict__ flag) {
  const int bf = flag[0];
  int idx = blockIdx.x * 256 + threadIdx.x;      // S*D/2 threads
  int dp = idx & (D_ / 2 - 1);
  int s  = idx / (D_ / 2);
  int d0 = dp * 2;
  int fi = freq_idx[0];
  const float cexp = -9.2103403719761836f / (float)D_;
  float ang = (float)s * expf((float)d0 * cexp);
  float sv, cv;
  sincosf(ang, &sv, &cv);
  addtab[(size_t)s * D_ + d0]     = sv + ldin(bp, d0, bf)     + ldin(femb, (size_t)fi * D_ + d0, bf);
  addtab[(size_t)s * D_ + d0 + 1] = cv + ldin(bp, d0 + 1, bf) + ldin(femb, (size_t)fi * D_ + d0 + 1, bf);
}

// ---------------- input projection: xn @ Wp^T + addtab -----------------------------
constexpr int IPG_ = 8;   // tokens per block
__global__ __launch_bounds__(256) void input_proj_kernel(const float* __restrict__ xn,
                                                         const void* __restrict__ Wp,
                                                         const float* __restrict__ addtab,
                                                         float* __restrict__ h,
                                                         bf16* __restrict__ hb16,
                                                         const int* __restrict__ flag) {
  const int bf = flag[0];
  const int tid = threadIdx.x;
  const int d0 = tid * 2;
  const int tbase = blockIdx.x * IPG_;
  float wp0[8], wp1[8];
  if (bf) {
    short8 w0 = *(const short8*)((const bf16*)Wp + (size_t)d0 * F_);
    short8 w1 = *(const short8*)((const bf16*)Wp + (size_t)(d0 + 1) * F_);
#pragma unroll
    for (int f = 0; f < 8; f++) {
      unsigned short u0 = (unsigned short)w0[f], u1 = (unsigned short)w1[f];
      wp0[f] = __bfloat162float(*(bf16*)&u0);
      wp1[f] = __bfloat162float(*(bf16*)&u1);
    }
  } else {
    const float* wpf = (const float*)Wp + (size_t)d0 * F_;
    f32x4 a = *(const f32x4*)(wpf);
    f32x4 b = *(const f32x4*)(wpf + 4);
    f32x4 c = *(const f32x4*)(wpf + 8);
    f32x4 d = *(const f32x4*)(wpf + 12);
#pragma unroll
    for (int f = 0; f < 4; f++) { wp0[f] = a[f]; wp0[4 + f] = b[f]; wp1[f] = c[f]; wp1[4 + f] = d[f]; }
  }
#pragma unroll
  for (int g = 0; g < IPG_; g++) {
    int t = tbase + g;
    int s = t & (S_ - 1);
    const float* xr = xn + (size_t)t * F_;
    f32x4 x0 = *(const f32x4*)xr;
    f32x4 x1 = *(const f32x4*)(xr + 4);
    const float2 at = *(const float2*)(addtab + (size_t)s * D_ + d0);
    float a0 = at.x, a1 = at.y;
#pragma unroll
    for (int f = 0; f < 4; f++) { a0 += x0[f] * wp0[f]; a1 += x0[f] * wp1[f]; }
#pragma unroll
    for (int f = 0; f < 4; f++) { a0 += x1[f] * wp0[4 + f]; a1 += x1[f] * wp1[4 + f]; }
    *(float2*)(h + (size_t)t * D_ + d0) = make_float2(a0, a1);
    bf16 b0 = __float2bfloat16(a0), b1 = __float2bfloat16(a1);
    unsigned pk = (unsigned)(*(unsigned short*)&b0) | ((unsigned)(*(unsigned short*)&b1) << 16);
    *(unsigned*)(hb16 + (size_t)t * D_ + d0) = pk;
  }
}

// ---------------- dense MFMA GEMM, 128x128, 3-stage counted-vmcnt pipeline ----------
// T3/T4: raw s_barrier + vmcnt(4) (one stage = 4 global_load_lds per wave stays in
// flight across the barrier; each stage has 2 iterations to land). WAR-safe: buffer
// written at step s+2 was last read at step s; writes issue only after barrier s+2,
// which every wave reaches only after its step-s ds_reads were consumed by MFMA.
// MODE 3: C bf16 = acc + bias (QKV). MODE 0: partial bf16 slice per z (O-proj).
template <int MODE>
__global__ __launch_bounds__(256) void mfma_gemm(
    const bf16* __restrict__ A, const bf16* __restrict__ Wt,
    const void* __restrict__ bias, size_t boff, void* __restrict__ C_,
    int Kd, int lda, int ldb, int ldc, const int* __restrict__ flag) {
  const int wbf = flag[0];
  __shared__ bf16 As[3][128][32];
  __shared__ bf16 Bs[3][128][32];
  const int tid = threadIdx.x;
  const int ln = tid & 63, wv = tid >> 6;
  int id = blockIdx.x + gridDim.x * blockIdx.y;
  int xcd = id & 7, idq = id >> 3;
  const int n0 = (idq % gridDim.x) * 128;
  const int m0 = (xcd + 8 * (idq / gridDim.x)) * 128;
  const int wr = (wv >> 1) * 64, wc = (wv & 1) * 64;
  const int mrow = ln & 15, quad = ln >> 4;
  const int srow = ln >> 2;
  const int skof = (ln & 3) * 8;
  const int kchunk = Kd / gridDim.z;
  const int kbeg = blockIdx.z * kchunk;
  const int kend = kbeg + kchunk;

  auto stage = [&](int pb, int k0) {
#pragma unroll
    for (int j = 0; j < 2; j++) {
      int row = 16 * (4 * j + wv) + srow;
      gload16(A + (size_t)(m0 + row) * lda + k0 + skof,
              (char*)&As[pb][0][0] + (size_t)(4 * j + wv) * 1024);
    }
#pragma unroll
    for (int j = 0; j < 2; j++) {
      int row = 16 * (4 * j + wv) + srow;
      gload16(Wt + (size_t)(n0 + row) * ldb + k0 + skof,
              (char*)&Bs[pb][0][0] + (size_t)(4 * j + wv) * 1024);
    }
  };

  f32x4 acc[4][4];
#pragma unroll
  for (int i = 0; i < 4; i++)
#pragma unroll
    for (int j = 0; j < 4; j++) acc[i][j] = (f32x4){0.f, 0.f, 0.f, 0.f};

  stage(0, kbeg);
  stage(1, kbeg + 32);
  int p = 0;
  for (int k0 = kbeg; k0 < kend; k0 += 32) {
    if (k0 + 32 < kend) asm volatile("s_waitcnt vmcnt(4)" ::: "memory");
    else                asm volatile("s_waitcnt vmcnt(0)" ::: "memory");
    __builtin_amdgcn_s_barrier();
    __builtin_amdgcn_sched_barrier(0);
    short8 af[4], bfr[4];
#pragma unroll
    for (int t = 0; t < 4; t++) {
      af[t]  = *(const short8*)&As[p][wr + t * 16 + mrow][quad * 8];
      bfr[t] = *(const short8*)&Bs[p][wc + t * 16 + mrow][quad * 8];
    }
    if (k0 + 64 < kend) {
      int ps = (p == 0) ? 2 : p - 1;   // (p+2)%3
      stage(ps, k0 + 64);
    }
#pragma unroll
    for (int i = 0; i < 4; i++)
#pragma unroll
      for (int j = 0; j < 4; j++)
        acc[i][j] = __builtin_amdgcn_mfma_f32_16x16x32_bf16(af[i], bfr[j], acc[i][j], 0, 0, 0);
    p = (p == 2) ? 0 : p + 1;
  }

  bf16* slice = (MODE == 0) ? (bf16*)C_ + (size_t)blockIdx.z * T_ * D_ : (bf16*)C_;
#pragma unroll
  for (int tj = 0; tj < 4; tj++) {
    int n = n0 + wc + tj * 16 + mrow;
    float bv = (MODE == 3) ? ldin(bias, boff + n, wbf) : 0.f;
#pragma unroll
    for (int ti = 0; ti < 4; ti++) {
      int mbase = m0 + wr + ti * 16 + quad * 4;
#pragma unroll
      for (int r = 0; r < 4; r++) {
        int m = mbase + r;
        float v = acc[ti][tj][r];
        slice[(size_t)m * ldc + n] = __float2bfloat16(MODE == 3 ? v + bv : v);
      }
    }
  }
}

// ---------------- MFMA flash attention: 64-query tile, swapped QK^T softmax --------
__global__ __launch_bounds__(256) void attn_kernel(const bf16* __restrict__ qkv,
                                                   bf16* __restrict__ o) {
  __shared__ bf16 QP[64][72];    // Q tile, then P tile (aliased; rows wv*16.. wave-private)
  __shared__ bf16 Ks[64][72];
  __shared__ bf16 Vt[64][72];    // [d][k ^ swz(d)]
  const int tid = threadIdx.x;
  const int ln = tid & 63, wv = tid >> 6;
  const int mrow = ln & 15, quad = ln >> 4;
  const int id = blockIdx.x;
  const int xcd = id & 7, j = id >> 3;
  const int qt = j & 15;
  const int pr = xcd + 8 * (j >> 4);     // 0..63
  const int hh = pr & 7, b = pr >> 3;
  const int q0 = qt * 64;
  const int sr = tid >> 2;
  const int sg = tid & 3;
  const int sc = sg * 8;

  {
    const bf16* src = qkv + (size_t)(b * S_ + q0 + sr) * D3_ + hh * 64;
    *(short8*)&QP[sr][sc]      = *(const short8*)(src + sc);
    *(short8*)&QP[sr][sc + 32] = *(const short8*)(src + sc + 32);
  }
  __syncthreads();
  short8 aq[2];
  aq[0] = *(const short8*)&QP[wv * 16 + mrow][quad * 8];
  aq[1] = *(const short8*)&QP[wv * 16 + mrow][quad * 8 + 32];

  float m_st = -1e30f, l_st = 0.f;
  f32x4 oacc[4];
#pragma unroll
  for (int t = 0; t < 4; t++) oacc[t] = (f32x4){0.f, 0.f, 0.f, 0.f};

  for (int kt = 0; kt < 16; kt++) {
    int k0 = kt * 64;
    __syncthreads();
    {
      const bf16* src = qkv + (size_t)(b * S_ + k0 + sr) * D3_ + D_ + hh * 64;
      *(short8*)&Ks[sr][sc]      = *(const short8*)(src + sc);
      *(short8*)&Ks[sr][sc + 32] = *(const short8*)(src + sc + 32);
    }
    {
      const bf16* src = qkv + (size_t)(b * S_ + k0 + sr) * D3_ + 2 * D_ + hh * 64;
      short8 v0 = *(const short8*)(src + sc);
      short8 v1 = *(const short8*)(src + sc + 32);
      int col0 = sr ^ (sg << 4);
      int col1 = sr ^ (((sg + 4) & 3) << 4);
#pragma unroll
      for (int u = 0; u < 8; u++) {
        *(short*)&Vt[sc + u][col0]      = v0[u];
        *(short*)&Vt[sc + 32 + u][col1] = v1[u];
      }
    }
    __syncthreads();
    f32x4 s[4];
#pragma unroll
    for (int t = 0; t < 4; t++) {
      s[t] = (f32x4){0.f, 0.f, 0.f, 0.f};
#pragma unroll
      for (int ks = 0; ks < 2; ks++) {
        short8 bk = *(const short8*)&Ks[t * 16 + mrow][quad * 8 + ks * 32];
        s[t] = __builtin_amdgcn_mfma_f32_16x16x32_bf16(bk, aq[ks], s[t], 0, 0, 0);
      }
    }
    float rm = s[0][0];
#pragma unroll
    for (int t = 0; t < 4; t++)
#pragma unroll
      for (int r = 0; r < 4; r++) rm = fmaxf(rm, s[t][r]);
    rm *= 0.125f;
    rm = fmaxf(rm, __shfl_xor(rm, 16, 64));
    rm = fmaxf(rm, __shfl_xor(rm, 32, 64));
    float mnew = fmaxf(m_st, rm);
    float alpha = __expf(m_st - mnew);
    m_st = mnew;
    float rs = 0.f;
#pragma unroll
    for (int t = 0; t < 4; t++) {
      s4v pk;
#pragma unroll
      for (int r = 0; r < 4; r++) {
        float p = __expf(s[t][r] * 0.125f - mnew);
        rs += p;
        bf16 tb = __float2bfloat16(p);
        pk[r] = *(short*)&tb;
      }
      *(s4v*)&QP[wv * 16 + mrow][t * 16 + quad * 4] = pk;
    }
    rs += __shfl_xor(rs, 16, 64);
    rs += __shfl_xor(rs, 32, 64);
    l_st = l_st * alpha + rs;
    float af4[4];
#pragma unroll
    for (int r = 0; r < 4; r++) af4[r] = __shfl(alpha, quad * 4 + r, 64);
#pragma unroll
    for (int t = 0; t < 4; t++)
#pragma unroll
      for (int r = 0; r < 4; r++) oacc[t][r] *= af4[r];
    short8 ap[2];
    ap[0] = *(const short8*)&QP[wv * 16 + mrow][quad * 8];
    ap[1] = *(const short8*)&QP[wv * 16 + mrow][quad * 8 + 32];
#pragma unroll
    for (int t = 0; t < 4; t++) {
      int d = t * 16 + mrow;
      int swz = ((d >> 3) & 3) << 4;
#pragma unroll
      for (int ks = 0; ks < 2; ks++) {
        short8 bv = *(const short8*)&Vt[d][(quad * 8 + ks * 32) ^ swz];
        oacc[t] = __builtin_amdgcn_mfma_f32_16x16x32_bf16(ap[ks], bv, oacc[t], 0, 0, 0);
      }
    }
  }
  float linv[4];
#pragma unroll
  for (int r = 0; r < 4; r++) linv[r] = 1.f / __shfl(l_st, quad * 4 + r, 64);
#pragma unroll
  for (int r = 0; r < 4; r++) {
    size_t base = (size_t)(b * S_ + q0 + wv * 16 + quad * 4 + r) * D_ + hh * 64;
#pragma unroll
    for (int t = 0; t < 4; t++)
      o[base + t * 16 + mrow] = __float2bfloat16(oacc[t][r] * linv[r]);
  }
}

// ---------------- fused: sum partial slices + bias + residual + LayerNorm ----------
__global__ __launch_bounds__(256) void reduce_ln_kernel(float* __restrict__ h,
                                                        bf16* __restrict__ hb16,
                                                        const bf16* __restrict__ ps,
                                                        int nsl, int mode,
                                                        const void* __restrict__ bias,
                                                        size_t boff,
                                                        const float* __restrict__ cw,
                                                        const void* __restrict__ eb2p,
                                                        size_t e2off,
                                                        const void* __restrict__ g,
                                                        const void* __restrict__ beta,
                                                        size_t off,
                                                        const int* __restrict__ flag) {
  const int bf = flag[0];
  int t = blockIdx.x, tid = threadIdx.x;
  __shared__ float r1[256], r2[256];
  const size_t base = (size_t)t * D_;
  float o0 = 0.f, o1 = 0.f;
  for (int s = 0; s < nsl; s++) {
    o0 += b2f(ps[(size_t)s * T_ * D_ + base + tid]);
    o1 += b2f(ps[(size_t)s * T_ * D_ + base + tid + 256]);
  }
  if (mode == 0) {
    o0 += ldin(bias, boff + tid, bf);
    o1 += ldin(bias, boff + tid + 256, bf);
  } else {
#pragma unroll
    for (int e = 0; e < 4; e++) {
      float w = cw[t * 4 + e];
      o0 += w * ldin(eb2p, e2off + e * D_ + tid, bf);
      o1 += w * ldin(eb2p, e2off + e * D_ + tid + 256, bf);
    }
  }
  float* hr = h + base;
  float v0 = hr[tid] + o0;
  float v1 = hr[tid + 256] + o1;
  r1[tid] = v0 + v1;
  r2[tid] = v0 * v0 + v1 * v1;
  __syncthreads();
  for (int w = 128; w; w >>= 1) { if (tid < w) { r1[tid] += r1[tid + w]; r2[tid] += r2[tid + w]; } __syncthreads(); }
  float mean = r1[0] * (1.f / D_);
  float var  = r2[0] * (1.f / D_) - mean * mean;
  float rstd = rsqrtf(var + 1e-5f);
  float n0 = (v0 - mean) * rstd * ldin(g, off + tid, bf) + ldin(beta, off + tid, bf);
  float n1 = (v1 - mean) * rstd * ldin(g, off + tid + 256, bf) + ldin(beta, off + tid + 256, bf);
  hr[tid] = n0;
  hr[tid + 256] = n1;
  hb16[base + tid] = __float2bfloat16(n0);
  hb16[base + tid + 256] = __float2bfloat16(n1);
}

// ---------------- MoE gating: softmax over E=4, top-2; emits routing info ----------
__global__ __launch_bounds__(256) void gate_kernel(const float* __restrict__ hbuf,
                                                   const void* __restrict__ gw, size_t gwoff,
                                                   const void* __restrict__ gb, size_t gboff,
                                                   float* __restrict__ cw,
                                                   int* __restrict__ einfo,
                                                   float* __restrict__ w0a,
                                                   float* __restrict__ w1a,
                                                   const int* __restrict__ flag) {
  const int bf = flag[0];
  int lane = threadIdx.x & 63, wv = threadIdx.x >> 6;
  int t = blockIdx.x * 4 + wv;
  const float* xr = hbuf + (size_t)t * D_;
  float a[4] = {0, 0, 0, 0};
  for (int d = lane; d < D_; d += 64) {
    float xv = xr[d];
#pragma unroll
    for (int e = 0; e < 4; e++) a[e] += xv * ldin(gw, gwoff + e * D_ + d, bf);
  }
#pragma unroll
  for (int e = 0; e < 4; e++)
    for (int off = 32; off; off >>= 1) a[e] += __shfl_xor(a[e], off, 64);
  if (lane == 0) {
    float lg[4];
#pragma unroll
    for (int e = 0; e < 4; e++) lg[e] = a[e] + ldin(gb, gboff + e, bf);
    float m = fmaxf(fmaxf(lg[0], lg[1]), fmaxf(lg[2], lg[3]));
    float p[4], s = 0.f;
#pragma unroll
    for (int e = 0; e < 4; e++) { p[e] = __expf(lg[e] - m); s += p[e]; }
#pragma unroll
    for (int e = 0; e < 4; e++) p[e] /= s;
    int i0 = 0;
    for (int e = 1; e < 4; e++) if (p[e] > p[i0]) i0 = e;
    int i1 = -1;
    for (int e = 0; e < 4; e++) if (e != i0 && (i1 < 0 || p[e] > p[i1])) i1 = e;
    float s2 = p[i0] + p[i1];
    float ww0 = p[i0] / s2, ww1 = p[i1] / s2;
    float outw[4] = {0, 0, 0, 0};
    outw[i0] = ww0; outw[i1] = ww1;
#pragma unroll
    for (int e = 0; e < 4; e++) cw[t * 4 + e] = outw[e];
    einfo[t] = i0 | (i1 << 4);
    w0a[t] = ww0; w1a[t] = ww1;
  }
}

// ---------------- route scan: counts -> offsets + tile table (1 block) ----------------
__global__ __launch_bounds__(256) void route_scan_kernel(const int* __restrict__ einfo,
                                                         int* __restrict__ off,
                                                         int* __restrict__ endp,
                                                         int* __restrict__ cur,
                                                         int* __restrict__ tmap) {
  __shared__ int red[4][256];
  int tid = threadIdx.x;
  int c[4] = {0, 0, 0, 0};
  for (int t = tid; t < T_; t += 256) {
    int inf = einfo[t];
    c[inf & 15]++;
    c[(inf >> 4) & 15]++;
  }
#pragma unroll
  for (int e = 0; e < 4; e++) red[e][tid] = c[e];
  __syncthreads();
  for (int w = 128; w; w >>= 1) {
    if (tid < w)
#pragma unroll
      for (int e = 0; e < 4; e++) red[e][tid] += red[e][tid + w];
    __syncthreads();
  }
  if (tid == 0) {
    int o = 0, idx = 0;
#pragma unroll
    for (int e = 0; e < 4; e++) {
      int cnt = red[e][0];
      off[e] = o;
      endp[e] = o + cnt;
      cur[e] = 0;
      int nt = (cnt + 127) >> 7;
      for (int i = 0; i < nt; i++) tmap[1 + idx++] = e | (i << 8);
      o += nt << 7;
    }
    tmap[0] = idx;   // total active m-tiles (<= 131)
  }
}

// ---------------- scatter: token -> (expert bucket, rank), ballot-aggregated --------
__global__ __launch_bounds__(256) void scatter_kernel(const int* __restrict__ einfo,
                                                      const float* __restrict__ w0a,
                                                      const float* __restrict__ w1a,
                                                      const int* __restrict__ off,
                                                      int* __restrict__ cur,
                                                      int* __restrict__ pack,
                                                      float* __restrict__ wlist) {
  int t = blockIdx.x * 256 + threadIdx.x;
  int lane = threadIdx.x & 63;
  int inf = einfo[t];
#pragma unroll
  for (int rank = 0; rank < 2; rank++) {
    int my_e = (rank == 0) ? (inf & 15) : ((inf >> 4) & 15);
    float w = (rank == 0) ? w0a[t] : w1a[t];
#pragma unroll
    for (int e = 0; e < 4; e++) {
      bool p = (my_e == e);
      unsigned long long mask = __ballot(p);
      if (!mask) continue;
      int leader = __ffsll((long long)mask) - 1;
      int base = 0;
      if (lane == leader) base = atomicAdd(&cur[e], (int)__popcll(mask));
      base = __shfl(base, leader, 64);
      if (p) {
        int pos = off[e] + base + (int)__popcll(mask & ((1ULL << lane) - 1ULL));
        pack[pos] = t * 2 + rank;
        wlist[pos] = w;
      }
    }
  }
}

// ---------------- sparse MoE mat1: 128x128, 3-stage counted-vmcnt pipeline ----------
__global__ __launch_bounds__(256) void moe_mat1_kernel(
    const bf16* __restrict__ A, const bf16* __restrict__ Wt,
    const void* __restrict__ bias, size_t boff, bf16* __restrict__ hid,
    const int* __restrict__ off, const int* __restrict__ endp,
    const int* __restrict__ pack, const float* __restrict__ wlist,
    const int* __restrict__ tmap, const int* __restrict__ flag) {
  const int wbf = flag[0];
  int id = blockIdx.x + 8 * blockIdx.y;
  int xcd = id & 7, idq = id >> 3;
  int wx = idq & 7, wy = xcd + 8 * (idq >> 3);
  if (wy >= tmap[0]) return;
  int ent = tmap[1 + wy];
  const int e = ent & 255, mt = ent >> 8;
  const int o = off[e], en = endp[e];
  const int n0 = wx * 128;
  __shared__ bf16 As[3][128][32];
  __shared__ bf16 Bs[3][128][32];
  const int tid = threadIdx.x;
  const int ln = tid & 63, wv = tid >> 6;
  const int m0 = o + mt * 128;
  const int wr = (wv >> 1) * 64, wc = (wv & 1) * 64;
  const int mrow = ln & 15, quad = ln >> 4;
  const int srow = ln >> 2;
  const int skof = (ln & 3) * 8;
  int tokr[2];
#pragma unroll
  for (int j = 0; j < 2; j++) {
    int pos = m0 + 16 * (4 * j + wv) + srow;
    tokr[j] = pack[min(pos, en - 1)] >> 1;
  }
  const size_t wbase = (size_t)e * 1024 * 512;

  auto stage = [&](int pb, int k0) {
#pragma unroll
    for (int j = 0; j < 2; j++)
      gload16(A + (size_t)tokr[j] * 512 + k0 + skof,
              (char*)&As[pb][0][0] + (size_t)(4 * j + wv) * 1024);
#pragma unroll
    for (int j = 0; j < 2; j++) {
      int row = 16 * (4 * j + wv) + srow;
      gload16(Wt + wbase + (size_t)(n0 + row) * 512 + k0 + skof,
              (char*)&Bs[pb][0][0] + (size_t)(4 * j + wv) * 1024);
    }
  };

  f32x4 acc[4][4];
#pragma unroll
  for (int i = 0; i < 4; i++)
#pragma unroll
    for (int j = 0; j < 4; j++) acc[i][j] = (f32x4){0.f, 0.f, 0.f, 0.f};

  stage(0, 0);
  stage(1, 32);
  int p = 0;
  for (int k0 = 0; k0 < 512; k0 += 32) {
    if (k0 + 32 < 512) asm volatile("s_waitcnt vmcnt(4)" ::: "memory");
    else               asm volatile("s_waitcnt vmcnt(0)" ::: "memory");
    __builtin_amdgcn_s_barrier();
    __builtin_amdgcn_sched_barrier(0);
    short8 af[4], bfr[4];
#pragma unroll
    for (int t = 0; t < 4; t++) {
      af[t]  = *(const short8*)&As[p][wr + t * 16 + mrow][quad * 8];
      bfr[t] = *(const short8*)&Bs[p][wc + t * 16 + mrow][quad * 8];
    }
    if (k0 + 64 < 512) {
      int ps = (p == 0) ? 2 : p - 1;
      stage(ps, k0 + 64);
    }
#pragma unroll
    for (int i = 0; i < 4; i++)
#pragma unroll
      for (int j = 0; j < 4; j++)
        acc[i][j] = __builtin_amdgcn_mfma_f32_16x16x32_bf16(af[i], bfr[j], acc[i][j], 0, 0, 0);
    p = (p == 2) ? 0 : p + 1;
  }

#pragma unroll
  for (int ti = 0; ti < 4; ti++) {
#pragma unroll
    for (int r = 0; r < 4; r++) {
      int pos = m0 + wr + ti * 16 + quad * 4 + r;
      float w = (pos < en) ? wlist[pos] : 0.f;
#pragma unroll
      for (int tj = 0; tj < 4; tj++) {
        int ncol = n0 + wc + tj * 16 + mrow;
        float v = acc[ti][tj][r] + ldin(bias, boff + e * 1024 + ncol, wbf);
        hid[(size_t)pos * 1024 + ncol] = __float2bfloat16(fmaxf(v, 0.f) * w);
      }
    }
  }
}

// ---------------- sparse MoE mat2: 128x128, 3-stage counted-vmcnt pipeline, z=2 -----
__global__ __launch_bounds__(256) void moe_mat2_kernel(
    const bf16* __restrict__ hid, const bf16* __restrict__ Wt,
    bf16* __restrict__ psl,
    const int* __restrict__ off, const int* __restrict__ endp,
    const int* __restrict__ pack, const int* __restrict__ tmap,
    const int* __restrict__ flag) {
  int id = blockIdx.x + 4 * blockIdx.y;
  int xcd = id & 7, idq = id >> 3;
  int wx = idq & 3, wy = xcd + 8 * (idq >> 2);
  if (wy >= tmap[0]) return;
  int ent = tmap[1 + wy];
  const int e = ent & 255, mt = ent >> 8;
  const int o = off[e], en = endp[e];
  const int n0 = wx * 128;
  __shared__ bf16 As[3][128][32];
  __shared__ bf16 Bs[3][128][32];
  const int tid = threadIdx.x;
  const int ln = tid & 63, wv = tid >> 6;
  const int m0 = o + mt * 128;
  const int wr = (wv >> 1) * 64, wc = (wv & 1) * 64;
  const int mrow = ln & 15, quad = ln >> 4;
  const int srow = ln >> 2;
  const int skof = (ln & 3) * 8;
  const int kbeg = blockIdx.z * 512;
  const size_t wbase = (size_t)e * 512 * 1024;

  auto stage = [&](int pb, int k0) {
#pragma unroll
    for (int j = 0; j < 2; j++) {
      int row = 16 * (4 * j + wv) + srow;
      gload16(hid + (size_t)(m0 + row) * 1024 + k0 + skof,
              (char*)&As[pb][0][0] + (size_t)(4 * j + wv) * 1024);
    }
#pragma unroll
    for (int j = 0; j < 2; j++) {
      int row = 16 * (4 * j + wv) + srow;
      gload16(Wt + wbase + (size_t)(n0 + row) * 1024 + k0 + skof,
              (char*)&Bs[pb][0][0] + (size_t)(4 * j + wv) * 1024);
    }
  };

  f32x4 acc[4][4];
#pragma unroll
  for (int i = 0; i < 4; i++)
#pragma unroll
    for (int j = 0; j < 4; j++) acc[i][j] = (f32x4){0.f, 0.f, 0.f, 0.f};

  stage(0, kbeg);
  stage(1, kbeg + 32);
  int p = 0;
  for (int k0 = kbeg; k0 < kbeg + 512; k0 += 32) {
    if (k0 + 32 < kbeg + 512) asm volatile("s_waitcnt vmcnt(4)" ::: "memory");
    else                      asm volatile("s_waitcnt vmcnt(0)" ::: "memory");
    __builtin_amdgcn_s_barrier();
    __builtin_amdgcn_sched_barrier(0);
    short8 af[4], bfr[4];
#pragma unroll
    for (int t = 0; t < 4; t++) {
      af[t]  = *(const short8*)&As[p][wr + t * 16 + mrow][quad * 8];
      bfr[t] = *(const short8*)&Bs[p][wc + t * 16 + mrow][quad * 8];
    }
    if (k0 + 64 < kbeg + 512) {
      int ps = (p == 0) ? 2 : p - 1;
      stage(ps, k0 + 64);
    }
#pragma unroll
    for (int i = 0; i < 4; i++)
#pragma unroll
      for (int j = 0; j < 4; j++)
        acc[i][j] = __builtin_amdgcn_mfma_f32_16x16x32_bf16(af[i], bfr[j], acc[i][j], 0, 0, 0);
    p = (p == 2) ? 0 : p + 1;
  }

#pragma unroll
  for (int ti = 0; ti < 4; ti++) {
#pragma unroll
    for (int r = 0; r < 4; r++) {
      int pos = m0 + wr + ti * 16 + quad * 4 + r;
      if (pos < en) {
        int pk = pack[pos];
        int tok = pk >> 1, rank = pk & 1;
        bf16* dst = psl + (size_t)(rank * 2 + blockIdx.z) * T_ * D_ + (size_t)tok * D_;
#pragma unroll
        for (int tj = 0; tj < 4; tj++) {
          int ncol = n0 + wc + tj * 16 + mrow;
          dst[ncol] = __float2bfloat16(acc[ti][tj][r]);
        }
      }
    }
  }
}

// ---------------- head ----------------
__global__ __launch_bounds__(256) void head_kernel(const float* __restrict__ hbuf,
                                                   const void* __restrict__ hw,
                                                   const void* __restrict__ hb,
                                                   void* __restrict__ out,
                                                   const int* __restrict__ flag) {
  const int bf = flag[0];
  int bq = blockIdx.x, tid = threadIdx.x;
  int b = bq / 3, q = bq % 3;
  __shared__ float red[256];
  const float* xr = hbuf + (size_t)(b * S_ + (S_ - 1)) * D_;
  float sacc = xr[tid] * ldin(hw, (size_t)q * D_ + tid, bf)
             + xr[tid + 256] * ldin(hw, (size_t)q * D_ + tid + 256, bf);
  red[tid] = sacc; __syncthreads();
  for (int w = 128; w; w >>= 1) { if (tid < w) red[tid] += red[tid + w]; __syncthreads(); }
  if (tid == 0) {
    float r = red[0] + ldin(hb, q, bf);
    if (bf) ((bf16*)out)[bq] = __float2bfloat16(r);
    else    ((float*)out)[bq] = r;
  }
}

extern "C" void kernel_launch(void* const* d_in, const int* in_sizes, int n_in,
                              void* d_out, int out_size, void* d_ws, size_t ws_size,
                              hipStream_t stream) {
  const void* x    = d_in[0];
  const void* Wp   = d_in[1];
  const void* bp   = d_in[2];
  const void* femb = d_in[3];
  const void* qkvw = d_in[4];
  const void* qkvb = d_in[5];
  const void* ow   = d_in[6];
  const void* ob   = d_in[7];
  const void* g1   = d_in[8];
  const void* be1  = d_in[9];
  const void* gw   = d_in[10];
  const void* gb   = d_in[11];
  const void* ew1  = d_in[12];
  const void* eb1  = d_in[13];
  const void* ew2  = d_in[14];
  const void* eb2  = d_in[15];
  const void* g2   = d_in[16];
  const void* be2  = d_in[17];
  const void* hw   = d_in[18];
  const void* hb   = d_in[19];
  const int*  freq = (const int*)d_in[20];

  // workspace layout: peak ~99.6 MB (within previously proven-safe 101 MB)
  int*   flag  = (int*)d_ws;                        // 64 ints
  int*   off   = flag + 64;                         // 4
  int*   endp  = off + 4;                           // 4
  int*   cur   = endp + 4;                          // 4 (+pad)
  int*   einfo = flag + 128;                        // T ints
  float* w0a   = (float*)(einfo + T_);              // T
  float* w1a   = w0a + T_;                          // T
  int*   pack  = (int*)(w1a + T_);                  // CAP ints
  float* wlist = (float*)(pack + CAP_);             // CAP
  int*   tmap  = (int*)(wlist + CAP_);              // 160 ints (count + tiles)
  float* xn    = (float*)(tmap + 160);              // 65536
  float* h     = xn + 65536;                        // T*D f    (16 MB)
  float* cw    = h + (size_t)T_ * D_;               // T*4
  bf16*  hb16  = (bf16*)(cw + (size_t)T_ * E_);     // T*D bf16 (8 MB)
  bf16*  R     = hb16 + (size_t)T_ * D_;            // alias region
  bf16*  qkvb16 = R;                                // T*3D bf16 (24 MB)
  bf16*  ao    = R + (size_t)T_ * D3_;              // T*D bf16  (8 MB)
  bf16*  hid   = R;                                 // CAP*1024 bf16 (~33 MB)
  bf16*  psl   = R + (size_t)CAP_ * 1024;           // 4x T*D bf16 (32 MB partial slices)
  bf16*  wcvt  = psl + (size_t)4 * T_ * D_;         // 8.4 MB bf16 weight scratch
  bf16*  wq    = wcvt;
  bf16*  wo    = wcvt + (size_t)D3_ * D_;
  bf16*  we1   = wcvt;
  bf16*  we2   = wcvt + (size_t)E_ * 1024 * 512;
  float* addtab = (float*)R;                        // [S][D] f32 PE table (dead before QKV GEMM)

  constexpr size_t NQ = (size_t)D3_ * D_;           // 786432
  constexpr size_t NO = (size_t)D_ * D_;            // 262144
  constexpr size_t NE = (size_t)E_ * 1024 * 512;    // 2097152

  detect_kernel<<<1, 64, 0, stream>>>(x, flag);
  instnorm_kernel<<<B_ * F_, 256, 0, stream>>>(x, xn, flag);
  pe_kernel<<<(S_ * D_ / 2) / 256, 256, 0, stream>>>(bp, femb, freq, addtab, flag);
  input_proj_kernel<<<T_ / IPG_, 256, 0, stream>>>(xn, Wp, addtab, h, hb16, flag);

  for (int l = 0; l < 3; l++) {
    // convert this layer's qkv_w + ow to bf16 scratch (copy if already bf16)
    convw_kernel<<<(NQ + NO) / 2048, 256, 0, stream>>>(
        qkvw, (size_t)l * NQ, NQ, ow, (size_t)l * NO, wcvt, flag);
    // QKV projection -> bf16
    mfma_gemm<3><<<dim3(D3_ / 128, T_ / 128), 256, 0, stream>>>(
        hb16, wq, qkvb, (size_t)l * D3_, qkvb16, D_, D_, D_, D3_, flag);
    attn_kernel<<<B_ * H_ * (S_ / 64), 256, 0, stream>>>(qkvb16, ao);
    // O-projection: split-K=2 -> slices 0,1; fused reduce + bias + LN
    mfma_gemm<0><<<dim3(D_ / 128, T_ / 128, 2), 256, 0, stream>>>(
        ao, wo, nullptr, 0, psl, D_, D_, D_, D_, flag);
    reduce_ln_kernel<<<T_, 256, 0, stream>>>(
        h, hb16, psl, 2, 0, ob, (size_t)l * D_, nullptr, nullptr, 0,
        g1, be1, (size_t)l * D_, flag);
    // gating + routing
    gate_kernel<<<T_ / 4, 256, 0, stream>>>(h, gw, (size_t)l * E_ * D_, gb, (size_t)l * E_,
                                            cw, einfo, w0a, w1a, flag);
    route_scan_kernel<<<1, 256, 0, stream>>>(einfo, off, endp, cur, tmap);
    scatter_kernel<<<T_ / 256, 256, 0, stream>>>(einfo, w0a, w1a, off, cur, pack, wlist);
    // convert this layer's ew1 + ew2 to bf16 scratch (wq/wo dead past here)
    convw_kernel<<<(NE + NE) / 2048, 256, 0, stream>>>(
        ew1, (size_t)l * NE, NE, ew2, (size_t)l * NE, wcvt, flag);
    // sparse expert GEMMs (hid aliases qkv+ao, both dead here)
    moe_mat1_kernel<<<dim3(8, 136), 256, 0, stream>>>(
        hb16, we1, eb1, (size_t)l * E_ * 1024, hid,
        off, endp, pack, wlist, tmap, flag);
    moe_mat2_kernel<<<dim3(4, 136, 2), 256, 0, stream>>>(
        hid, we2, psl, off, endp, pack, tmap, flag);
    reduce_ln_kernel<<<T_, 256, 0, stream>>>(
        h, hb16, psl, 4, 1, nullptr, 0, cw, eb2, (size_t)l * E_ * D_,
        g2, be2, (size_t)l * D_, flag);
  }

  head_kernel<<<24, 256, 0, stream>>>(h, hw, hb, d_out, flag);
}

// Round 9
// 844.480 us; speedup vs baseline: 1.2966x; 1.0069x over previous
//
#include <hip/hip_runtime.h>
#include <hip/hip_bf16.h>
#include <math.h>

typedef __hip_bfloat16 bf16;
typedef __attribute__((ext_vector_type(8))) short short8;   // 8 bf16 (4 VGPRs)
typedef __attribute__((ext_vector_type(4))) short s4v;      // 4 bf16 (8 bytes)
typedef __attribute__((ext_vector_type(4))) float f32x4;

constexpr int B_ = 8, S_ = 1024, F_ = 8, D_ = 512, H_ = 8, E_ = 4;
constexpr int T_  = B_ * S_;       // 8192 tokens
constexpr int D3_ = 3 * D_;        // 1536
constexpr int CAP_ = T_ * 2 + E_ * 128;   // sparse row capacity (top-2, 128-pad/expert)

__device__ __forceinline__ float b2f(bf16 v) { return __bfloat162float(v); }
__device__ __forceinline__ float ldin(const void* p, size_t i, int bf) {
  return bf ? __bfloat162float(((const bf16*)p)[i]) : ((const float*)p)[i];
}
__device__ __forceinline__ void gload16(const void* g, void* l) {
  __builtin_amdgcn_global_load_lds((const __attribute__((address_space(1))) unsigned int*)g,
                                   (__attribute__((address_space(3))) unsigned int*)l, 16, 0, 0);
}

// ---------------- dtype detector ----------------
__global__ void detect_kernel(const void* __restrict__ x, int* __restrict__ flag) {
  if (threadIdx.x == 0 && blockIdx.x == 0) {
    const unsigned short* u = (const unsigned short*)x;
    int c = 0;
    for (int i = 0; i < 256; i += 2) {
      int ex = (u[i] >> 7) & 0xFF;
      if (ex >= 96 && ex <= 144) c++;
    }
    flag[0] = (c >= 64) ? 1 : 0;
  }
}

// ---------------- weight pre-convert: fp32 (or bf16 copy) -> bf16 scratch ----------
__global__ __launch_bounds__(256) void convw_kernel(const void* __restrict__ Asrc, size_t offA,
                                                    size_t nA,
                                                    const void* __restrict__ Bsrc, size_t offB,
                                                    bf16* __restrict__ dst,
                                                    const int* __restrict__ flag) {
  const int bf = flag[0];
  size_t i = ((size_t)blockIdx.x * 256 + threadIdx.x) * 8;
  const void* s = Asrc;
  size_t so = offA + i;
  if (i >= nA) { s = Bsrc; so = offB + (i - nA); }
  if (bf) {
    *(short8*)(dst + i) = *(const short8*)((const bf16*)s + so);
  } else {
    const float* sp = (const float*)s + so;
    short8 v;
#pragma unroll
    for (int u = 0; u < 8; u++) { bf16 t = __float2bfloat16(sp[u]); v[u] = *(short*)&t; }
    *(short8*)(dst + i) = v;
  }
}

// ---------------- instance norm over time axis ----------------
__global__ __launch_bounds__(256) void instnorm_kernel(const void* __restrict__ x,
                                                       float* __restrict__ xn,
                                                       const int* __restrict__ flag) {
  const int bf = flag[0];
  int b = blockIdx.x / F_, f = blockIdx.x % F_;
  int tid = threadIdx.x;
  __shared__ float red[256];
  const int base = b * S_ * F_ + f;
  float s = 0.f;
  for (int j = tid; j < S_; j += 256) s += ldin(x, base + j * F_, bf);
  red[tid] = s; __syncthreads();
  for (int w = 128; w; w >>= 1) { if (tid < w) red[tid] += red[tid + w]; __syncthreads(); }
  float mean = red[0] / S_;
  __syncthreads();
  float v = 0.f;
  for (int j = tid; j < S_; j += 256) { float d = ldin(x, base + j * F_, bf) - mean; v += d * d; }
  red[tid] = v; __syncthreads();
  for (int w = 128; w; w >>= 1) { if (tid < w) red[tid] += red[tid + w]; __syncthreads(); }
  float inv = 1.f / (sqrtf(red[0] / (float)(S_ - 1)) + 1e-5f);
  for (int j = tid; j < S_; j += 256) xn[base + j * F_] = (ldin(x, base + j * F_, bf) - mean) * inv;
}

// ---------------- positional-encoding + bias + freq-emb add-table [S][D] -----------
__global__ __launch_bounds__(256) void pe_kernel(const void* __restrict__ bp,
                                                 const void* __restrict__ femb,
                                                 const int* __restrict__ freq_idx,
                                                 float* __restrict__ addtab,
                                                 const int* __restrict__ flag) {
  const int bf = flag[0];
  int idx = blockIdx.x * 256 + threadIdx.x;      // S*D/2 threads
  int dp = idx & (D_ / 2 - 1);
  int s  = idx / (D_ / 2);
  int d0 = dp * 2;
  int fi = freq_idx[0];
  const float cexp = -9.2103403719761836f / (float)D_;
  float ang = (float)s * expf((float)d0 * cexp);
  float sv, cv;
  sincosf(ang, &sv, &cv);
  addtab[(size_t)s * D_ + d0]     = sv + ldin(bp, d0, bf)     + ldin(femb, (size_t)fi * D_ + d0, bf);
  addtab[(size_t)s * D_ + d0 + 1] = cv + ldin(bp, d0 + 1, bf) + ldin(femb, (size_t)fi * D_ + d0 + 1, bf);
}

// ---------------- input projection: xn @ Wp^T + addtab -----------------------------
constexpr int IPG_ = 8;   // tokens per block
__global__ __launch_bounds__(256) void input_proj_kernel(const float* __restrict__ xn,
                                                         const void* __restrict__ Wp,
                                                         const float* __restrict__ addtab,
                                                         float* __restrict__ h,
                                                         bf16* __restrict__ hb16,
                                                         const int* __restrict__ flag) {
  const int bf = flag[0];
  const int tid = threadIdx.x;
  const int d0 = tid * 2;
  const int tbase = blockIdx.x * IPG_;
  float wp0[8], wp1[8];
  if (bf) {
    short8 w0 = *(const short8*)((const bf16*)Wp + (size_t)d0 * F_);
    short8 w1 = *(const short8*)((const bf16*)Wp + (size_t)(d0 + 1) * F_);
#pragma unroll
    for (int f = 0; f < 8; f++) {
      unsigned short u0 = (unsigned short)w0[f], u1 = (unsigned short)w1[f];
      wp0[f] = __bfloat162float(*(bf16*)&u0);
      wp1[f] = __bfloat162float(*(bf16*)&u1);
    }
  } else {
    const float* wpf = (const float*)Wp + (size_t)d0 * F_;
    f32x4 a = *(const f32x4*)(wpf);
    f32x4 b = *(const f32x4*)(wpf + 4);
    f32x4 c = *(const f32x4*)(wpf + 8);
    f32x4 d = *(const f32x4*)(wpf + 12);
#pragma unroll
    for (int f = 0; f < 4; f++) { wp0[f] = a[f]; wp0[4 + f] = b[f]; wp1[f] = c[f]; wp1[4 + f] = d[f]; }
  }
#pragma unroll
  for (int g = 0; g < IPG_; g++) {
    int t = tbase + g;
    int s = t & (S_ - 1);
    const float* xr = xn + (size_t)t * F_;
    f32x4 x0 = *(const f32x4*)xr;
    f32x4 x1 = *(const f32x4*)(xr + 4);
    const float2 at = *(const float2*)(addtab + (size_t)s * D_ + d0);
    float a0 = at.x, a1 = at.y;
#pragma unroll
    for (int f = 0; f < 4; f++) { a0 += x0[f] * wp0[f]; a1 += x0[f] * wp1[f]; }
#pragma unroll
    for (int f = 0; f < 4; f++) { a0 += x1[f] * wp0[4 + f]; a1 += x1[f] * wp1[4 + f]; }
    *(float2*)(h + (size_t)t * D_ + d0) = make_float2(a0, a1);
    bf16 b0 = __float2bfloat16(a0), b1 = __float2bfloat16(a1);
    unsigned pk = (unsigned)(*(unsigned short*)&b0) | ((unsigned)(*(unsigned short*)&b1) << 16);
    *(unsigned*)(hb16 + (size_t)t * D_ + d0) = pk;
  }
}

// ---------------- dense MFMA GEMM, 128x128, 3-stage counted-vmcnt pipeline ----------
template <int MODE>
__global__ __launch_bounds__(256) void mfma_gemm(
    const bf16* __restrict__ A, const bf16* __restrict__ Wt,
    const void* __restrict__ bias, size_t boff, void* __restrict__ C_,
    int Kd, int lda, int ldb, int ldc, const int* __restrict__ flag) {
  const int wbf = flag[0];
  __shared__ bf16 As[3][128][32];
  __shared__ bf16 Bs[3][128][32];
  const int tid = threadIdx.x;
  const int ln = tid & 63, wv = tid >> 6;
  int id = blockIdx.x + gridDim.x * blockIdx.y;
  int xcd = id & 7, idq = id >> 3;
  const int n0 = (idq % gridDim.x) * 128;
  const int m0 = (xcd + 8 * (idq / gridDim.x)) * 128;
  const int wr = (wv >> 1) * 64, wc = (wv & 1) * 64;
  const int mrow = ln & 15, quad = ln >> 4;
  const int srow = ln >> 2;
  const int skof = (ln & 3) * 8;
  const int kchunk = Kd / gridDim.z;
  const int kbeg = blockIdx.z * kchunk;
  const int kend = kbeg + kchunk;

  auto stage = [&](int pb, int k0) {
#pragma unroll
    for (int j = 0; j < 2; j++) {
      int row = 16 * (4 * j + wv) + srow;
      gload16(A + (size_t)(m0 + row) * lda + k0 + skof,
              (char*)&As[pb][0][0] + (size_t)(4 * j + wv) * 1024);
    }
#pragma unroll
    for (int j = 0; j < 2; j++) {
      int row = 16 * (4 * j + wv) + srow;
      gload16(Wt + (size_t)(n0 + row) * ldb + k0 + skof,
              (char*)&Bs[pb][0][0] + (size_t)(4 * j + wv) * 1024);
    }
  };

  f32x4 acc[4][4];
#pragma unroll
  for (int i = 0; i < 4; i++)
#pragma unroll
    for (int j = 0; j < 4; j++) acc[i][j] = (f32x4){0.f, 0.f, 0.f, 0.f};

  stage(0, kbeg);
  stage(1, kbeg + 32);
  int p = 0;
  for (int k0 = kbeg; k0 < kend; k0 += 32) {
    if (k0 + 32 < kend) asm volatile("s_waitcnt vmcnt(4)" ::: "memory");
    else                asm volatile("s_waitcnt vmcnt(0)" ::: "memory");
    __builtin_amdgcn_s_barrier();
    __builtin_amdgcn_sched_barrier(0);
    short8 af[4], bfr[4];
#pragma unroll
    for (int t = 0; t < 4; t++) {
      af[t]  = *(const short8*)&As[p][wr + t * 16 + mrow][quad * 8];
      bfr[t] = *(const short8*)&Bs[p][wc + t * 16 + mrow][quad * 8];
    }
    if (k0 + 64 < kend) {
      int ps = (p == 0) ? 2 : p - 1;   // (p+2)%3
      stage(ps, k0 + 64);
    }
#pragma unroll
    for (int i = 0; i < 4; i++)
#pragma unroll
      for (int j = 0; j < 4; j++)
        acc[i][j] = __builtin_amdgcn_mfma_f32_16x16x32_bf16(af[i], bfr[j], acc[i][j], 0, 0, 0);
    p = (p == 2) ? 0 : p + 1;
  }

  bf16* slice = (MODE == 0) ? (bf16*)C_ + (size_t)blockIdx.z * T_ * D_ : (bf16*)C_;
#pragma unroll
  for (int tj = 0; tj < 4; tj++) {
    int n = n0 + wc + tj * 16 + mrow;
    float bv = (MODE == 3) ? ldin(bias, boff + n, wbf) : 0.f;
#pragma unroll
    for (int ti = 0; ti < 4; ti++) {
      int mbase = m0 + wr + ti * 16 + quad * 4;
#pragma unroll
      for (int r = 0; r < 4; r++) {
        int m = mbase + r;
        float v = acc[ti][tj][r];
        slice[(size_t)m * ldc + n] = __float2bfloat16(MODE == 3 ? v + bv : v);
      }
    }
  }
}

// ---------------- MFMA flash attention: 64-query tile, swapped QK^T softmax --------
// T14 async-STAGE: K/V tile held in regs; ds_write at loop top, next tile's global
// loads issued immediately after (latency hides under QK+softmax+PV). Pre-compute
// barrier = raw s_barrier + lgkmcnt(0) only (prefetch loads stay in flight - they
// are reg-destined, invisible to other waves). T5 setprio around MFMA clusters.
__global__ __launch_bounds__(256) void attn_kernel(const bf16* __restrict__ qkv,
                                                   bf16* __restrict__ o) {
  __shared__ bf16 QP[64][72];    // Q tile, then P tile (aliased; rows wv*16.. wave-private)
  __shared__ bf16 Ks[64][72];
  __shared__ bf16 Vt[64][72];    // [d][k ^ swz(d)]
  const int tid = threadIdx.x;
  const int ln = tid & 63, wv = tid >> 6;
  const int mrow = ln & 15, quad = ln >> 4;
  const int id = blockIdx.x;
  const int xcd = id & 7, j = id >> 3;
  const int qt = j & 15;
  const int pr = xcd + 8 * (j >> 4);     // 0..63
  const int hh = pr & 7, b = pr >> 3;
  const int q0 = qt * 64;
  const int sr = tid >> 2;
  const int sg = tid & 3;
  const int sc = sg * 8;
  const int col0 = sr ^ (sg << 4);
  const int col1 = sr ^ (((sg + 4) & 3) << 4);

  {
    const bf16* src = qkv + (size_t)(b * S_ + q0 + sr) * D3_ + hh * 64;
    *(short8*)&QP[sr][sc]      = *(const short8*)(src + sc);
    *(short8*)&QP[sr][sc + 32] = *(const short8*)(src + sc + 32);
  }
  __syncthreads();
  short8 aq[2];
  aq[0] = *(const short8*)&QP[wv * 16 + mrow][quad * 8];
  aq[1] = *(const short8*)&QP[wv * 16 + mrow][quad * 8 + 32];

  float m_st = -1e30f, l_st = 0.f;
  f32x4 oacc[4];
#pragma unroll
  for (int t = 0; t < 4; t++) oacc[t] = (f32x4){0.f, 0.f, 0.f, 0.f};

  // prologue: prefetch tile 0 K/V into registers
  short8 kA, kB, vA, vB;
  {
    const bf16* srcK = qkv + (size_t)(b * S_ + sr) * D3_ + D_ + hh * 64;
    kA = *(const short8*)(srcK + sc);
    kB = *(const short8*)(srcK + sc + 32);
    const bf16* srcV = qkv + (size_t)(b * S_ + sr) * D3_ + 2 * D_ + hh * 64;
    vA = *(const short8*)(srcV + sc);
    vB = *(const short8*)(srcV + sc + 32);
  }

  for (int kt = 0; kt < 16; kt++) {
    __builtin_amdgcn_s_barrier();          // all waves done reading previous tile
    // write staged tile (compiler waits vmcnt for kA..vB deps automatically)
    *(short8*)&Ks[sr][sc]      = kA;
    *(short8*)&Ks[sr][sc + 32] = kB;
#pragma unroll
    for (int u = 0; u < 8; u++) {
      *(short*)&Vt[sc + u][col0]      = vA[u];
      *(short*)&Vt[sc + 32 + u][col1] = vB[u];
    }
    // issue next tile's loads; they stay in flight across the barrier below
    if (kt + 1 < 16) {
      int k0n = (kt + 1) * 64;
      const bf16* srcK = qkv + (size_t)(b * S_ + k0n + sr) * D3_ + D_ + hh * 64;
      kA = *(const short8*)(srcK + sc);
      kB = *(const short8*)(srcK + sc + 32);
      const bf16* srcV = qkv + (size_t)(b * S_ + k0n + sr) * D3_ + 2 * D_ + hh * 64;
      vA = *(const short8*)(srcV + sc);
      vB = *(const short8*)(srcV + sc + 32);
    }
    asm volatile("s_waitcnt lgkmcnt(0)" ::: "memory");   // ds_writes visible; vmcnt NOT drained
    __builtin_amdgcn_s_barrier();
    __builtin_amdgcn_sched_barrier(0);
    // swapped QK^T: sT[t] row = k_local (quad*4+r), col = q (mrow)
    f32x4 s[4];
    __builtin_amdgcn_s_setprio(1);
#pragma unroll
    for (int t = 0; t < 4; t++) {
      s[t] = (f32x4){0.f, 0.f, 0.f, 0.f};
#pragma unroll
      for (int ks = 0; ks < 2; ks++) {
        short8 bk = *(const short8*)&Ks[t * 16 + mrow][quad * 8 + ks * 32];
        s[t] = __builtin_amdgcn_mfma_f32_16x16x32_bf16(bk, aq[ks], s[t], 0, 0, 0);
      }
    }
    __builtin_amdgcn_s_setprio(0);
    float rm = s[0][0];
#pragma unroll
    for (int t = 0; t < 4; t++)
#pragma unroll
      for (int r = 0; r < 4; r++) rm = fmaxf(rm, s[t][r]);
    rm *= 0.125f;
    rm = fmaxf(rm, __shfl_xor(rm, 16, 64));
    rm = fmaxf(rm, __shfl_xor(rm, 32, 64));
    float mnew = fmaxf(m_st, rm);
    float alpha = __expf(m_st - mnew);
    m_st = mnew;
    float rs = 0.f;
#pragma unroll
    for (int t = 0; t < 4; t++) {
      s4v pk;
#pragma unroll
      for (int r = 0; r < 4; r++) {
        float p = __expf(s[t][r] * 0.125f - mnew);
        rs += p;
        bf16 tb = __float2bfloat16(p);
        pk[r] = *(short*)&tb;
      }
      *(s4v*)&QP[wv * 16 + mrow][t * 16 + quad * 4] = pk;
    }
    rs += __shfl_xor(rs, 16, 64);
    rs += __shfl_xor(rs, 32, 64);
    l_st = l_st * alpha + rs;
    float af4[4];
#pragma unroll
    for (int r = 0; r < 4; r++) af4[r] = __shfl(alpha, quad * 4 + r, 64);
#pragma unroll
    for (int t = 0; t < 4; t++)
#pragma unroll
      for (int r = 0; r < 4; r++) oacc[t][r] *= af4[r];
    short8 ap[2];
    ap[0] = *(const short8*)&QP[wv * 16 + mrow][quad * 8];
    ap[1] = *(const short8*)&QP[wv * 16 + mrow][quad * 8 + 32];
    __builtin_amdgcn_s_setprio(1);
#pragma unroll
    for (int t = 0; t < 4; t++) {
      int d = t * 16 + mrow;
      int swz = ((d >> 3) & 3) << 4;
#pragma unroll
      for (int ks = 0; ks < 2; ks++) {
        short8 bv = *(const short8*)&Vt[d][(quad * 8 + ks * 32) ^ swz];
        oacc[t] = __builtin_amdgcn_mfma_f32_16x16x32_bf16(ap[ks], bv, oacc[t], 0, 0, 0);
      }
    }
    __builtin_amdgcn_s_setprio(0);
  }
  float linv[4];
#pragma unroll
  for (int r = 0; r < 4; r++) linv[r] = 1.f / __shfl(l_st, quad * 4 + r, 64);
#pragma unroll
  for (int r = 0; r < 4; r++) {
    size_t base = (size_t)(b * S_ + q0 + wv * 16 + quad * 4 + r) * D_ + hh * 64;
#pragma unroll
    for (int t = 0; t < 4; t++)
      o[base + t * 16 + mrow] = __float2bfloat16(oacc[t][r] * linv[r]);
  }
}

// ---------------- fused: sum partial slices + bias + residual + LayerNorm ----------
__global__ __launch_bounds__(256) void reduce_ln_kernel(float* __restrict__ h,
                                                        bf16* __restrict__ hb16,
                                                        const bf16* __restrict__ ps,
                                                        int nsl, int mode,
                                                        const void* __restrict__ bias,
                                                        size_t boff,
                                                        const float* __restrict__ cw,
                                                        const void* __restrict__ eb2p,
                                                        size_t e2off,
                                                        const void* __restrict__ g,
                                                        const void* __restrict__ beta,
                                                        size_t off,
                                                        const int* __restrict__ flag) {
  const int bf = flag[0];
  int t = blockIdx.x, tid = threadIdx.x;
  __shared__ float r1[256], r2[256];
  const size_t base = (size_t)t * D_;
  float o0 = 0.f, o1 = 0.f;
  for (int s = 0; s < nsl; s++) {
    o0 += b2f(ps[(size_t)s * T_ * D_ + base + tid]);
    o1 += b2f(ps[(size_t)s * T_ * D_ + base + tid + 256]);
  }
  if (mode == 0) {
    o0 += ldin(bias, boff + tid, bf);
    o1 += ldin(bias, boff + tid + 256, bf);
  } else {
#pragma unroll
    for (int e = 0; e < 4; e++) {
      float w = cw[t * 4 + e];
      o0 += w * ldin(eb2p, e2off + e * D_ + tid, bf);
      o1 += w * ldin(eb2p, e2off + e * D_ + tid + 256, bf);
    }
  }
  float* hr = h + base;
  float v0 = hr[tid] + o0;
  float v1 = hr[tid + 256] + o1;
  r1[tid] = v0 + v1;
  r2[tid] = v0 * v0 + v1 * v1;
  __syncthreads();
  for (int w = 128; w; w >>= 1) { if (tid < w) { r1[tid] += r1[tid + w]; r2[tid] += r2[tid + w]; } __syncthreads(); }
  float mean = r1[0] * (1.f / D_);
  float var  = r2[0] * (1.f / D_) - mean * mean;
  float rstd = rsqrtf(var + 1e-5f);
  float n0 = (v0 - mean) * rstd * ldin(g, off + tid, bf) + ldin(beta, off + tid, bf);
  float n1 = (v1 - mean) * rstd * ldin(g, off + tid + 256, bf) + ldin(beta, off + tid + 256, bf);
  hr[tid] = n0;
  hr[tid + 256] = n1;
  hb16[base + tid] = __float2bfloat16(n0);
  hb16[base + tid + 256] = __float2bfloat16(n1);
}

// ---------------- MoE gating: softmax over E=4, top-2; emits routing info ----------
__global__ __launch_bounds__(256) void gate_kernel(const float* __restrict__ hbuf,
                                                   const void* __restrict__ gw, size_t gwoff,
                                                   const void* __restrict__ gb, size_t gboff,
                                                   float* __restrict__ cw,
                                                   int* __restrict__ einfo,
                                                   float* __restrict__ w0a,
                                                   float* __restrict__ w1a,
                                                   const int* __restrict__ flag) {
  const int bf = flag[0];
  int lane = threadIdx.x & 63, wv = threadIdx.x >> 6;
  int t = blockIdx.x * 4 + wv;
  const float* xr = hbuf + (size_t)t * D_;
  float a[4] = {0, 0, 0, 0};
  for (int d = lane; d < D_; d += 64) {
    float xv = xr[d];
#pragma unroll
    for (int e = 0; e < 4; e++) a[e] += xv * ldin(gw, gwoff + e * D_ + d, bf);
  }
#pragma unroll
  for (int e = 0; e < 4; e++)
    for (int off = 32; off; off >>= 1) a[e] += __shfl_xor(a[e], off, 64);
  if (lane == 0) {
    float lg[4];
#pragma unroll
    for (int e = 0; e < 4; e++) lg[e] = a[e] + ldin(gb, gboff + e, bf);
    float m = fmaxf(fmaxf(lg[0], lg[1]), fmaxf(lg[2], lg[3]));
    float p[4], s = 0.f;
#pragma unroll
    for (int e = 0; e < 4; e++) { p[e] = __expf(lg[e] - m); s += p[e]; }
#pragma unroll
    for (int e = 0; e < 4; e++) p[e] /= s;
    int i0 = 0;
    for (int e = 1; e < 4; e++) if (p[e] > p[i0]) i0 = e;
    int i1 = -1;
    for (int e = 0; e < 4; e++) if (e != i0 && (i1 < 0 || p[e] > p[i1])) i1 = e;
    float s2 = p[i0] + p[i1];
    float ww0 = p[i0] / s2, ww1 = p[i1] / s2;
    float outw[4] = {0, 0, 0, 0};
    outw[i0] = ww0; outw[i1] = ww1;
#pragma unroll
    for (int e = 0; e < 4; e++) cw[t * 4 + e] = outw[e];
    einfo[t] = i0 | (i1 << 4);
    w0a[t] = ww0; w1a[t] = ww1;
  }
}

// ---------------- route scan: counts -> offsets + tile table (1 block) ----------------
__global__ __launch_bounds__(256) void route_scan_kernel(const int* __restrict__ einfo,
                                                         int* __restrict__ off,
                                                         int* __restrict__ endp,
                                                         int* __restrict__ cur,
                                                         int* __restrict__ tmap) {
  __shared__ int red[4][256];
  int tid = threadIdx.x;
  int c[4] = {0, 0, 0, 0};
  for (int t = tid; t < T_; t += 256) {
    int inf = einfo[t];
    c[inf & 15]++;
    c[(inf >> 4) & 15]++;
  }
#pragma unroll
  for (int e = 0; e < 4; e++) red[e][tid] = c[e];
  __syncthreads();
  for (int w = 128; w; w >>= 1) {
    if (tid < w)
#pragma unroll
      for (int e = 0; e < 4; e++) red[e][tid] += red[e][tid + w];
    __syncthreads();
  }
  if (tid == 0) {
    int o = 0, idx = 0;
#pragma unroll
    for (int e = 0; e < 4; e++) {
      int cnt = red[e][0];
      off[e] = o;
      endp[e] = o + cnt;
      cur[e] = 0;
      int nt = (cnt + 127) >> 7;
      for (int i = 0; i < nt; i++) tmap[1 + idx++] = e | (i << 8);
      o += nt << 7;
    }
    tmap[0] = idx;   // total active m-tiles (<= 131)
  }
}

// ---------------- scatter: token -> (expert bucket, rank), ballot-aggregated --------
__global__ __launch_bounds__(256) void scatter_kernel(const int* __restrict__ einfo,
                                                      const float* __restrict__ w0a,
                                                      const float* __restrict__ w1a,
                                                      const int* __restrict__ off,
                                                      int* __restrict__ cur,
                                                      int* __restrict__ pack,
                                                      float* __restrict__ wlist) {
  int t = blockIdx.x * 256 + threadIdx.x;
  int lane = threadIdx.x & 63;
  int inf = einfo[t];
#pragma unroll
  for (int rank = 0; rank < 2; rank++) {
    int my_e = (rank == 0) ? (inf & 15) : ((inf >> 4) & 15);
    float w = (rank == 0) ? w0a[t] : w1a[t];
#pragma unroll
    for (int e = 0; e < 4; e++) {
      bool p = (my_e == e);
      unsigned long long mask = __ballot(p);
      if (!mask) continue;
      int leader = __ffsll((long long)mask) - 1;
      int base = 0;
      if (lane == leader) base = atomicAdd(&cur[e], (int)__popcll(mask));
      base = __shfl(base, leader, 64);
      if (p) {
        int pos = off[e] + base + (int)__popcll(mask & ((1ULL << lane) - 1ULL));
        pack[pos] = t * 2 + rank;
        wlist[pos] = w;
      }
    }
  }
}

// ---------------- sparse MoE mat1: 128x128, 3-stage counted-vmcnt pipeline ----------
__global__ __launch_bounds__(256) void moe_mat1_kernel(
    const bf16* __restrict__ A, const bf16* __restrict__ Wt,
    const void* __restrict__ bias, size_t boff, bf16* __restrict__ hid,
    const int* __restrict__ off, const int* __restrict__ endp,
    const int* __restrict__ pack, const float* __restrict__ wlist,
    const int* __restrict__ tmap, const int* __restrict__ flag) {
  const int wbf = flag[0];
  int id = blockIdx.x + 8 * blockIdx.y;
  int xcd = id & 7, idq = id >> 3;
  int wx = idq & 7, wy = xcd + 8 * (idq >> 3);
  if (wy >= tmap[0]) return;
  int ent = tmap[1 + wy];
  const int e = ent & 255, mt = ent >> 8;
  const int o = off[e], en = endp[e];
  const int n0 = wx * 128;
  __shared__ bf16 As[3][128][32];
  __shared__ bf16 Bs[3][128][32];
  const int tid = threadIdx.x;
  const int ln = tid & 63, wv = tid >> 6;
  const int m0 = o + mt * 128;
  const int wr = (wv >> 1) * 64, wc = (wv & 1) * 64;
  const int mrow = ln & 15, quad = ln >> 4;
  const int srow = ln >> 2;
  const int skof = (ln & 3) * 8;
  int tokr[2];
#pragma unroll
  for (int j = 0; j < 2; j++) {
    int pos = m0 + 16 * (4 * j + wv) + srow;
    tokr[j] = pack[min(pos, en - 1)] >> 1;
  }
  const size_t wbase = (size_t)e * 1024 * 512;

  auto stage = [&](int pb, int k0) {
#pragma unroll
    for (int j = 0; j < 2; j++)
      gload16(A + (size_t)tokr[j] * 512 + k0 + skof,
              (char*)&As[pb][0][0] + (size_t)(4 * j + wv) * 1024);
#pragma unroll
    for (int j = 0; j < 2; j++) {
      int row = 16 * (4 * j + wv) + srow;
      gload16(Wt + wbase + (size_t)(n0 + row) * 512 + k0 + skof,
              (char*)&Bs[pb][0][0] + (size_t)(4 * j + wv) * 1024);
    }
  };

  f32x4 acc[4][4];
#pragma unroll
  for (int i = 0; i < 4; i++)
#pragma unroll
    for (int j = 0; j < 4; j++) acc[i][j] = (f32x4){0.f, 0.f, 0.f, 0.f};

  stage(0, 0);
  stage(1, 32);
  int p = 0;
  for (int k0 = 0; k0 < 512; k0 += 32) {
    if (k0 + 32 < 512) asm volatile("s_waitcnt vmcnt(4)" ::: "memory");
    else               asm volatile("s_waitcnt vmcnt(0)" ::: "memory");
    __builtin_amdgcn_s_barrier();
    __builtin_amdgcn_sched_barrier(0);
    short8 af[4], bfr[4];
#pragma unroll
    for (int t = 0; t < 4; t++) {
      af[t]  = *(const short8*)&As[p][wr + t * 16 + mrow][quad * 8];
      bfr[t] = *(const short8*)&Bs[p][wc + t * 16 + mrow][quad * 8];
    }
    if (k0 + 64 < 512) {
      int ps = (p == 0) ? 2 : p - 1;
      stage(ps, k0 + 64);
    }
#pragma unroll
    for (int i = 0; i < 4; i++)
#pragma unroll
      for (int j = 0; j < 4; j++)
        acc[i][j] = __builtin_amdgcn_mfma_f32_16x16x32_bf16(af[i], bfr[j], acc[i][j], 0, 0, 0);
    p = (p == 2) ? 0 : p + 1;
  }

#pragma unroll
  for (int ti = 0; ti < 4; ti++) {
#pragma unroll
    for (int r = 0; r < 4; r++) {
      int pos = m0 + wr + ti * 16 + quad * 4 + r;
      float w = (pos < en) ? wlist[pos] : 0.f;
#pragma unroll
      for (int tj = 0; tj < 4; tj++) {
        int ncol = n0 + wc + tj * 16 + mrow;
        float v = acc[ti][tj][r] + ldin(bias, boff + e * 1024 + ncol, wbf);
        hid[(size_t)pos * 1024 + ncol] = __float2bfloat16(fmaxf(v, 0.f) * w);
      }
    }
  }
}

// ---------------- sparse MoE mat2: 128x128, 3-stage counted-vmcnt pipeline, z=2 -----
__global__ __launch_bounds__(256) void moe_mat2_kernel(
    const bf16* __restrict__ hid, const bf16* __restrict__ Wt,
    bf16* __restrict__ psl,
    const int* __restrict__ off, const int* __restrict__ endp,
    const int* __restrict__ pack, const int* __restrict__ tmap,
    const int* __restrict__ flag) {
  int id = blockIdx.x + 4 * blockIdx.y;
  int xcd = id & 7, idq = id >> 3;
  int wx = idq & 3, wy = xcd + 8 * (idq >> 2);
  if (wy >= tmap[0]) return;
  int ent = tmap[1 + wy];
  const int e = ent & 255, mt = ent >> 8;
  const int o = off[e], en = endp[e];
  const int n0 = wx * 128;
  __shared__ bf16 As[3][128][32];
  __shared__ bf16 Bs[3][128][32];
  const int tid = threadIdx.x;
  const int ln = tid & 63, wv = tid >> 6;
  const int m0 = o + mt * 128;
  const int wr = (wv >> 1) * 64, wc = (wv & 1) * 64;
  const int mrow = ln & 15, quad = ln >> 4;
  const int srow = ln >> 2;
  const int skof = (ln & 3) * 8;
  const int kbeg = blockIdx.z * 512;
  const size_t wbase = (size_t)e * 512 * 1024;

  auto stage = [&](int pb, int k0) {
#pragma unroll
    for (int j = 0; j < 2; j++) {
      int row = 16 * (4 * j + wv) + srow;
      gload16(hid + (size_t)(m0 + row) * 1024 + k0 + skof,
              (char*)&As[pb][0][0] + (size_t)(4 * j + wv) * 1024);
    }
#pragma unroll
    for (int j = 0; j < 2; j++) {
      int row = 16 * (4 * j + wv) + srow;
      gload16(Wt + wbase + (size_t)(n0 + row) * 1024 + k0 + skof,
              (char*)&Bs[pb][0][0] + (size_t)(4 * j + wv) * 1024);
    }
  };

  f32x4 acc[4][4];
#pragma unroll
  for (int i = 0; i < 4; i++)
#pragma unroll
    for (int j = 0; j < 4; j++) acc[i][j] = (f32x4){0.f, 0.f, 0.f, 0.f};

  stage(0, kbeg);
  stage(1, kbeg + 32);
  int p = 0;
  for (int k0 = kbeg; k0 < kbeg + 512; k0 += 32) {
    if (k0 + 32 < kbeg + 512) asm volatile("s_waitcnt vmcnt(4)" ::: "memory");
    else                      asm volatile("s_waitcnt vmcnt(0)" ::: "memory");
    __builtin_amdgcn_s_barrier();
    __builtin_amdgcn_sched_barrier(0);
    short8 af[4], bfr[4];
#pragma unroll
    for (int t = 0; t < 4; t++) {
      af[t]  = *(const short8*)&As[p][wr + t * 16 + mrow][quad * 8];
      bfr[t] = *(const short8*)&Bs[p][wc + t * 16 + mrow][quad * 8];
    }
    if (k0 + 64 < kbeg + 512) {
      int ps = (p == 0) ? 2 : p - 1;
      stage(ps, k0 + 64);
    }
#pragma unroll
    for (int i = 0; i < 4; i++)
#pragma unroll
      for (int j = 0; j < 4; j++)
        acc[i][j] = __builtin_amdgcn_mfma_f32_16x16x32_bf16(af[i], bfr[j], acc[i][j], 0, 0, 0);
    p = (p == 2) ? 0 : p + 1;
  }

#pragma unroll
  for (int ti = 0; ti < 4; ti++) {
#pragma unroll
    for (int r = 0; r < 4; r++) {
      int pos = m0 + wr + ti * 16 + quad * 4 + r;
      if (pos < en) {
        int pk = pack[pos];
        int tok = pk >> 1, rank = pk & 1;
        bf16* dst = psl + (size_t)(rank * 2 + blockIdx.z) * T_ * D_ + (size_t)tok * D_;
#pragma unroll
        for (int tj = 0; tj < 4; tj++) {
          int ncol = n0 + wc + tj * 16 + mrow;
          dst[ncol] = __float2bfloat16(acc[ti][tj][r]);
        }
      }
    }
  }
}

// ---------------- head ----------------
__global__ __launch_bounds__(256) void head_kernel(const float* __restrict__ hbuf,
                                                   const void* __restrict__ hw,
                                                   const void* __restrict__ hb,
                                                   void* __restrict__ out,
                                                   const int* __restrict__ flag) {
  const int bf = flag[0];
  int bq = blockIdx.x, tid = threadIdx.x;
  int b = bq / 3, q = bq % 3;
  __shared__ float red[256];
  const float* xr = hbuf + (size_t)(b * S_ + (S_ - 1)) * D_;
  float sacc = xr[tid] * ldin(hw, (size_t)q * D_ + tid, bf)
             + xr[tid + 256] * ldin(hw, (size_t)q * D_ + tid + 256, bf);
  red[tid] = sacc; __syncthreads();
  for (int w = 128; w; w >>= 1) { if (tid < w) red[tid] += red[tid + w]; __syncthreads(); }
  if (tid == 0) {
    float r = red[0] + ldin(hb, q, bf);
    if (bf) ((bf16*)out)[bq] = __float2bfloat16(r);
    else    ((float*)out)[bq] = r;
  }
}

extern "C" void kernel_launch(void* const* d_in, const int* in_sizes, int n_in,
                              void* d_out, int out_size, void* d_ws, size_t ws_size,
                              hipStream_t stream) {
  const void* x    = d_in[0];
  const void* Wp   = d_in[1];
  const void* bp   = d_in[2];
  const void* femb = d_in[3];
  const void* qkvw = d_in[4];
  const void* qkvb = d_in[5];
  const void* ow   = d_in[6];
  const void* ob   = d_in[7];
  const void* g1   = d_in[8];
  const void* be1  = d_in[9];
  const void* gw   = d_in[10];
  const void* gb   = d_in[11];
  const void* ew1  = d_in[12];
  const void* eb1  = d_in[13];
  const void* ew2  = d_in[14];
  const void* eb2  = d_in[15];
  const void* g2   = d_in[16];
  const void* be2  = d_in[17];
  const void* hw   = d_in[18];
  const void* hb   = d_in[19];
  const int*  freq = (const int*)d_in[20];

  // workspace layout: peak ~99.6 MB (within previously proven-safe 101 MB)
  int*   flag  = (int*)d_ws;                        // 64 ints
  int*   off   = flag + 64;                         // 4
  int*   endp  = off + 4;                           // 4
  int*   cur   = endp + 4;                          // 4 (+pad)
  int*   einfo = flag + 128;                        // T ints
  float* w0a   = (float*)(einfo + T_);              // T
  float* w1a   = w0a + T_;                          // T
  int*   pack  = (int*)(w1a + T_);                  // CAP ints
  float* wlist = (float*)(pack + CAP_);             // CAP
  int*   tmap  = (int*)(wlist + CAP_);              // 160 ints (count + tiles)
  float* xn    = (float*)(tmap + 160);              // 65536
  float* h     = xn + 65536;                        // T*D f    (16 MB)
  float* cw    = h + (size_t)T_ * D_;               // T*4
  bf16*  hb16  = (bf16*)(cw + (size_t)T_ * E_);     // T*D bf16 (8 MB)
  bf16*  R     = hb16 + (size_t)T_ * D_;            // alias region
  bf16*  qkvb16 = R;                                // T*3D bf16 (24 MB)
  bf16*  ao    = R + (size_t)T_ * D3_;              // T*D bf16  (8 MB)
  bf16*  hid   = R;                                 // CAP*1024 bf16 (~33 MB)
  bf16*  psl   = R + (size_t)CAP_ * 1024;           // 4x T*D bf16 (32 MB partial slices)
  bf16*  wcvt  = psl + (size_t)4 * T_ * D_;         // 8.4 MB bf16 weight scratch
  bf16*  wq    = wcvt;
  bf16*  wo    = wcvt + (size_t)D3_ * D_;
  bf16*  we1   = wcvt;
  bf16*  we2   = wcvt + (size_t)E_ * 1024 * 512;
  float* addtab = (float*)R;                        // [S][D] f32 PE table (dead before QKV GEMM)

  constexpr size_t NQ = (size_t)D3_ * D_;           // 786432
  constexpr size_t NO = (size_t)D_ * D_;            // 262144
  constexpr size_t NE = (size_t)E_ * 1024 * 512;    // 2097152

  detect_kernel<<<1, 64, 0, stream>>>(x, flag);
  instnorm_kernel<<<B_ * F_, 256, 0, stream>>>(x, xn, flag);
  pe_kernel<<<(S_ * D_ / 2) / 256, 256, 0, stream>>>(bp, femb, freq, addtab, flag);
  input_proj_kernel<<<T_ / IPG_, 256, 0, stream>>>(xn, Wp, addtab, h, hb16, flag);

  for (int l = 0; l < 3; l++) {
    // convert this layer's qkv_w + ow to bf16 scratch (copy if already bf16)
    convw_kernel<<<(NQ + NO) / 2048, 256, 0, stream>>>(
        qkvw, (size_t)l * NQ, NQ, ow, (size_t)l * NO, wcvt, flag);
    // QKV projection -> bf16
    mfma_gemm<3><<<dim3(D3_ / 128, T_ / 128), 256, 0, stream>>>(
        hb16, wq, qkvb, (size_t)l * D3_, qkvb16, D_, D_, D_, D3_, flag);
    attn_kernel<<<B_ * H_ * (S_ / 64), 256, 0, stream>>>(qkvb16, ao);
    // O-projection: split-K=2 -> slices 0,1; fused reduce + bias + LN
    mfma_gemm<0><<<dim3(D_ / 128, T_ / 128, 2), 256, 0, stream>>>(
        ao, wo, nullptr, 0, psl, D_, D_, D_, D_, flag);
    reduce_ln_kernel<<<T_, 256, 0, stream>>>(
        h, hb16, psl, 2, 0, ob, (size_t)l * D_, nullptr, nullptr, 0,
        g1, be1, (size_t)l * D_, flag);
    // gating + routing
    gate_kernel<<<T_ / 4, 256, 0, stream>>>(h, gw, (size_t)l * E_ * D_, gb, (size_t)l * E_,
                                            cw, einfo, w0a, w1a, flag);
    route_scan_kernel<<<1, 256, 0, stream>>>(einfo, off, endp, cur, tmap);
    scatter_kernel<<<T_ / 256, 256, 0, stream>>>(einfo, w0a, w1a, off, cur, pack, wlist);
    // convert this layer's ew1 + ew2 to bf16 scratch (wq/wo dead past here)
    convw_kernel<<<(NE + NE) / 2048, 256, 0, stream>>>(
        ew1, (size_t)l * NE, NE, ew2, (size_t)l * NE, wcvt, flag);
    // sparse expert GEMMs (hid aliases qkv+ao, both dead here)
    moe_mat1_kernel<<<dim3(8, 136), 256, 0, stream>>>(
        hb16, we1, eb1, (size_t)l * E_ * 1024, hid,
        off, endp, pack, wlist, tmap, flag);
    moe_mat2_kernel<<<dim3(4, 136, 2), 256, 0, stream>>>(
        hid, we2, psl, off, endp, pack, tmap, flag);
    reduce_ln_kernel<<<T_, 256, 0, stream>>>(
        h, hb16, psl, 4, 1, nullptr, 0, cw, eb2, (size_t)l * E_ * D_,
        g2, be2, (size_t)l * D_, flag);
  }

  head_kernel<<<24, 256, 0, stream>>>(h, hw, hb, d_out, flag);
}

// Round 10
// 827.399 us; speedup vs baseline: 1.3234x; 1.0206x over previous
//
#include <hip/hip_runtime.h>
#include <hip/hip_bf16.h>
#include <math.h>

typedef __hip_bfloat16 bf16;
typedef __attribute__((ext_vector_type(8))) short short8;   // 8 bf16 (4 VGPRs)
typedef __attribute__((ext_vector_type(4))) short s4v;      // 4 bf16 (8 bytes)
typedef __attribute__((ext_vector_type(4))) float f32x4;

constexpr int B_ = 8, S_ = 1024, F_ = 8, D_ = 512, H_ = 8, E_ = 4;
constexpr int T_  = B_ * S_;       // 8192 tokens
constexpr int D3_ = 3 * D_;        // 1536
constexpr int CAP_ = T_ * 2 + E_ * 128;   // sparse row capacity (top-2, 128-pad/expert)

__device__ __forceinline__ float b2f(bf16 v) { return __bfloat162float(v); }
__device__ __forceinline__ float ldin(const void* p, size_t i, int bf) {
  return bf ? __bfloat162float(((const bf16*)p)[i]) : ((const float*)p)[i];
}
__device__ __forceinline__ void gload16(const void* g, void* l) {
  __builtin_amdgcn_global_load_lds((const __attribute__((address_space(1))) unsigned int*)g,
                                   (__attribute__((address_space(3))) unsigned int*)l, 16, 0, 0);
}

// ---------------- dtype detector ----------------
__global__ void detect_kernel(const void* __restrict__ x, int* __restrict__ flag) {
  if (threadIdx.x == 0 && blockIdx.x == 0) {
    const unsigned short* u = (const unsigned short*)x;
    int c = 0;
    for (int i = 0; i < 256; i += 2) {
      int ex = (u[i] >> 7) & 0xFF;
      if (ex >= 96 && ex <= 144) c++;
    }
    flag[0] = (c >= 64) ? 1 : 0;
  }
}

// ---------------- weight pre-convert: fp32 (or bf16 copy) -> bf16 scratch ----------
__global__ __launch_bounds__(256) void convw_kernel(const void* __restrict__ Asrc, size_t offA,
                                                    size_t nA,
                                                    const void* __restrict__ Bsrc, size_t offB,
                                                    bf16* __restrict__ dst,
                                                    const int* __restrict__ flag) {
  const int bf = flag[0];
  size_t i = ((size_t)blockIdx.x * 256 + threadIdx.x) * 8;
  const void* s = Asrc;
  size_t so = offA + i;
  if (i >= nA) { s = Bsrc; so = offB + (i - nA); }
  if (bf) {
    *(short8*)(dst + i) = *(const short8*)((const bf16*)s + so);
  } else {
    const float* sp = (const float*)s + so;
    short8 v;
#pragma unroll
    for (int u = 0; u < 8; u++) { bf16 t = __float2bfloat16(sp[u]); v[u] = *(short*)&t; }
    *(short8*)(dst + i) = v;
  }
}

// ---------------- instance norm over time axis ----------------
__global__ __launch_bounds__(256) void instnorm_kernel(const void* __restrict__ x,
                                                       float* __restrict__ xn,
                                                       const int* __restrict__ flag) {
  const int bf = flag[0];
  int b = blockIdx.x / F_, f = blockIdx.x % F_;
  int tid = threadIdx.x;
  __shared__ float red[256];
  const int base = b * S_ * F_ + f;
  float s = 0.f;
  for (int j = tid; j < S_; j += 256) s += ldin(x, base + j * F_, bf);
  red[tid] = s; __syncthreads();
  for (int w = 128; w; w >>= 1) { if (tid < w) red[tid] += red[tid + w]; __syncthreads(); }
  float mean = red[0] / S_;
  __syncthreads();
  float v = 0.f;
  for (int j = tid; j < S_; j += 256) { float d = ldin(x, base + j * F_, bf) - mean; v += d * d; }
  red[tid] = v; __syncthreads();
  for (int w = 128; w; w >>= 1) { if (tid < w) red[tid] += red[tid + w]; __syncthreads(); }
  float inv = 1.f / (sqrtf(red[0] / (float)(S_ - 1)) + 1e-5f);
  for (int j = tid; j < S_; j += 256) xn[base + j * F_] = (ldin(x, base + j * F_, bf) - mean) * inv;
}

// ---------------- positional-encoding + bias + freq-emb add-table [S][D] -----------
__global__ __launch_bounds__(256) void pe_kernel(const void* __restrict__ bp,
                                                 const void* __restrict__ femb,
                                                 const int* __restrict__ freq_idx,
                                                 float* __restrict__ addtab,
                                                 const int* __restrict__ flag) {
  const int bf = flag[0];
  int idx = blockIdx.x * 256 + threadIdx.x;      // S*D/2 threads
  int dp = idx & (D_ / 2 - 1);
  int s  = idx / (D_ / 2);
  int d0 = dp * 2;
  int fi = freq_idx[0];
  const float cexp = -9.2103403719761836f / (float)D_;
  float ang = (float)s * expf((float)d0 * cexp);
  float sv, cv;
  sincosf(ang, &sv, &cv);
  addtab[(size_t)s * D_ + d0]     = sv + ldin(bp, d0, bf)     + ldin(femb, (size_t)fi * D_ + d0, bf);
  addtab[(size_t)s * D_ + d0 + 1] = cv + ldin(bp, d0 + 1, bf) + ldin(femb, (size_t)fi * D_ + d0 + 1, bf);
}

// ---------------- input projection: xn @ Wp^T + addtab -----------------------------
constexpr int IPG_ = 8;   // tokens per block
__global__ __launch_bounds__(256) void input_proj_kernel(const float* __restrict__ xn,
                                                         const void* __restrict__ Wp,
                                                         const float* __restrict__ addtab,
                                                         float* __restrict__ h,
                                                         bf16* __restrict__ hb16,
                                                         const int* __restrict__ flag) {
  const int bf = flag[0];
  const int tid = threadIdx.x;
  const int d0 = tid * 2;
  const int tbase = blockIdx.x * IPG_;
  float wp0[8], wp1[8];
  if (bf) {
    short8 w0 = *(const short8*)((const bf16*)Wp + (size_t)d0 * F_);
    short8 w1 = *(const short8*)((const bf16*)Wp + (size_t)(d0 + 1) * F_);
#pragma unroll
    for (int f = 0; f < 8; f++) {
      unsigned short u0 = (unsigned short)w0[f], u1 = (unsigned short)w1[f];
      wp0[f] = __bfloat162float(*(bf16*)&u0);
      wp1[f] = __bfloat162float(*(bf16*)&u1);
    }
  } else {
    const float* wpf = (const float*)Wp + (size_t)d0 * F_;
    f32x4 a = *(const f32x4*)(wpf);
    f32x4 b = *(const f32x4*)(wpf + 4);
    f32x4 c = *(const f32x4*)(wpf + 8);
    f32x4 d = *(const f32x4*)(wpf + 12);
#pragma unroll
    for (int f = 0; f < 4; f++) { wp0[f] = a[f]; wp0[4 + f] = b[f]; wp1[f] = c[f]; wp1[4 + f] = d[f]; }
  }
#pragma unroll
  for (int g = 0; g < IPG_; g++) {
    int t = tbase + g;
    int s = t & (S_ - 1);
    const float* xr = xn + (size_t)t * F_;
    f32x4 x0 = *(const f32x4*)xr;
    f32x4 x1 = *(const f32x4*)(xr + 4);
    const float2 at = *(const float2*)(addtab + (size_t)s * D_ + d0);
    float a0 = at.x, a1 = at.y;
#pragma unroll
    for (int f = 0; f < 4; f++) { a0 += x0[f] * wp0[f]; a1 += x0[f] * wp1[f]; }
#pragma unroll
    for (int f = 0; f < 4; f++) { a0 += x1[f] * wp0[4 + f]; a1 += x1[f] * wp1[4 + f]; }
    *(float2*)(h + (size_t)t * D_ + d0) = make_float2(a0, a1);
    bf16 b0 = __float2bfloat16(a0), b1 = __float2bfloat16(a1);
    unsigned pk = (unsigned)(*(unsigned short*)&b0) | ((unsigned)(*(unsigned short*)&b1) << 16);
    *(unsigned*)(hb16 + (size_t)t * D_ + d0) = pk;
  }
}

// ---------------- dense MFMA GEMM, 128x128, 3-stage counted-vmcnt pipeline ----------
template <int MODE>
__global__ __launch_bounds__(256) void mfma_gemm(
    const bf16* __restrict__ A, const bf16* __restrict__ Wt,
    const void* __restrict__ bias, size_t boff, void* __restrict__ C_,
    int Kd, int lda, int ldb, int ldc, const int* __restrict__ flag) {
  const int wbf = flag[0];
  __shared__ bf16 As[3][128][32];
  __shared__ bf16 Bs[3][128][32];
  const int tid = threadIdx.x;
  const int ln = tid & 63, wv = tid >> 6;
  int id = blockIdx.x + gridDim.x * blockIdx.y;
  int xcd = id & 7, idq = id >> 3;
  const int n0 = (idq % gridDim.x) * 128;
  const int m0 = (xcd + 8 * (idq / gridDim.x)) * 128;
  const int wr = (wv >> 1) * 64, wc = (wv & 1) * 64;
  const int mrow = ln & 15, quad = ln >> 4;
  const int srow = ln >> 2;
  const int skof = (ln & 3) * 8;
  const int kchunk = Kd / gridDim.z;
  const int kbeg = blockIdx.z * kchunk;
  const int kend = kbeg + kchunk;

  auto stage = [&](int pb, int k0) {
#pragma unroll
    for (int j = 0; j < 2; j++) {
      int row = 16 * (4 * j + wv) + srow;
      gload16(A + (size_t)(m0 + row) * lda + k0 + skof,
              (char*)&As[pb][0][0] + (size_t)(4 * j + wv) * 1024);
    }
#pragma unroll
    for (int j = 0; j < 2; j++) {
      int row = 16 * (4 * j + wv) + srow;
      gload16(Wt + (size_t)(n0 + row) * ldb + k0 + skof,
              (char*)&Bs[pb][0][0] + (size_t)(4 * j + wv) * 1024);
    }
  };

  f32x4 acc[4][4];
#pragma unroll
  for (int i = 0; i < 4; i++)
#pragma unroll
    for (int j = 0; j < 4; j++) acc[i][j] = (f32x4){0.f, 0.f, 0.f, 0.f};

  stage(0, kbeg);
  stage(1, kbeg + 32);
  int p = 0;
  for (int k0 = kbeg; k0 < kend; k0 += 32) {
    if (k0 + 32 < kend) asm volatile("s_waitcnt vmcnt(4)" ::: "memory");
    else                asm volatile("s_waitcnt vmcnt(0)" ::: "memory");
    __builtin_amdgcn_s_barrier();
    __builtin_amdgcn_sched_barrier(0);
    short8 af[4], bfr[4];
#pragma unroll
    for (int t = 0; t < 4; t++) {
      af[t]  = *(const short8*)&As[p][wr + t * 16 + mrow][quad * 8];
      bfr[t] = *(const short8*)&Bs[p][wc + t * 16 + mrow][quad * 8];
    }
    if (k0 + 64 < kend) {
      int ps = (p == 0) ? 2 : p - 1;   // (p+2)%3
      stage(ps, k0 + 64);
    }
#pragma unroll
    for (int i = 0; i < 4; i++)
#pragma unroll
      for (int j = 0; j < 4; j++)
        acc[i][j] = __builtin_amdgcn_mfma_f32_16x16x32_bf16(af[i], bfr[j], acc[i][j], 0, 0, 0);
    p = (p == 2) ? 0 : p + 1;
  }

  bf16* slice = (MODE == 0) ? (bf16*)C_ + (size_t)blockIdx.z * T_ * D_ : (bf16*)C_;
#pragma unroll
  for (int tj = 0; tj < 4; tj++) {
    int n = n0 + wc + tj * 16 + mrow;
    float bv = (MODE == 3) ? ldin(bias, boff + n, wbf) : 0.f;
#pragma unroll
    for (int ti = 0; ti < 4; ti++) {
      int mbase = m0 + wr + ti * 16 + quad * 4;
#pragma unroll
      for (int r = 0; r < 4; r++) {
        int m = mbase + r;
        float v = acc[ti][tj][r];
        slice[(size_t)m * ldc + n] = __float2bfloat16(MODE == 3 ? v + bv : v);
      }
    }
  }
}

// ---------------- MFMA flash attention: 128-q tile, 8 waves, swapped QK^T ----------
// 512-thread blocks: one K/V stage + barrier pair serves 128 q-rows (2x amortization
// vs 64-q/256-thr). Per-thread staging: 1 K short8 + 1 V short8 (scattered). Grid
// 512 = 2 blocks/CU x 8 waves = 16 waves/CU (same wave pool as before). P region of
// QP is wave-private (rows wv*16..). T14 reg-prefetch + T5 setprio retained.
__global__ __launch_bounds__(512) void attn_kernel(const bf16* __restrict__ qkv,
                                                   bf16* __restrict__ o) {
  __shared__ bf16 QP[128][72];   // Q tile, then P tile (aliased)
  __shared__ bf16 Ks[64][72];
  __shared__ bf16 Vt[64][72];    // [d][k ^ swz(d)]
  const int tid = threadIdx.x;
  const int ln = tid & 63, wv = tid >> 6;          // wv 0..7
  const int mrow = ln & 15, quad = ln >> 4;
  const int id = blockIdx.x;
  const int xcd = id & 7, j = id >> 3;
  const int qt = j & 7;                            // 8 q-tiles of 128
  const int pr = xcd + 8 * (j >> 3);               // 0..63
  const int hh = pr & 7, b = pr >> 3;
  const int q0 = qt * 128;
  const int sr = tid >> 3;                         // 0..63 staging row
  const int sg8 = tid & 7;                         // 0..7 col group
  const int sc = sg8 * 8;
  const int colv = sr ^ ((sg8 & 3) << 4);          // V transpose swizzled col

  {
    const int qr = tid >> 2;                       // 0..127
    const int qc = (tid & 3) * 16;
    const bf16* src = qkv + (size_t)(b * S_ + q0 + qr) * D3_ + hh * 64 + qc;
    *(short8*)&QP[qr][qc]     = *(const short8*)(src);
    *(short8*)&QP[qr][qc + 8] = *(const short8*)(src + 8);
  }
  __syncthreads();
  short8 aq[2];
  aq[0] = *(const short8*)&QP[wv * 16 + mrow][quad * 8];
  aq[1] = *(const short8*)&QP[wv * 16 + mrow][quad * 8 + 32];

  float m_st = -1e30f, l_st = 0.f;
  f32x4 oacc[4];
#pragma unroll
  for (int t = 0; t < 4; t++) oacc[t] = (f32x4){0.f, 0.f, 0.f, 0.f};

  // prologue: prefetch tile 0 K/V into registers
  short8 kA, vA;
  {
    kA = *(const short8*)(qkv + (size_t)(b * S_ + sr) * D3_ + D_ + hh * 64 + sc);
    vA = *(const short8*)(qkv + (size_t)(b * S_ + sr) * D3_ + 2 * D_ + hh * 64 + sc);
  }

  for (int kt = 0; kt < 16; kt++) {
    __builtin_amdgcn_s_barrier();          // all waves done reading previous tile
    *(short8*)&Ks[sr][sc] = kA;
#pragma unroll
    for (int u = 0; u < 8; u++) *(short*)&Vt[sc + u][colv] = vA[u];
    if (kt + 1 < 16) {
      int k0n = (kt + 1) * 64;
      kA = *(const short8*)(qkv + (size_t)(b * S_ + k0n + sr) * D3_ + D_ + hh * 64 + sc);
      vA = *(const short8*)(qkv + (size_t)(b * S_ + k0n + sr) * D3_ + 2 * D_ + hh * 64 + sc);
    }
    asm volatile("s_waitcnt lgkmcnt(0)" ::: "memory");   // ds_writes visible; vmcnt NOT drained
    __builtin_amdgcn_s_barrier();
    __builtin_amdgcn_sched_barrier(0);
    // swapped QK^T: sT[t] row = k_local (quad*4+r), col = q (mrow)
    f32x4 s[4];
    __builtin_amdgcn_s_setprio(1);
#pragma unroll
    for (int t = 0; t < 4; t++) {
      s[t] = (f32x4){0.f, 0.f, 0.f, 0.f};
#pragma unroll
      for (int ks = 0; ks < 2; ks++) {
        short8 bk = *(const short8*)&Ks[t * 16 + mrow][quad * 8 + ks * 32];
        s[t] = __builtin_amdgcn_mfma_f32_16x16x32_bf16(bk, aq[ks], s[t], 0, 0, 0);
      }
    }
    __builtin_amdgcn_s_setprio(0);
    float rm = s[0][0];
#pragma unroll
    for (int t = 0; t < 4; t++)
#pragma unroll
      for (int r = 0; r < 4; r++) rm = fmaxf(rm, s[t][r]);
    rm *= 0.125f;
    rm = fmaxf(rm, __shfl_xor(rm, 16, 64));
    rm = fmaxf(rm, __shfl_xor(rm, 32, 64));
    float mnew = fmaxf(m_st, rm);
    float alpha = __expf(m_st - mnew);
    m_st = mnew;
    float rs = 0.f;
#pragma unroll
    for (int t = 0; t < 4; t++) {
      s4v pk;
#pragma unroll
      for (int r = 0; r < 4; r++) {
        float p = __expf(s[t][r] * 0.125f - mnew);
        rs += p;
        bf16 tb = __float2bfloat16(p);
        pk[r] = *(short*)&tb;
      }
      *(s4v*)&QP[wv * 16 + mrow][t * 16 + quad * 4] = pk;
    }
    rs += __shfl_xor(rs, 16, 64);
    rs += __shfl_xor(rs, 32, 64);
    l_st = l_st * alpha + rs;
    float af4[4];
#pragma unroll
    for (int r = 0; r < 4; r++) af4[r] = __shfl(alpha, quad * 4 + r, 64);
#pragma unroll
    for (int t = 0; t < 4; t++)
#pragma unroll
      for (int r = 0; r < 4; r++) oacc[t][r] *= af4[r];
    short8 ap[2];
    ap[0] = *(const short8*)&QP[wv * 16 + mrow][quad * 8];
    ap[1] = *(const short8*)&QP[wv * 16 + mrow][quad * 8 + 32];
    __builtin_amdgcn_s_setprio(1);
#pragma unroll
    for (int t = 0; t < 4; t++) {
      int d = t * 16 + mrow;
      int swz = ((d >> 3) & 3) << 4;
#pragma unroll
      for (int ks = 0; ks < 2; ks++) {
        short8 bv = *(const short8*)&Vt[d][(quad * 8 + ks * 32) ^ swz];
        oacc[t] = __builtin_amdgcn_mfma_f32_16x16x32_bf16(ap[ks], bv, oacc[t], 0, 0, 0);
      }
    }
    __builtin_amdgcn_s_setprio(0);
  }
  float linv[4];
#pragma unroll
  for (int r = 0; r < 4; r++) linv[r] = 1.f / __shfl(l_st, quad * 4 + r, 64);
#pragma unroll
  for (int r = 0; r < 4; r++) {
    size_t base = (size_t)(b * S_ + q0 + wv * 16 + quad * 4 + r) * D_ + hh * 64;
#pragma unroll
    for (int t = 0; t < 4; t++)
      o[base + t * 16 + mrow] = __float2bfloat16(oacc[t][r] * linv[r]);
  }
}

// ---------------- fused: sum partial slices + bias + residual + LayerNorm ----------
__global__ __launch_bounds__(256) void reduce_ln_kernel(float* __restrict__ h,
                                                        bf16* __restrict__ hb16,
                                                        const bf16* __restrict__ ps,
                                                        int nsl, int mode,
                                                        const void* __restrict__ bias,
                                                        size_t boff,
                                                        const float* __restrict__ cw,
                                                        const void* __restrict__ eb2p,
                                                        size_t e2off,
                                                        const void* __restrict__ g,
                                                        const void* __restrict__ beta,
                                                        size_t off,
                                                        const int* __restrict__ flag) {
  const int bf = flag[0];
  int t = blockIdx.x, tid = threadIdx.x;
  __shared__ float r1[256], r2[256];
  const size_t base = (size_t)t * D_;
  float o0 = 0.f, o1 = 0.f;
  for (int s = 0; s < nsl; s++) {
    o0 += b2f(ps[(size_t)s * T_ * D_ + base + tid]);
    o1 += b2f(ps[(size_t)s * T_ * D_ + base + tid + 256]);
  }
  if (mode == 0) {
    o0 += ldin(bias, boff + tid, bf);
    o1 += ldin(bias, boff + tid + 256, bf);
  } else {
#pragma unroll
    for (int e = 0; e < 4; e++) {
      float w = cw[t * 4 + e];
      o0 += w * ldin(eb2p, e2off + e * D_ + tid, bf);
      o1 += w * ldin(eb2p, e2off + e * D_ + tid + 256, bf);
    }
  }
  float* hr = h + base;
  float v0 = hr[tid] + o0;
  float v1 = hr[tid + 256] + o1;
  r1[tid] = v0 + v1;
  r2[tid] = v0 * v0 + v1 * v1;
  __syncthreads();
  for (int w = 128; w; w >>= 1) { if (tid < w) { r1[tid] += r1[tid + w]; r2[tid] += r2[tid + w]; } __syncthreads(); }
  float mean = r1[0] * (1.f / D_);
  float var  = r2[0] * (1.f / D_) - mean * mean;
  float rstd = rsqrtf(var + 1e-5f);
  float n0 = (v0 - mean) * rstd * ldin(g, off + tid, bf) + ldin(beta, off + tid, bf);
  float n1 = (v1 - mean) * rstd * ldin(g, off + tid + 256, bf) + ldin(beta, off + tid + 256, bf);
  hr[tid] = n0;
  hr[tid + 256] = n1;
  hb16[base + tid] = __float2bfloat16(n0);
  hb16[base + tid + 256] = __float2bfloat16(n1);
}

// ---------------- MoE gating: softmax over E=4, top-2; emits routing info ----------
__global__ __launch_bounds__(256) void gate_kernel(const float* __restrict__ hbuf,
                                                   const void* __restrict__ gw, size_t gwoff,
                                                   const void* __restrict__ gb, size_t gboff,
                                                   float* __restrict__ cw,
                                                   int* __restrict__ einfo,
                                                   float* __restrict__ w0a,
                                                   float* __restrict__ w1a,
                                                   const int* __restrict__ flag) {
  const int bf = flag[0];
  int lane = threadIdx.x & 63, wv = threadIdx.x >> 6;
  int t = blockIdx.x * 4 + wv;
  const float* xr = hbuf + (size_t)t * D_;
  float a[4] = {0, 0, 0, 0};
  for (int d = lane; d < D_; d += 64) {
    float xv = xr[d];
#pragma unroll
    for (int e = 0; e < 4; e++) a[e] += xv * ldin(gw, gwoff + e * D_ + d, bf);
  }
#pragma unroll
  for (int e = 0; e < 4; e++)
    for (int off = 32; off; off >>= 1) a[e] += __shfl_xor(a[e], off, 64);
  if (lane == 0) {
    float lg[4];
#pragma unroll
    for (int e = 0; e < 4; e++) lg[e] = a[e] + ldin(gb, gboff + e, bf);
    float m = fmaxf(fmaxf(lg[0], lg[1]), fmaxf(lg[2], lg[3]));
    float p[4], s = 0.f;
#pragma unroll
    for (int e = 0; e < 4; e++) { p[e] = __expf(lg[e] - m); s += p[e]; }
#pragma unroll
    for (int e = 0; e < 4; e++) p[e] /= s;
    int i0 = 0;
    for (int e = 1; e < 4; e++) if (p[e] > p[i0]) i0 = e;
    int i1 = -1;
    for (int e = 0; e < 4; e++) if (e != i0 && (i1 < 0 || p[e] > p[i1])) i1 = e;
    float s2 = p[i0] + p[i1];
    float ww0 = p[i0] / s2, ww1 = p[i1] / s2;
    float outw[4] = {0, 0, 0, 0};
    outw[i0] = ww0; outw[i1] = ww1;
#pragma unroll
    for (int e = 0; e < 4; e++) cw[t * 4 + e] = outw[e];
    einfo[t] = i0 | (i1 << 4);
    w0a[t] = ww0; w1a[t] = ww1;
  }
}

// ---------------- route scan: counts -> offsets + tile table (1 block) ----------------
__global__ __launch_bounds__(256) void route_scan_kernel(const int* __restrict__ einfo,
                                                         int* __restrict__ off,
                                                         int* __restrict__ endp,
                                                         int* __restrict__ cur,
                                                         int* __restrict__ tmap) {
  __shared__ int red[4][256];
  int tid = threadIdx.x;
  int c[4] = {0, 0, 0, 0};
  for (int t = tid; t < T_; t += 256) {
    int inf = einfo[t];
    c[inf & 15]++;
    c[(inf >> 4) & 15]++;
  }
#pragma unroll
  for (int e = 0; e < 4; e++) red[e][tid] = c[e];
  __syncthreads();
  for (int w = 128; w; w >>= 1) {
    if (tid < w)
#pragma unroll
      for (int e = 0; e < 4; e++) red[e][tid] += red[e][tid + w];
    __syncthreads();
  }
  if (tid == 0) {
    int o = 0, idx = 0;
#pragma unroll
    for (int e = 0; e < 4; e++) {
      int cnt = red[e][0];
      off[e] = o;
      endp[e] = o + cnt;
      cur[e] = 0;
      int nt = (cnt + 127) >> 7;
      for (int i = 0; i < nt; i++) tmap[1 + idx++] = e | (i << 8);
      o += nt << 7;
    }
    tmap[0] = idx;   // total active m-tiles (<= 131)
  }
}

// ---------------- scatter: token -> (expert bucket, rank), ballot-aggregated --------
__global__ __launch_bounds__(256) void scatter_kernel(const int* __restrict__ einfo,
                                                      const float* __restrict__ w0a,
                                                      const float* __restrict__ w1a,
                                                      const int* __restrict__ off,
                                                      int* __restrict__ cur,
                                                      int* __restrict__ pack,
                                                      float* __restrict__ wlist) {
  int t = blockIdx.x * 256 + threadIdx.x;
  int lane = threadIdx.x & 63;
  int inf = einfo[t];
#pragma unroll
  for (int rank = 0; rank < 2; rank++) {
    int my_e = (rank == 0) ? (inf & 15) : ((inf >> 4) & 15);
    float w = (rank == 0) ? w0a[t] : w1a[t];
#pragma unroll
    for (int e = 0; e < 4; e++) {
      bool p = (my_e == e);
      unsigned long long mask = __ballot(p);
      if (!mask) continue;
      int leader = __ffsll((long long)mask) - 1;
      int base = 0;
      if (lane == leader) base = atomicAdd(&cur[e], (int)__popcll(mask));
      base = __shfl(base, leader, 64);
      if (p) {
        int pos = off[e] + base + (int)__popcll(mask & ((1ULL << lane) - 1ULL));
        pack[pos] = t * 2 + rank;
        wlist[pos] = w;
      }
    }
  }
}

// ---------------- sparse MoE mat1: 128x128, 3-stage counted-vmcnt pipeline ----------
__global__ __launch_bounds__(256) void moe_mat1_kernel(
    const bf16* __restrict__ A, const bf16* __restrict__ Wt,
    const void* __restrict__ bias, size_t boff, bf16* __restrict__ hid,
    const int* __restrict__ off, const int* __restrict__ endp,
    const int* __restrict__ pack, const float* __restrict__ wlist,
    const int* __restrict__ tmap, const int* __restrict__ flag) {
  const int wbf = flag[0];
  int id = blockIdx.x + 8 * blockIdx.y;
  int xcd = id & 7, idq = id >> 3;
  int wx = idq & 7, wy = xcd + 8 * (idq >> 3);
  if (wy >= tmap[0]) return;
  int ent = tmap[1 + wy];
  const int e = ent & 255, mt = ent >> 8;
  const int o = off[e], en = endp[e];
  const int n0 = wx * 128;
  __shared__ bf16 As[3][128][32];
  __shared__ bf16 Bs[3][128][32];
  const int tid = threadIdx.x;
  const int ln = tid & 63, wv = tid >> 6;
  const int m0 = o + mt * 128;
  const int wr = (wv >> 1) * 64, wc = (wv & 1) * 64;
  const int mrow = ln & 15, quad = ln >> 4;
  const int srow = ln >> 2;
  const int skof = (ln & 3) * 8;
  int tokr[2];
#pragma unroll
  for (int j = 0; j < 2; j++) {
    int pos = m0 + 16 * (4 * j + wv) + srow;
    tokr[j] = pack[min(pos, en - 1)] >> 1;
  }
  const size_t wbase = (size_t)e * 1024 * 512;

  auto stage = [&](int pb, int k0) {
#pragma unroll
    for (int j = 0; j < 2; j++)
      gload16(A + (size_t)tokr[j] * 512 + k0 + skof,
              (char*)&As[pb][0][0] + (size_t)(4 * j + wv) * 1024);
#pragma unroll
    for (int j = 0; j < 2; j++) {
      int row = 16 * (4 * j + wv) + srow;
      gload16(Wt + wbase + (size_t)(n0 + row) * 512 + k0 + skof,
              (char*)&Bs[pb][0][0] + (size_t)(4 * j + wv) * 1024);
    }
  };

  f32x4 acc[4][4];
#pragma unroll
  for (int i = 0; i < 4; i++)
#pragma unroll
    for (int j = 0; j < 4; j++) acc[i][j] = (f32x4){0.f, 0.f, 0.f, 0.f};

  stage(0, 0);
  stage(1, 32);
  int p = 0;
  for (int k0 = 0; k0 < 512; k0 += 32) {
    if (k0 + 32 < 512) asm volatile("s_waitcnt vmcnt(4)" ::: "memory");
    else               asm volatile("s_waitcnt vmcnt(0)" ::: "memory");
    __builtin_amdgcn_s_barrier();
    __builtin_amdgcn_sched_barrier(0);
    short8 af[4], bfr[4];
#pragma unroll
    for (int t = 0; t < 4; t++) {
      af[t]  = *(const short8*)&As[p][wr + t * 16 + mrow][quad * 8];
      bfr[t] = *(const short8*)&Bs[p][wc + t * 16 + mrow][quad * 8];
    }
    if (k0 + 64 < 512) {
      int ps = (p == 0) ? 2 : p - 1;
      stage(ps, k0 + 64);
    }
#pragma unroll
    for (int i = 0; i < 4; i++)
#pragma unroll
      for (int j = 0; j < 4; j++)
        acc[i][j] = __builtin_amdgcn_mfma_f32_16x16x32_bf16(af[i], bfr[j], acc[i][j], 0, 0, 0);
    p = (p == 2) ? 0 : p + 1;
  }

#pragma unroll
  for (int ti = 0; ti < 4; ti++) {
#pragma unroll
    for (int r = 0; r < 4; r++) {
      int pos = m0 + wr + ti * 16 + quad * 4 + r;
      float w = (pos < en) ? wlist[pos] : 0.f;
#pragma unroll
      for (int tj = 0; tj < 4; tj++) {
        int ncol = n0 + wc + tj * 16 + mrow;
        float v = acc[ti][tj][r] + ldin(bias, boff + e * 1024 + ncol, wbf);
        hid[(size_t)pos * 1024 + ncol] = __float2bfloat16(fmaxf(v, 0.f) * w);
      }
    }
  }
}

// ---------------- sparse MoE mat2: 128x128, 3-stage counted-vmcnt pipeline, z=2 -----
__global__ __launch_bounds__(256) void moe_mat2_kernel(
    const bf16* __restrict__ hid, const bf16* __restrict__ Wt,
    bf16* __restrict__ psl,
    const int* __restrict__ off, const int* __restrict__ endp,
    const int* __restrict__ pack, const int* __restrict__ tmap,
    const int* __restrict__ flag) {
  int id = blockIdx.x + 4 * blockIdx.y;
  int xcd = id & 7, idq = id >> 3;
  int wx = idq & 3, wy = xcd + 8 * (idq >> 2);
  if (wy >= tmap[0]) return;
  int ent = tmap[1 + wy];
  const int e = ent & 255, mt = ent >> 8;
  const int o = off[e], en = endp[e];
  const int n0 = wx * 128;
  __shared__ bf16 As[3][128][32];
  __shared__ bf16 Bs[3][128][32];
  const int tid = threadIdx.x;
  const int ln = tid & 63, wv = tid >> 6;
  const int m0 = o + mt * 128;
  const int wr = (wv >> 1) * 64, wc = (wv & 1) * 64;
  const int mrow = ln & 15, quad = ln >> 4;
  const int srow = ln >> 2;
  const int skof = (ln & 3) * 8;
  const int kbeg = blockIdx.z * 512;
  const size_t wbase = (size_t)e * 512 * 1024;

  auto stage = [&](int pb, int k0) {
#pragma unroll
    for (int j = 0; j < 2; j++) {
      int row = 16 * (4 * j + wv) + srow;
      gload16(hid + (size_t)(m0 + row) * 1024 + k0 + skof,
              (char*)&As[pb][0][0] + (size_t)(4 * j + wv) * 1024);
    }
#pragma unroll
    for (int j = 0; j < 2; j++) {
      int row = 16 * (4 * j + wv) + srow;
      gload16(Wt + wbase + (size_t)(n0 + row) * 1024 + k0 + skof,
              (char*)&Bs[pb][0][0] + (size_t)(4 * j + wv) * 1024);
    }
  };

  f32x4 acc[4][4];
#pragma unroll
  for (int i = 0; i < 4; i++)
#pragma unroll
    for (int j = 0; j < 4; j++) acc[i][j] = (f32x4){0.f, 0.f, 0.f, 0.f};

  stage(0, kbeg);
  stage(1, kbeg + 32);
  int p = 0;
  for (int k0 = kbeg; k0 < kbeg + 512; k0 += 32) {
    if (k0 + 32 < kbeg + 512) asm volatile("s_waitcnt vmcnt(4)" ::: "memory");
    else                      asm volatile("s_waitcnt vmcnt(0)" ::: "memory");
    __builtin_amdgcn_s_barrier();
    __builtin_amdgcn_sched_barrier(0);
    short8 af[4], bfr[4];
#pragma unroll
    for (int t = 0; t < 4; t++) {
      af[t]  = *(const short8*)&As[p][wr + t * 16 + mrow][quad * 8];
      bfr[t] = *(const short8*)&Bs[p][wc + t * 16 + mrow][quad * 8];
    }
    if (k0 + 64 < kbeg + 512) {
      int ps = (p == 0) ? 2 : p - 1;
      stage(ps, k0 + 64);
    }
#pragma unroll
    for (int i = 0; i < 4; i++)
#pragma unroll
      for (int j = 0; j < 4; j++)
        acc[i][j] = __builtin_amdgcn_mfma_f32_16x16x32_bf16(af[i], bfr[j], acc[i][j], 0, 0, 0);
    p = (p == 2) ? 0 : p + 1;
  }

#pragma unroll
  for (int ti = 0; ti < 4; ti++) {
#pragma unroll
    for (int r = 0; r < 4; r++) {
      int pos = m0 + wr + ti * 16 + quad * 4 + r;
      if (pos < en) {
        int pk = pack[pos];
        int tok = pk >> 1, rank = pk & 1;
        bf16* dst = psl + (size_t)(rank * 2 + blockIdx.z) * T_ * D_ + (size_t)tok * D_;
#pragma unroll
        for (int tj = 0; tj < 4; tj++) {
          int ncol = n0 + wc + tj * 16 + mrow;
          dst[ncol] = __float2bfloat16(acc[ti][tj][r]);
        }
      }
    }
  }
}

// ---------------- head ----------------
__global__ __launch_bounds__(256) void head_kernel(const float* __restrict__ hbuf,
                                                   const void* __restrict__ hw,
                                                   const void* __restrict__ hb,
                                                   void* __restrict__ out,
                                                   const int* __restrict__ flag) {
  const int bf = flag[0];
  int bq = blockIdx.x, tid = threadIdx.x;
  int b = bq / 3, q = bq % 3;
  __shared__ float red[256];
  const float* xr = hbuf + (size_t)(b * S_ + (S_ - 1)) * D_;
  float sacc = xr[tid] * ldin(hw, (size_t)q * D_ + tid, bf)
             + xr[tid + 256] * ldin(hw, (size_t)q * D_ + tid + 256, bf);
  red[tid] = sacc; __syncthreads();
  for (int w = 128; w; w >>= 1) { if (tid < w) red[tid] += red[tid + w]; __syncthreads(); }
  if (tid == 0) {
    float r = red[0] + ldin(hb, q, bf);
    if (bf) ((bf16*)out)[bq] = __float2bfloat16(r);
    else    ((float*)out)[bq] = r;
  }
}

extern "C" void kernel_launch(void* const* d_in, const int* in_sizes, int n_in,
                              void* d_out, int out_size, void* d_ws, size_t ws_size,
                              hipStream_t stream) {
  const void* x    = d_in[0];
  const void* Wp   = d_in[1];
  const void* bp   = d_in[2];
  const void* femb = d_in[3];
  const void* qkvw = d_in[4];
  const void* qkvb = d_in[5];
  const void* ow   = d_in[6];
  const void* ob   = d_in[7];
  const void* g1   = d_in[8];
  const void* be1  = d_in[9];
  const void* gw   = d_in[10];
  const void* gb   = d_in[11];
  const void* ew1  = d_in[12];
  const void* eb1  = d_in[13];
  const void* ew2  = d_in[14];
  const void* eb2  = d_in[15];
  const void* g2   = d_in[16];
  const void* be2  = d_in[17];
  const void* hw   = d_in[18];
  const void* hb   = d_in[19];
  const int*  freq = (const int*)d_in[20];

  // workspace layout: peak ~99.6 MB (within previously proven-safe 101 MB)
  int*   flag  = (int*)d_ws;                        // 64 ints
  int*   off   = flag + 64;                         // 4
  int*   endp  = off + 4;                           // 4
  int*   cur   = endp + 4;                          // 4 (+pad)
  int*   einfo = flag + 128;                        // T ints
  float* w0a   = (float*)(einfo + T_);              // T
  float* w1a   = w0a + T_;                          // T
  int*   pack  = (int*)(w1a + T_);                  // CAP ints
  float* wlist = (float*)(pack + CAP_);             // CAP
  int*   tmap  = (int*)(wlist + CAP_);              // 160 ints (count + tiles)
  float* xn    = (float*)(tmap + 160);              // 65536
  float* h     = xn + 65536;                        // T*D f    (16 MB)
  float* cw    = h + (size_t)T_ * D_;               // T*4
  bf16*  hb16  = (bf16*)(cw + (size_t)T_ * E_);     // T*D bf16 (8 MB)
  bf16*  R     = hb16 + (size_t)T_ * D_;            // alias region
  bf16*  qkvb16 = R;                                // T*3D bf16 (24 MB)
  bf16*  ao    = R + (size_t)T_ * D3_;              // T*D bf16  (8 MB)
  bf16*  hid   = R;                                 // CAP*1024 bf16 (~33 MB)
  bf16*  psl   = R + (size_t)CAP_ * 1024;           // 4x T*D bf16 (32 MB partial slices)
  bf16*  wcvt  = psl + (size_t)4 * T_ * D_;         // 8.4 MB bf16 weight scratch
  bf16*  wq    = wcvt;
  bf16*  wo    = wcvt + (size_t)D3_ * D_;
  bf16*  we1   = wcvt;
  bf16*  we2   = wcvt + (size_t)E_ * 1024 * 512;
  float* addtab = (float*)R;                        // [S][D] f32 PE table (dead before QKV GEMM)

  constexpr size_t NQ = (size_t)D3_ * D_;           // 786432
  constexpr size_t NO = (size_t)D_ * D_;            // 262144
  constexpr size_t NE = (size_t)E_ * 1024 * 512;    // 2097152

  detect_kernel<<<1, 64, 0, stream>>>(x, flag);
  instnorm_kernel<<<B_ * F_, 256, 0, stream>>>(x, xn, flag);
  pe_kernel<<<(S_ * D_ / 2) / 256, 256, 0, stream>>>(bp, femb, freq, addtab, flag);
  input_proj_kernel<<<T_ / IPG_, 256, 0, stream>>>(xn, Wp, addtab, h, hb16, flag);

  for (int l = 0; l < 3; l++) {
    // convert this layer's qkv_w + ow to bf16 scratch (copy if already bf16)
    convw_kernel<<<(NQ + NO) / 2048, 256, 0, stream>>>(
        qkvw, (size_t)l * NQ, NQ, ow, (size_t)l * NO, wcvt, flag);
    // QKV projection -> bf16
    mfma_gemm<3><<<dim3(D3_ / 128, T_ / 128), 256, 0, stream>>>(
        hb16, wq, qkvb, (size_t)l * D3_, qkvb16, D_, D_, D_, D3_, flag);
    attn_kernel<<<B_ * H_ * (S_ / 128), 512, 0, stream>>>(qkvb16, ao);
    // O-projection: split-K=2 -> slices 0,1; fused reduce + bias + LN
    mfma_gemm<0><<<dim3(D_ / 128, T_ / 128, 2), 256, 0, stream>>>(
        ao, wo, nullptr, 0, psl, D_, D_, D_, D_, flag);
    reduce_ln_kernel<<<T_, 256, 0, stream>>>(
        h, hb16, psl, 2, 0, ob, (size_t)l * D_, nullptr, nullptr, 0,
        g1, be1, (size_t)l * D_, flag);
    // gating + routing
    gate_kernel<<<T_ / 4, 256, 0, stream>>>(h, gw, (size_t)l * E_ * D_, gb, (size_t)l * E_,
                                            cw, einfo, w0a, w1a, flag);
    route_scan_kernel<<<1, 256, 0, stream>>>(einfo, off, endp, cur, tmap);
    scatter_kernel<<<T_ / 256, 256, 0, stream>>>(einfo, w0a, w1a, off, cur, pack, wlist);
    // convert this layer's ew1 + ew2 to bf16 scratch (wq/wo dead past here)
    convw_kernel<<<(NE + NE) / 2048, 256, 0, stream>>>(
        ew1, (size_t)l * NE, NE, ew2, (size_t)l * NE, wcvt, flag);
    // sparse expert GEMMs (hid aliases qkv+ao, both dead here)
    moe_mat1_kernel<<<dim3(8, 136), 256, 0, stream>>>(
        hb16, we1, eb1, (size_t)l * E_ * 1024, hid,
        off, endp, pack, wlist, tmap, flag);
    moe_mat2_kernel<<<dim3(4, 136, 2), 256, 0, stream>>>(
        hid, we2, psl, off, endp, pack, tmap, flag);
    reduce_ln_kernel<<<T_, 256, 0, stream>>>(
        h, hb16, psl, 4, 1, nullptr, 0, cw, eb2, (size_t)l * E_ * D_,
        g2, be2, (size_t)l * D_, flag);
  }

  head_kernel<<<24, 256, 0, stream>>>(h, hw, hb, d_out, flag);
}

// Round 11
// 824.737 us; speedup vs baseline: 1.3276x; 1.0032x over previous
//
#include <hip/hip_runtime.h>
#include <hip/hip_bf16.h>
#include <math.h>

typedef __hip_bfloat16 bf16;
typedef __attribute__((ext_vector_type(8))) short short8;   // 8 bf16 (4 VGPRs)
typedef __attribute__((ext_vector_type(4))) short s4v;      // 4 bf16 (8 bytes)
typedef __attribute__((ext_vector_type(4))) float f32x4;

constexpr int B_ = 8, S_ = 1024, F_ = 8, D_ = 512, H_ = 8, E_ = 4;
constexpr int T_  = B_ * S_;       // 8192 tokens
constexpr int D3_ = 3 * D_;        // 1536
constexpr int CAP_ = T_ * 2 + E_ * 128;   // sparse row capacity (top-2, 128-pad/expert)

__device__ __forceinline__ float b2f(bf16 v) { return __bfloat162float(v); }
__device__ __forceinline__ float ldin(const void* p, size_t i, int bf) {
  return bf ? __bfloat162float(((const bf16*)p)[i]) : ((const float*)p)[i];
}
__device__ __forceinline__ void gload16(const void* g, void* l) {
  __builtin_amdgcn_global_load_lds((const __attribute__((address_space(1))) unsigned int*)g,
                                   (__attribute__((address_space(3))) unsigned int*)l, 16, 0, 0);
}

// ---------------- dtype detector ----------------
__global__ void detect_kernel(const void* __restrict__ x, int* __restrict__ flag) {
  if (threadIdx.x == 0 && blockIdx.x == 0) {
    const unsigned short* u = (const unsigned short*)x;
    int c = 0;
    for (int i = 0; i < 256; i += 2) {
      int ex = (u[i] >> 7) & 0xFF;
      if (ex >= 96 && ex <= 144) c++;
    }
    flag[0] = (c >= 64) ? 1 : 0;
  }
}

// ---------------- weight pre-convert: fp32 (or bf16 copy) -> bf16 scratch ----------
__global__ __launch_bounds__(256) void convw_kernel(const void* __restrict__ Asrc, size_t offA,
                                                    size_t nA,
                                                    const void* __restrict__ Bsrc, size_t offB,
                                                    bf16* __restrict__ dst,
                                                    const int* __restrict__ flag) {
  const int bf = flag[0];
  size_t i = ((size_t)blockIdx.x * 256 + threadIdx.x) * 8;
  const void* s = Asrc;
  size_t so = offA + i;
  if (i >= nA) { s = Bsrc; so = offB + (i - nA); }
  if (bf) {
    *(short8*)(dst + i) = *(const short8*)((const bf16*)s + so);
  } else {
    const float* sp = (const float*)s + so;
    short8 v;
#pragma unroll
    for (int u = 0; u < 8; u++) { bf16 t = __float2bfloat16(sp[u]); v[u] = *(short*)&t; }
    *(short8*)(dst + i) = v;
  }
}

// ---------------- instance norm over time axis ----------------
__global__ __launch_bounds__(256) void instnorm_kernel(const void* __restrict__ x,
                                                       float* __restrict__ xn,
                                                       const int* __restrict__ flag) {
  const int bf = flag[0];
  int b = blockIdx.x / F_, f = blockIdx.x % F_;
  int tid = threadIdx.x;
  __shared__ float red[256];
  const int base = b * S_ * F_ + f;
  float s = 0.f;
  for (int j = tid; j < S_; j += 256) s += ldin(x, base + j * F_, bf);
  red[tid] = s; __syncthreads();
  for (int w = 128; w; w >>= 1) { if (tid < w) red[tid] += red[tid + w]; __syncthreads(); }
  float mean = red[0] / S_;
  __syncthreads();
  float v = 0.f;
  for (int j = tid; j < S_; j += 256) { float d = ldin(x, base + j * F_, bf) - mean; v += d * d; }
  red[tid] = v; __syncthreads();
  for (int w = 128; w; w >>= 1) { if (tid < w) red[tid] += red[tid + w]; __syncthreads(); }
  float inv = 1.f / (sqrtf(red[0] / (float)(S_ - 1)) + 1e-5f);
  for (int j = tid; j < S_; j += 256) xn[base + j * F_] = (ldin(x, base + j * F_, bf) - mean) * inv;
}

// ---------------- positional-encoding + bias + freq-emb add-table [S][D] -----------
__global__ __launch_bounds__(256) void pe_kernel(const void* __restrict__ bp,
                                                 const void* __restrict__ femb,
                                                 const int* __restrict__ freq_idx,
                                                 float* __restrict__ addtab,
                                                 const int* __restrict__ flag) {
  const int bf = flag[0];
  int idx = blockIdx.x * 256 + threadIdx.x;      // S*D/2 threads
  int dp = idx & (D_ / 2 - 1);
  int s  = idx / (D_ / 2);
  int d0 = dp * 2;
  int fi = freq_idx[0];
  const float cexp = -9.2103403719761836f / (float)D_;
  float ang = (float)s * expf((float)d0 * cexp);
  float sv, cv;
  sincosf(ang, &sv, &cv);
  addtab[(size_t)s * D_ + d0]     = sv + ldin(bp, d0, bf)     + ldin(femb, (size_t)fi * D_ + d0, bf);
  addtab[(size_t)s * D_ + d0 + 1] = cv + ldin(bp, d0 + 1, bf) + ldin(femb, (size_t)fi * D_ + d0 + 1, bf);
}

// ---------------- input projection: xn @ Wp^T + addtab -----------------------------
constexpr int IPG_ = 8;   // tokens per block
__global__ __launch_bounds__(256) void input_proj_kernel(const float* __restrict__ xn,
                                                         const void* __restrict__ Wp,
                                                         const float* __restrict__ addtab,
                                                         float* __restrict__ h,
                                                         bf16* __restrict__ hb16,
                                                         const int* __restrict__ flag) {
  const int bf = flag[0];
  const int tid = threadIdx.x;
  const int d0 = tid * 2;
  const int tbase = blockIdx.x * IPG_;
  float wp0[8], wp1[8];
  if (bf) {
    short8 w0 = *(const short8*)((const bf16*)Wp + (size_t)d0 * F_);
    short8 w1 = *(const short8*)((const bf16*)Wp + (size_t)(d0 + 1) * F_);
#pragma unroll
    for (int f = 0; f < 8; f++) {
      unsigned short u0 = (unsigned short)w0[f], u1 = (unsigned short)w1[f];
      wp0[f] = __bfloat162float(*(bf16*)&u0);
      wp1[f] = __bfloat162float(*(bf16*)&u1);
    }
  } else {
    const float* wpf = (const float*)Wp + (size_t)d0 * F_;
    f32x4 a = *(const f32x4*)(wpf);
    f32x4 b = *(const f32x4*)(wpf + 4);
    f32x4 c = *(const f32x4*)(wpf + 8);
    f32x4 d = *(const f32x4*)(wpf + 12);
#pragma unroll
    for (int f = 0; f < 4; f++) { wp0[f] = a[f]; wp0[4 + f] = b[f]; wp1[f] = c[f]; wp1[4 + f] = d[f]; }
  }
#pragma unroll
  for (int g = 0; g < IPG_; g++) {
    int t = tbase + g;
    int s = t & (S_ - 1);
    const float* xr = xn + (size_t)t * F_;
    f32x4 x0 = *(const f32x4*)xr;
    f32x4 x1 = *(const f32x4*)(xr + 4);
    const float2 at = *(const float2*)(addtab + (size_t)s * D_ + d0);
    float a0 = at.x, a1 = at.y;
#pragma unroll
    for (int f = 0; f < 4; f++) { a0 += x0[f] * wp0[f]; a1 += x0[f] * wp1[f]; }
#pragma unroll
    for (int f = 0; f < 4; f++) { a0 += x1[f] * wp0[4 + f]; a1 += x1[f] * wp1[4 + f]; }
    *(float2*)(h + (size_t)t * D_ + d0) = make_float2(a0, a1);
    bf16 b0 = __float2bfloat16(a0), b1 = __float2bfloat16(a1);
    unsigned pk = (unsigned)(*(unsigned short*)&b0) | ((unsigned)(*(unsigned short*)&b1) << 16);
    *(unsigned*)(hb16 + (size_t)t * D_ + d0) = pk;
  }
}

// ---------------- dense MFMA GEMM, 128x128, 3-stage counted-vmcnt pipeline ----------
template <int MODE>
__global__ __launch_bounds__(256) void mfma_gemm(
    const bf16* __restrict__ A, const bf16* __restrict__ Wt,
    const void* __restrict__ bias, size_t boff, void* __restrict__ C_,
    int Kd, int lda, int ldb, int ldc, const int* __restrict__ flag) {
  const int wbf = flag[0];
  __shared__ bf16 As[3][128][32];
  __shared__ bf16 Bs[3][128][32];
  const int tid = threadIdx.x;
  const int ln = tid & 63, wv = tid >> 6;
  int id = blockIdx.x + gridDim.x * blockIdx.y;
  int xcd = id & 7, idq = id >> 3;
  const int n0 = (idq % gridDim.x) * 128;
  const int m0 = (xcd + 8 * (idq / gridDim.x)) * 128;
  const int wr = (wv >> 1) * 64, wc = (wv & 1) * 64;
  const int mrow = ln & 15, quad = ln >> 4;
  const int srow = ln >> 2;
  const int skof = (ln & 3) * 8;
  const int kchunk = Kd / gridDim.z;
  const int kbeg = blockIdx.z * kchunk;
  const int kend = kbeg + kchunk;

  auto stage = [&](int pb, int k0) {
#pragma unroll
    for (int j = 0; j < 2; j++) {
      int row = 16 * (4 * j + wv) + srow;
      gload16(A + (size_t)(m0 + row) * lda + k0 + skof,
              (char*)&As[pb][0][0] + (size_t)(4 * j + wv) * 1024);
    }
#pragma unroll
    for (int j = 0; j < 2; j++) {
      int row = 16 * (4 * j + wv) + srow;
      gload16(Wt + (size_t)(n0 + row) * ldb + k0 + skof,
              (char*)&Bs[pb][0][0] + (size_t)(4 * j + wv) * 1024);
    }
  };

  f32x4 acc[4][4];
#pragma unroll
  for (int i = 0; i < 4; i++)
#pragma unroll
    for (int j = 0; j < 4; j++) acc[i][j] = (f32x4){0.f, 0.f, 0.f, 0.f};

  stage(0, kbeg);
  stage(1, kbeg + 32);
  int p = 0;
  for (int k0 = kbeg; k0 < kend; k0 += 32) {
    if (k0 + 32 < kend) asm volatile("s_waitcnt vmcnt(4)" ::: "memory");
    else                asm volatile("s_waitcnt vmcnt(0)" ::: "memory");
    __builtin_amdgcn_s_barrier();
    __builtin_amdgcn_sched_barrier(0);
    short8 af[4], bfr[4];
#pragma unroll
    for (int t = 0; t < 4; t++) {
      af[t]  = *(const short8*)&As[p][wr + t * 16 + mrow][quad * 8];
      bfr[t] = *(const short8*)&Bs[p][wc + t * 16 + mrow][quad * 8];
    }
    if (k0 + 64 < kend) {
      int ps = (p == 0) ? 2 : p - 1;   // (p+2)%3
      stage(ps, k0 + 64);
    }
#pragma unroll
    for (int i = 0; i < 4; i++)
#pragma unroll
      for (int j = 0; j < 4; j++)
        acc[i][j] = __builtin_amdgcn_mfma_f32_16x16x32_bf16(af[i], bfr[j], acc[i][j], 0, 0, 0);
    p = (p == 2) ? 0 : p + 1;
  }

  bf16* slice = (MODE == 0) ? (bf16*)C_ + (size_t)blockIdx.z * T_ * D_ : (bf16*)C_;
#pragma unroll
  for (int tj = 0; tj < 4; tj++) {
    int n = n0 + wc + tj * 16 + mrow;
    float bv = (MODE == 3) ? ldin(bias, boff + n, wbf) : 0.f;
#pragma unroll
    for (int ti = 0; ti < 4; ti++) {
      int mbase = m0 + wr + ti * 16 + quad * 4;
#pragma unroll
      for (int r = 0; r < 4; r++) {
        int m = mbase + r;
        float v = acc[ti][tj][r];
        slice[(size_t)m * ldc + n] = __float2bfloat16(MODE == 3 ? v + bv : v);
      }
    }
  }
}

// ---------------- MFMA flash attention: 128-q tile, 8 waves, swapped QK^T ----------
__global__ __launch_bounds__(512) void attn_kernel(const bf16* __restrict__ qkv,
                                                   bf16* __restrict__ o) {
  __shared__ bf16 QP[128][72];   // Q tile, then P tile (aliased)
  __shared__ bf16 Ks[64][72];
  __shared__ bf16 Vt[64][72];    // [d][k ^ swz(d)]
  const int tid = threadIdx.x;
  const int ln = tid & 63, wv = tid >> 6;          // wv 0..7
  const int mrow = ln & 15, quad = ln >> 4;
  const int id = blockIdx.x;
  const int xcd = id & 7, j = id >> 3;
  const int qt = j & 7;                            // 8 q-tiles of 128
  const int pr = xcd + 8 * (j >> 3);               // 0..63
  const int hh = pr & 7, b = pr >> 3;
  const int q0 = qt * 128;
  const int sr = tid >> 3;                         // 0..63 staging row
  const int sg8 = tid & 7;                         // 0..7 col group
  const int sc = sg8 * 8;
  const int colv = sr ^ ((sg8 & 3) << 4);          // V transpose swizzled col

  {
    const int qr = tid >> 2;                       // 0..127
    const int qc = (tid & 3) * 16;
    const bf16* src = qkv + (size_t)(b * S_ + q0 + qr) * D3_ + hh * 64 + qc;
    *(short8*)&QP[qr][qc]     = *(const short8*)(src);
    *(short8*)&QP[qr][qc + 8] = *(const short8*)(src + 8);
  }
  __syncthreads();
  short8 aq[2];
  aq[0] = *(const short8*)&QP[wv * 16 + mrow][quad * 8];
  aq[1] = *(const short8*)&QP[wv * 16 + mrow][quad * 8 + 32];

  float m_st = -1e30f, l_st = 0.f;
  f32x4 oacc[4];
#pragma unroll
  for (int t = 0; t < 4; t++) oacc[t] = (f32x4){0.f, 0.f, 0.f, 0.f};

  // prologue: prefetch tile 0 K/V into registers
  short8 kA, vA;
  {
    kA = *(const short8*)(qkv + (size_t)(b * S_ + sr) * D3_ + D_ + hh * 64 + sc);
    vA = *(const short8*)(qkv + (size_t)(b * S_ + sr) * D3_ + 2 * D_ + hh * 64 + sc);
  }

  for (int kt = 0; kt < 16; kt++) {
    __builtin_amdgcn_s_barrier();          // all waves done reading previous tile
    *(short8*)&Ks[sr][sc] = kA;
#pragma unroll
    for (int u = 0; u < 8; u++) *(short*)&Vt[sc + u][colv] = vA[u];
    if (kt + 1 < 16) {
      int k0n = (kt + 1) * 64;
      kA = *(const short8*)(qkv + (size_t)(b * S_ + k0n + sr) * D3_ + D_ + hh * 64 + sc);
      vA = *(const short8*)(qkv + (size_t)(b * S_ + k0n + sr) * D3_ + 2 * D_ + hh * 64 + sc);
    }
    asm volatile("s_waitcnt lgkmcnt(0)" ::: "memory");   // ds_writes visible; vmcnt NOT drained
    __builtin_amdgcn_s_barrier();
    __builtin_amdgcn_sched_barrier(0);
    // swapped QK^T: sT[t] row = k_local (quad*4+r), col = q (mrow)
    f32x4 s[4];
    __builtin_amdgcn_s_setprio(1);
#pragma unroll
    for (int t = 0; t < 4; t++) {
      s[t] = (f32x4){0.f, 0.f, 0.f, 0.f};
#pragma unroll
      for (int ks = 0; ks < 2; ks++) {
        short8 bk = *(const short8*)&Ks[t * 16 + mrow][quad * 8 + ks * 32];
        s[t] = __builtin_amdgcn_mfma_f32_16x16x32_bf16(bk, aq[ks], s[t], 0, 0, 0);
      }
    }
    __builtin_amdgcn_s_setprio(0);
    float rm = s[0][0];
#pragma unroll
    for (int t = 0; t < 4; t++)
#pragma unroll
      for (int r = 0; r < 4; r++) rm = fmaxf(rm, s[t][r]);
    rm *= 0.125f;
    rm = fmaxf(rm, __shfl_xor(rm, 16, 64));
    rm = fmaxf(rm, __shfl_xor(rm, 32, 64));
    float mnew = fmaxf(m_st, rm);
    float alpha = __expf(m_st - mnew);
    m_st = mnew;
    float rs = 0.f;
#pragma unroll
    for (int t = 0; t < 4; t++) {
      s4v pk;
#pragma unroll
      for (int r = 0; r < 4; r++) {
        float p = __expf(s[t][r] * 0.125f - mnew);
        rs += p;
        bf16 tb = __float2bfloat16(p);
        pk[r] = *(short*)&tb;
      }
      *(s4v*)&QP[wv * 16 + mrow][t * 16 + quad * 4] = pk;
    }
    rs += __shfl_xor(rs, 16, 64);
    rs += __shfl_xor(rs, 32, 64);
    l_st = l_st * alpha + rs;
    float af4[4];
#pragma unroll
    for (int r = 0; r < 4; r++) af4[r] = __shfl(alpha, quad * 4 + r, 64);
#pragma unroll
    for (int t = 0; t < 4; t++)
#pragma unroll
      for (int r = 0; r < 4; r++) oacc[t][r] *= af4[r];
    short8 ap[2];
    ap[0] = *(const short8*)&QP[wv * 16 + mrow][quad * 8];
    ap[1] = *(const short8*)&QP[wv * 16 + mrow][quad * 8 + 32];
    __builtin_amdgcn_s_setprio(1);
#pragma unroll
    for (int t = 0; t < 4; t++) {
      int d = t * 16 + mrow;
      int swz = ((d >> 3) & 3) << 4;
#pragma unroll
      for (int ks = 0; ks < 2; ks++) {
        short8 bv = *(const short8*)&Vt[d][(quad * 8 + ks * 32) ^ swz];
        oacc[t] = __builtin_amdgcn_mfma_f32_16x16x32_bf16(ap[ks], bv, oacc[t], 0, 0, 0);
      }
    }
    __builtin_amdgcn_s_setprio(0);
  }
  float linv[4];
#pragma unroll
  for (int r = 0; r < 4; r++) linv[r] = 1.f / __shfl(l_st, quad * 4 + r, 64);
#pragma unroll
  for (int r = 0; r < 4; r++) {
    size_t base = (size_t)(b * S_ + q0 + wv * 16 + quad * 4 + r) * D_ + hh * 64;
#pragma unroll
    for (int t = 0; t < 4; t++)
      o[base + t * 16 + mrow] = __float2bfloat16(oacc[t][r] * linv[r]);
  }
}

// ---------------- fused: sum partial slices + bias + residual + LayerNorm ----------
// Vectorized: each thread owns the adjacent element pair (2*tid, 2*tid+1) -> uint
// psl loads (2 bf16), float2 h r/w, packed hb16 write. Halves load instruction count.
__global__ __launch_bounds__(256) void reduce_ln_kernel(float* __restrict__ h,
                                                        bf16* __restrict__ hb16,
                                                        const bf16* __restrict__ ps,
                                                        int nsl, int mode,
                                                        const void* __restrict__ bias,
                                                        size_t boff,
                                                        const float* __restrict__ cw,
                                                        const void* __restrict__ eb2p,
                                                        size_t e2off,
                                                        const void* __restrict__ g,
                                                        const void* __restrict__ beta,
                                                        size_t off,
                                                        const int* __restrict__ flag) {
  const int bf = flag[0];
  int t = blockIdx.x, tid = threadIdx.x;
  __shared__ float r1[256], r2[256];
  const size_t base = (size_t)t * D_;
  const int e0 = tid * 2;
  float o0 = 0.f, o1 = 0.f;
  for (int s = 0; s < nsl; s++) {
    unsigned pk = *(const unsigned*)(ps + (size_t)s * T_ * D_ + base + e0);
    unsigned short lo = (unsigned short)(pk & 0xffff), hi = (unsigned short)(pk >> 16);
    o0 += b2f(*(bf16*)&lo);
    o1 += b2f(*(bf16*)&hi);
  }
  if (mode == 0) {
    o0 += ldin(bias, boff + e0, bf);
    o1 += ldin(bias, boff + e0 + 1, bf);
  } else {
#pragma unroll
    for (int e = 0; e < 4; e++) {
      float w = cw[t * 4 + e];
      o0 += w * ldin(eb2p, e2off + e * D_ + e0, bf);
      o1 += w * ldin(eb2p, e2off + e * D_ + e0 + 1, bf);
    }
  }
  float* hr = h + base;
  float2 hv = *(float2*)(hr + e0);
  float v0 = hv.x + o0;
  float v1 = hv.y + o1;
  r1[tid] = v0 + v1;
  r2[tid] = v0 * v0 + v1 * v1;
  __syncthreads();
  for (int w = 128; w; w >>= 1) { if (tid < w) { r1[tid] += r1[tid + w]; r2[tid] += r2[tid + w]; } __syncthreads(); }
  float mean = r1[0] * (1.f / D_);
  float var  = r2[0] * (1.f / D_) - mean * mean;
  float rstd = rsqrtf(var + 1e-5f);
  float n0 = (v0 - mean) * rstd * ldin(g, off + e0, bf) + ldin(beta, off + e0, bf);
  float n1 = (v1 - mean) * rstd * ldin(g, off + e0 + 1, bf) + ldin(beta, off + e0 + 1, bf);
  *(float2*)(hr + e0) = make_float2(n0, n1);
  bf16 b0 = __float2bfloat16(n0), b1 = __float2bfloat16(n1);
  unsigned pk2 = (unsigned)(*(unsigned short*)&b0) | ((unsigned)(*(unsigned short*)&b1) << 16);
  *(unsigned*)(hb16 + base + e0) = pk2;
}

// ---------------- MoE gating: softmax over E=4, top-2; emits routing info ----------
__global__ __launch_bounds__(256) void gate_kernel(const float* __restrict__ hbuf,
                                                   const void* __restrict__ gw, size_t gwoff,
                                                   const void* __restrict__ gb, size_t gboff,
                                                   float* __restrict__ cw,
                                                   int* __restrict__ einfo,
                                                   float* __restrict__ w0a,
                                                   float* __restrict__ w1a,
                                                   const int* __restrict__ flag) {
  const int bf = flag[0];
  int lane = threadIdx.x & 63, wv = threadIdx.x >> 6;
  int t = blockIdx.x * 4 + wv;
  const float* xr = hbuf + (size_t)t * D_;
  float a[4] = {0, 0, 0, 0};
  for (int d = lane; d < D_; d += 64) {
    float xv = xr[d];
#pragma unroll
    for (int e = 0; e < 4; e++) a[e] += xv * ldin(gw, gwoff + e * D_ + d, bf);
  }
#pragma unroll
  for (int e = 0; e < 4; e++)
    for (int off = 32; off; off >>= 1) a[e] += __shfl_xor(a[e], off, 64);
  if (lane == 0) {
    float lg[4];
#pragma unroll
    for (int e = 0; e < 4; e++) lg[e] = a[e] + ldin(gb, gboff + e, bf);
    float m = fmaxf(fmaxf(lg[0], lg[1]), fmaxf(lg[2], lg[3]));
    float p[4], s = 0.f;
#pragma unroll
    for (int e = 0; e < 4; e++) { p[e] = __expf(lg[e] - m); s += p[e]; }
#pragma unroll
    for (int e = 0; e < 4; e++) p[e] /= s;
    int i0 = 0;
    for (int e = 1; e < 4; e++) if (p[e] > p[i0]) i0 = e;
    int i1 = -1;
    for (int e = 0; e < 4; e++) if (e != i0 && (i1 < 0 || p[e] > p[i1])) i1 = e;
    float s2 = p[i0] + p[i1];
    float ww0 = p[i0] / s2, ww1 = p[i1] / s2;
    float outw[4] = {0, 0, 0, 0};
    outw[i0] = ww0; outw[i1] = ww1;
#pragma unroll
    for (int e = 0; e < 4; e++) cw[t * 4 + e] = outw[e];
    einfo[t] = i0 | (i1 << 4);
    w0a[t] = ww0; w1a[t] = ww1;
  }
}

// ---------------- route scan: counts -> offsets + tile table (1 block) ----------------
__global__ __launch_bounds__(256) void route_scan_kernel(const int* __restrict__ einfo,
                                                         int* __restrict__ off,
                                                         int* __restrict__ endp,
                                                         int* __restrict__ cur,
                                                         int* __restrict__ tmap) {
  __shared__ int red[4][256];
  int tid = threadIdx.x;
  int c[4] = {0, 0, 0, 0};
  for (int t = tid; t < T_; t += 256) {
    int inf = einfo[t];
    c[inf & 15]++;
    c[(inf >> 4) & 15]++;
  }
#pragma unroll
  for (int e = 0; e < 4; e++) red[e][tid] = c[e];
  __syncthreads();
  for (int w = 128; w; w >>= 1) {
    if (tid < w)
#pragma unroll
      for (int e = 0; e < 4; e++) red[e][tid] += red[e][tid + w];
    __syncthreads();
  }
  if (tid == 0) {
    int o = 0, idx = 0;
#pragma unroll
    for (int e = 0; e < 4; e++) {
      int cnt = red[e][0];
      off[e] = o;
      endp[e] = o + cnt;
      cur[e] = 0;
      int nt = (cnt + 127) >> 7;
      for (int i = 0; i < nt; i++) tmap[1 + idx++] = e | (i << 8);
      o += nt << 7;
    }
    tmap[0] = idx;   // total active m-tiles (<= 131)
  }
}

// ---------------- scatter: token -> (expert bucket, rank), ballot-aggregated --------
__global__ __launch_bounds__(256) void scatter_kernel(const int* __restrict__ einfo,
                                                      const float* __restrict__ w0a,
                                                      const float* __restrict__ w1a,
                                                      const int* __restrict__ off,
                                                      int* __restrict__ cur,
                                                      int* __restrict__ pack,
                                                      float* __restrict__ wlist) {
  int t = blockIdx.x * 256 + threadIdx.x;
  int lane = threadIdx.x & 63;
  int inf = einfo[t];
#pragma unroll
  for (int rank = 0; rank < 2; rank++) {
    int my_e = (rank == 0) ? (inf & 15) : ((inf >> 4) & 15);
    float w = (rank == 0) ? w0a[t] : w1a[t];
#pragma unroll
    for (int e = 0; e < 4; e++) {
      bool p = (my_e == e);
      unsigned long long mask = __ballot(p);
      if (!mask) continue;
      int leader = __ffsll((long long)mask) - 1;
      int base = 0;
      if (lane == leader) base = atomicAdd(&cur[e], (int)__popcll(mask));
      base = __shfl(base, leader, 64);
      if (p) {
        int pos = off[e] + base + (int)__popcll(mask & ((1ULL << lane) - 1ULL));
        pack[pos] = t * 2 + rank;
        wlist[pos] = w;
      }
    }
  }
}

// ---------------- sparse MoE mat1: 128x128, 3-stage counted-vmcnt pipeline ----------
__global__ __launch_bounds__(256) void moe_mat1_kernel(
    const bf16* __restrict__ A, const bf16* __restrict__ Wt,
    const void* __restrict__ bias, size_t boff, bf16* __restrict__ hid,
    const int* __restrict__ off, const int* __restrict__ endp,
    const int* __restrict__ pack, const float* __restrict__ wlist,
    const int* __restrict__ tmap, const int* __restrict__ flag) {
  const int wbf = flag[0];
  int id = blockIdx.x + 8 * blockIdx.y;
  int xcd = id & 7, idq = id >> 3;
  int wx = idq & 7, wy = xcd + 8 * (idq >> 3);
  if (wy >= tmap[0]) return;
  int ent = tmap[1 + wy];
  const int e = ent & 255, mt = ent >> 8;
  const int o = off[e], en = endp[e];
  const int n0 = wx * 128;
  __shared__ bf16 As[3][128][32];
  __shared__ bf16 Bs[3][128][32];
  const int tid = threadIdx.x;
  const int ln = tid & 63, wv = tid >> 6;
  const int m0 = o + mt * 128;
  const int wr = (wv >> 1) * 64, wc = (wv & 1) * 64;
  const int mrow = ln & 15, quad = ln >> 4;
  const int srow = ln >> 2;
  const int skof = (ln & 3) * 8;
  int tokr[2];
#pragma unroll
  for (int j = 0; j < 2; j++) {
    int pos = m0 + 16 * (4 * j + wv) + srow;
    tokr[j] = pack[min(pos, en - 1)] >> 1;
  }
  const size_t wbase = (size_t)e * 1024 * 512;

  auto stage = [&](int pb, int k0) {
#pragma unroll
    for (int j = 0; j < 2; j++)
      gload16(A + (size_t)tokr[j] * 512 + k0 + skof,
              (char*)&As[pb][0][0] + (size_t)(4 * j + wv) * 1024);
#pragma unroll
    for (int j = 0; j < 2; j++) {
      int row = 16 * (4 * j + wv) + srow;
      gload16(Wt + wbase + (size_t)(n0 + row) * 512 + k0 + skof,
              (char*)&Bs[pb][0][0] + (size_t)(4 * j + wv) * 1024);
    }
  };

  f32x4 acc[4][4];
#pragma unroll
  for (int i = 0; i < 4; i++)
#pragma unroll
    for (int j = 0; j < 4; j++) acc[i][j] = (f32x4){0.f, 0.f, 0.f, 0.f};

  stage(0, 0);
  stage(1, 32);
  int p = 0;
  for (int k0 = 0; k0 < 512; k0 += 32) {
    if (k0 + 32 < 512) asm volatile("s_waitcnt vmcnt(4)" ::: "memory");
    else               asm volatile("s_waitcnt vmcnt(0)" ::: "memory");
    __builtin_amdgcn_s_barrier();
    __builtin_amdgcn_sched_barrier(0);
    short8 af[4], bfr[4];
#pragma unroll
    for (int t = 0; t < 4; t++) {
      af[t]  = *(const short8*)&As[p][wr + t * 16 + mrow][quad * 8];
      bfr[t] = *(const short8*)&Bs[p][wc + t * 16 + mrow][quad * 8];
    }
    if (k0 + 64 < 512) {
      int ps = (p == 0) ? 2 : p - 1;
      stage(ps, k0 + 64);
    }
#pragma unroll
    for (int i = 0; i < 4; i++)
#pragma unroll
      for (int j = 0; j < 4; j++)
        acc[i][j] = __builtin_amdgcn_mfma_f32_16x16x32_bf16(af[i], bfr[j], acc[i][j], 0, 0, 0);
    p = (p == 2) ? 0 : p + 1;
  }

#pragma unroll
  for (int ti = 0; ti < 4; ti++) {
#pragma unroll
    for (int r = 0; r < 4; r++) {
      int pos = m0 + wr + ti * 16 + quad * 4 + r;
      float w = (pos < en) ? wlist[pos] : 0.f;
#pragma unroll
      for (int tj = 0; tj < 4; tj++) {
        int ncol = n0 + wc + tj * 16 + mrow;
        float v = acc[ti][tj][r] + ldin(bias, boff + e * 1024 + ncol, wbf);
        hid[(size_t)pos * 1024 + ncol] = __float2bfloat16(fmaxf(v, 0.f) * w);
      }
    }
  }
}

// ---------------- sparse MoE mat2: 128x128, K=1024 single pass, counted vmcnt -------
// z-split removed: 32 K-steps amortize prologue/epilogue; writes 2 psl slices (rank
// 0/1) instead of 4 -> 16 MB less written + 16 MB less read in reduce_ln.
__global__ __launch_bounds__(256) void moe_mat2_kernel(
    const bf16* __restrict__ hid, const bf16* __restrict__ Wt,
    bf16* __restrict__ psl,
    const int* __restrict__ off, const int* __restrict__ endp,
    const int* __restrict__ pack, const int* __restrict__ tmap,
    const int* __restrict__ flag) {
  int id = blockIdx.x + 4 * blockIdx.y;
  int xcd = id & 7, idq = id >> 3;
  int wx = idq & 3, wy = xcd + 8 * (idq >> 2);
  if (wy >= tmap[0]) return;
  int ent = tmap[1 + wy];
  const int e = ent & 255, mt = ent >> 8;
  const int o = off[e], en = endp[e];
  const int n0 = wx * 128;
  __shared__ bf16 As[3][128][32];
  __shared__ bf16 Bs[3][128][32];
  const int tid = threadIdx.x;
  const int ln = tid & 63, wv = tid >> 6;
  const int m0 = o + mt * 128;
  const int wr = (wv >> 1) * 64, wc = (wv & 1) * 64;
  const int mrow = ln & 15, quad = ln >> 4;
  const int srow = ln >> 2;
  const int skof = (ln & 3) * 8;
  const size_t wbase = (size_t)e * 512 * 1024;

  auto stage = [&](int pb, int k0) {
#pragma unroll
    for (int j = 0; j < 2; j++) {
      int row = 16 * (4 * j + wv) + srow;
      gload16(hid + (size_t)(m0 + row) * 1024 + k0 + skof,
              (char*)&As[pb][0][0] + (size_t)(4 * j + wv) * 1024);
    }
#pragma unroll
    for (int j = 0; j < 2; j++) {
      int row = 16 * (4 * j + wv) + srow;
      gload16(Wt + wbase + (size_t)(n0 + row) * 1024 + k0 + skof,
              (char*)&Bs[pb][0][0] + (size_t)(4 * j + wv) * 1024);
    }
  };

  f32x4 acc[4][4];
#pragma unroll
  for (int i = 0; i < 4; i++)
#pragma unroll
    for (int j = 0; j < 4; j++) acc[i][j] = (f32x4){0.f, 0.f, 0.f, 0.f};

  stage(0, 0);
  stage(1, 32);
  int p = 0;
  for (int k0 = 0; k0 < 1024; k0 += 32) {
    if (k0 + 32 < 1024) asm volatile("s_waitcnt vmcnt(4)" ::: "memory");
    else                asm volatile("s_waitcnt vmcnt(0)" ::: "memory");
    __builtin_amdgcn_s_barrier();
    __builtin_amdgcn_sched_barrier(0);
    short8 af[4], bfr[4];
#pragma unroll
    for (int t = 0; t < 4; t++) {
      af[t]  = *(const short8*)&As[p][wr + t * 16 + mrow][quad * 8];
      bfr[t] = *(const short8*)&Bs[p][wc + t * 16 + mrow][quad * 8];
    }
    if (k0 + 64 < 1024) {
      int ps = (p == 0) ? 2 : p - 1;
      stage(ps, k0 + 64);
    }
#pragma unroll
    for (int i = 0; i < 4; i++)
#pragma unroll
      for (int j = 0; j < 4; j++)
        acc[i][j] = __builtin_amdgcn_mfma_f32_16x16x32_bf16(af[i], bfr[j], acc[i][j], 0, 0, 0);
    p = (p == 2) ? 0 : p + 1;
  }

#pragma unroll
  for (int ti = 0; ti < 4; ti++) {
#pragma unroll
    for (int r = 0; r < 4; r++) {
      int pos = m0 + wr + ti * 16 + quad * 4 + r;
      if (pos < en) {
        int pk = pack[pos];
        int tok = pk >> 1, rank = pk & 1;
        bf16* dst = psl + (size_t)rank * T_ * D_ + (size_t)tok * D_;
#pragma unroll
        for (int tj = 0; tj < 4; tj++) {
          int ncol = n0 + wc + tj * 16 + mrow;
          dst[ncol] = __float2bfloat16(acc[ti][tj][r]);
        }
      }
    }
  }
}

// ---------------- head ----------------
__global__ __launch_bounds__(256) void head_kernel(const float* __restrict__ hbuf,
                                                   const void* __restrict__ hw,
                                                   const void* __restrict__ hb,
                                                   void* __restrict__ out,
                                                   const int* __restrict__ flag) {
  const int bf = flag[0];
  int bq = blockIdx.x, tid = threadIdx.x;
  int b = bq / 3, q = bq % 3;
  __shared__ float red[256];
  const float* xr = hbuf + (size_t)(b * S_ + (S_ - 1)) * D_;
  float sacc = xr[tid] * ldin(hw, (size_t)q * D_ + tid, bf)
             + xr[tid + 256] * ldin(hw, (size_t)q * D_ + tid + 256, bf);
  red[tid] = sacc; __syncthreads();
  for (int w = 128; w; w >>= 1) { if (tid < w) red[tid] += red[tid + w]; __syncthreads(); }
  if (tid == 0) {
    float r = red[0] + ldin(hb, q, bf);
    if (bf) ((bf16*)out)[bq] = __float2bfloat16(r);
    else    ((float*)out)[bq] = r;
  }
}

extern "C" void kernel_launch(void* const* d_in, const int* in_sizes, int n_in,
                              void* d_out, int out_size, void* d_ws, size_t ws_size,
                              hipStream_t stream) {
  const void* x    = d_in[0];
  const void* Wp   = d_in[1];
  const void* bp   = d_in[2];
  const void* femb = d_in[3];
  const void* qkvw = d_in[4];
  const void* qkvb = d_in[5];
  const void* ow   = d_in[6];
  const void* ob   = d_in[7];
  const void* g1   = d_in[8];
  const void* be1  = d_in[9];
  const void* gw   = d_in[10];
  const void* gb   = d_in[11];
  const void* ew1  = d_in[12];
  const void* eb1  = d_in[13];
  const void* ew2  = d_in[14];
  const void* eb2  = d_in[15];
  const void* g2   = d_in[16];
  const void* be2  = d_in[17];
  const void* hw   = d_in[18];
  const void* hb   = d_in[19];
  const int*  freq = (const int*)d_in[20];

  // workspace layout: peak ~99.6 MB (within previously proven-safe 101 MB)
  int*   flag  = (int*)d_ws;                        // 64 ints
  int*   off   = flag + 64;                         // 4
  int*   endp  = off + 4;                           // 4
  int*   cur   = endp + 4;                          // 4 (+pad)
  int*   einfo = flag + 128;                        // T ints
  float* w0a   = (float*)(einfo + T_);              // T
  float* w1a   = w0a + T_;                          // T
  int*   pack  = (int*)(w1a + T_);                  // CAP ints
  float* wlist = (float*)(pack + CAP_);             // CAP
  int*   tmap  = (int*)(wlist + CAP_);              // 160 ints (count + tiles)
  float* xn    = (float*)(tmap + 160);              // 65536
  float* h     = xn + 65536;                        // T*D f    (16 MB)
  float* cw    = h + (size_t)T_ * D_;               // T*4
  bf16*  hb16  = (bf16*)(cw + (size_t)T_ * E_);     // T*D bf16 (8 MB)
  bf16*  R     = hb16 + (size_t)T_ * D_;            // alias region
  bf16*  qkvb16 = R;                                // T*3D bf16 (24 MB)
  bf16*  ao    = R + (size_t)T_ * D3_;              // T*D bf16  (8 MB)
  bf16*  hid   = R;                                 // CAP*1024 bf16 (~33 MB)
  bf16*  psl   = R + (size_t)CAP_ * 1024;           // 4x T*D bf16 (2 used by mat2, 2 by o-proj)
  bf16*  wcvt  = psl + (size_t)4 * T_ * D_;         // 8.4 MB bf16 weight scratch
  bf16*  wq    = wcvt;
  bf16*  wo    = wcvt + (size_t)D3_ * D_;
  bf16*  we1   = wcvt;
  bf16*  we2   = wcvt + (size_t)E_ * 1024 * 512;
  float* addtab = (float*)R;                        // [S][D] f32 PE table (dead before QKV GEMM)

  constexpr size_t NQ = (size_t)D3_ * D_;           // 786432
  constexpr size_t NO = (size_t)D_ * D_;            // 262144
  constexpr size_t NE = (size_t)E_ * 1024 * 512;    // 2097152

  detect_kernel<<<1, 64, 0, stream>>>(x, flag);
  instnorm_kernel<<<B_ * F_, 256, 0, stream>>>(x, xn, flag);
  pe_kernel<<<(S_ * D_ / 2) / 256, 256, 0, stream>>>(bp, femb, freq, addtab, flag);
  input_proj_kernel<<<T_ / IPG_, 256, 0, stream>>>(xn, Wp, addtab, h, hb16, flag);

  for (int l = 0; l < 3; l++) {
    // convert this layer's qkv_w + ow to bf16 scratch (copy if already bf16)
    convw_kernel<<<(NQ + NO) / 2048, 256, 0, stream>>>(
        qkvw, (size_t)l * NQ, NQ, ow, (size_t)l * NO, wcvt, flag);
    // QKV projection -> bf16
    mfma_gemm<3><<<dim3(D3_ / 128, T_ / 128), 256, 0, stream>>>(
        hb16, wq, qkvb, (size_t)l * D3_, qkvb16, D_, D_, D_, D3_, flag);
    attn_kernel<<<B_ * H_ * (S_ / 128), 512, 0, stream>>>(qkvb16, ao);
    // O-projection: split-K=2 -> slices 0,1; fused reduce + bias + LN
    mfma_gemm<0><<<dim3(D_ / 128, T_ / 128, 2), 256, 0, stream>>>(
        ao, wo, nullptr, 0, psl, D_, D_, D_, D_, flag);
    reduce_ln_kernel<<<T_, 256, 0, stream>>>(
        h, hb16, psl, 2, 0, ob, (size_t)l * D_, nullptr, nullptr, 0,
        g1, be1, (size_t)l * D_, flag);
    // gating + routing
    gate_kernel<<<T_ / 4, 256, 0, stream>>>(h, gw, (size_t)l * E_ * D_, gb, (size_t)l * E_,
                                            cw, einfo, w0a, w1a, flag);
    route_scan_kernel<<<1, 256, 0, stream>>>(einfo, off, endp, cur, tmap);
    scatter_kernel<<<T_ / 256, 256, 0, stream>>>(einfo, w0a, w1a, off, cur, pack, wlist);
    // convert this layer's ew1 + ew2 to bf16 scratch (wq/wo dead past here)
    convw_kernel<<<(NE + NE) / 2048, 256, 0, stream>>>(
        ew1, (size_t)l * NE, NE, ew2, (size_t)l * NE, wcvt, flag);
    // sparse expert GEMMs (hid aliases qkv+ao, both dead here)
    moe_mat1_kernel<<<dim3(8, 136), 256, 0, stream>>>(
        hb16, we1, eb1, (size_t)l * E_ * 1024, hid,
        off, endp, pack, wlist, tmap, flag);
    moe_mat2_kernel<<<dim3(4, 136), 256, 0, stream>>>(
        hid, we2, psl, off, endp, pack, tmap, flag);
    reduce_ln_kernel<<<T_, 256, 0, stream>>>(
        h, hb16, psl, 2, 1, nullptr, 0, cw, eb2, (size_t)l * E_ * D_,
        g2, be2, (size_t)l * D_, flag);
  }

  head_kernel<<<24, 256, 0, stream>>>(h, hw, hb, d_out, flag);
}